// Round 1
// baseline (943.855 us; speedup 1.0000x reference)
//
#include <hip/hip_runtime.h>
#include <hip/hip_bf16.h>

// GNN: GAT(128->4x32) -> GAT(128->4x32) -> GraphConv(128->32) -> SAGE(32->32)
//      -> global mean pool (64 graphs) -> MLP(32->32->10)
// Strategy: build CSR-by-dst once per launch (no float atomics anywhere),
// per-dst gather aggregation, LDS-staged fp32 GEMMs.

__device__ __forceinline__ float lrelu(float x) { return x > 0.f ? x : 0.2f * x; }

// ---------------- CSR build ----------------
__global__ void hist_kernel(const int* __restrict__ dst, int* __restrict__ deg, int E) {
    int e = blockIdx.x * 256 + threadIdx.x;
    if (e < E) atomicAdd(&deg[dst[e]], 1);
}

__global__ __launch_bounds__(1024) void scan_kernel(const int* __restrict__ deg,
                                                    int* __restrict__ rowptr,
                                                    int* __restrict__ cur, int n, int E) {
    __shared__ int part[1024];
    int t = threadIdx.x;
    int chunk = (n + 1023) >> 10;
    int b = t * chunk;
    int e = b + chunk; if (e > n) e = n;
    int s = 0;
    for (int i = b; i < e; ++i) s += deg[i];
    part[t] = s;
    __syncthreads();
    for (int off = 1; off < 1024; off <<= 1) {
        int v = (t >= off) ? part[t - off] : 0;
        __syncthreads();
        part[t] += v;
        __syncthreads();
    }
    int run = (t == 0) ? 0 : part[t - 1];
    for (int i = b; i < e; ++i) { rowptr[i] = run; cur[i] = run; run += deg[i]; }
    if (t == 1023) rowptr[n] = part[1023];
}

__global__ void fill_kernel(const int* __restrict__ src, const int* __restrict__ dst,
                            int* __restrict__ cur, int* __restrict__ colsrc, int E) {
    int e = blockIdx.x * 256 + threadIdx.x;
    if (e < E) {
        int d = dst[e];
        int p = atomicAdd(&cur[d], 1);
        colsrc[p] = src[e];
    }
}

// ---------------- GAT: h = x@W, a_s/a_d attention dots ----------------
// Grid = 2*G blocks; even/odd blocks handle column halves [0,64)/[64,128).
__global__ __launch_bounds__(256) void gemm_att(
    const float* __restrict__ xin, const float* __restrict__ W,
    const float* __restrict__ att_s, const float* __restrict__ att_d,
    float* __restrict__ h, float* __restrict__ a_s, float* __restrict__ a_d, int n)
{
    __shared__ __align__(16) float sW[128 * 64];
    __shared__ __align__(16) float sx[8 * 128];
    int t = threadIdx.x;
    int colbase = (blockIdx.x & 1) << 6;
    for (int i = t; i < 128 * 64; i += 256) {
        int k = i >> 6, c = i & 63;
        sW[i] = W[k * 128 + colbase + c];
    }
    int cl = t & 63;
    int col = colbase + cl;
    int r0 = (t >> 6) * 2;           // 0,2,4,6
    float asv = att_s[col], adv = att_d[col];
    int hh = col >> 5;
    int rowstep = (gridDim.x >> 1) * 8;
    for (int row0 = (blockIdx.x >> 1) * 8; row0 < n; row0 += rowstep) {
        __syncthreads();
        for (int i = t; i < 8 * 128; i += 256) {
            int rr = i >> 7, cc = i & 127;
            int row = row0 + rr;
            sx[i] = (row < n) ? xin[row * 128 + cc] : 0.f;
        }
        __syncthreads();
        float acc0 = 0.f, acc1 = 0.f;
        const float4* xa4 = (const float4*)&sx[r0 * 128];
        const float4* xb4 = (const float4*)&sx[(r0 + 1) * 128];
        #pragma unroll 8
        for (int k4 = 0; k4 < 32; ++k4) {
            float4 xa = xa4[k4], xb = xb4[k4];
            const float* wp = &sW[(k4 * 4) * 64 + cl];
            float w0 = wp[0], w1 = wp[64], w2 = wp[128], w3 = wp[192];
            acc0 += xa.x * w0 + xa.y * w1 + xa.z * w2 + xa.w * w3;
            acc1 += xb.x * w0 + xb.y * w1 + xb.z * w2 + xb.w * w3;
        }
        int ra = row0 + r0, rb = ra + 1;
        if (ra < n) h[ra * 128 + col] = acc0;
        if (rb < n) h[rb * 128 + col] = acc1;
        float ps0 = acc0 * asv, pd0 = acc0 * adv;
        float ps1 = acc1 * asv, pd1 = acc1 * adv;
        for (int off = 16; off; off >>= 1) {
            ps0 += __shfl_xor(ps0, off, 32);
            pd0 += __shfl_xor(pd0, off, 32);
            ps1 += __shfl_xor(ps1, off, 32);
            pd1 += __shfl_xor(pd1, off, 32);
        }
        if ((cl & 31) == 0) {
            if (ra < n) { a_s[ra * 4 + hh] = ps0; a_d[ra * 4 + hh] = pd0; }
            if (rb < n) { a_s[rb * 4 + hh] = ps1; a_d[rb * 4 + hh] = pd1; }
        }
    }
}

// ---------------- GAT: per-dst softmax + aggregation (incl. self-loop) ----------------
__global__ __launch_bounds__(128) void gat_aggr(
    const float* __restrict__ h, const float* __restrict__ a_s, const float* __restrict__ a_d,
    const int* __restrict__ rowptr, const int* __restrict__ colsrc,
    const float* __restrict__ bias, float* __restrict__ out, int n)
{
    int d = blockIdx.x;
    int t = threadIdx.x;
    __shared__ float s_m[4], s_z[4], s_ws[4];
    int beg = rowptr[d], end = rowptr[d + 1];
    int cnt = end - beg;
    float4 ad4 = *(const float4*)&a_d[d * 4];
    if (t < 64) {
        float4 av = *(const float4*)&a_s[d * 4];
        float es0 = lrelu(av.x + ad4.x), es1 = lrelu(av.y + ad4.y);
        float es2 = lrelu(av.z + ad4.z), es3 = lrelu(av.w + ad4.w);
        float m0 = es0, m1 = es1, m2 = es2, m3 = es3;
        for (int j = t; j < cnt; j += 64) {
            int s = colsrc[beg + j];
            float4 sv = *(const float4*)&a_s[s * 4];
            m0 = fmaxf(m0, lrelu(sv.x + ad4.x));
            m1 = fmaxf(m1, lrelu(sv.y + ad4.y));
            m2 = fmaxf(m2, lrelu(sv.z + ad4.z));
            m3 = fmaxf(m3, lrelu(sv.w + ad4.w));
        }
        for (int off = 32; off; off >>= 1) {
            m0 = fmaxf(m0, __shfl_xor(m0, off));
            m1 = fmaxf(m1, __shfl_xor(m1, off));
            m2 = fmaxf(m2, __shfl_xor(m2, off));
            m3 = fmaxf(m3, __shfl_xor(m3, off));
        }
        float z0 = 0.f, z1 = 0.f, z2 = 0.f, z3 = 0.f;
        for (int j = t; j < cnt; j += 64) {
            int s = colsrc[beg + j];
            float4 sv = *(const float4*)&a_s[s * 4];
            z0 += __expf(lrelu(sv.x + ad4.x) - m0);
            z1 += __expf(lrelu(sv.y + ad4.y) - m1);
            z2 += __expf(lrelu(sv.z + ad4.z) - m2);
            z3 += __expf(lrelu(sv.w + ad4.w) - m3);
        }
        for (int off = 32; off; off >>= 1) {
            z0 += __shfl_xor(z0, off);
            z1 += __shfl_xor(z1, off);
            z2 += __shfl_xor(z2, off);
            z3 += __shfl_xor(z3, off);
        }
        if (t == 0) {
            float w0 = __expf(es0 - m0), w1 = __expf(es1 - m1);
            float w2 = __expf(es2 - m2), w3 = __expf(es3 - m3);
            s_m[0] = m0; s_m[1] = m1; s_m[2] = m2; s_m[3] = m3;
            s_ws[0] = w0; s_ws[1] = w1; s_ws[2] = w2; s_ws[3] = w3;
            s_z[0] = z0 + w0; s_z[1] = z1 + w1; s_z[2] = z2 + w2; s_z[3] = z3 + w3;
        }
    }
    __syncthreads();
    int hh = t >> 5;
    float m = s_m[hh];
    float zinv = 1.f / (s_z[hh] + 1e-16f);
    float adh = a_d[d * 4 + hh];
    float acc = s_ws[hh] * h[d * 128 + t];          // self-loop contribution
    for (int j = 0; j < cnt; ++j) {
        int s = colsrc[beg + j];
        float e = a_s[s * 4 + hh] + adh;
        e = e > 0.f ? e : 0.2f * e;
        acc += __expf(e - m) * h[s * 128 + t];
    }
    out[d * 128 + t] = fmaxf(acc * zinv + bias[t], 0.f);
}

// ---------------- GraphConv aggregation: agg[d] = sum_{src->d} x[src], 128 ch ---------
__global__ __launch_bounds__(128) void sum_aggr128(
    const float* __restrict__ x, const int* __restrict__ rowptr,
    const int* __restrict__ colsrc, float* __restrict__ agg, int n)
{
    int d = blockIdx.x;
    int t = threadIdx.x;
    int beg = rowptr[d], end = rowptr[d + 1];
    float acc = 0.f;
    for (int j = beg; j < end; ++j) acc += x[colsrc[j] * 128 + t];
    agg[d * 128 + t] = acc;
}

// ---------------- GraphConv GEMM: out = relu(agg@Wr + b + x@Wl), 128->32 -------------
__global__ __launch_bounds__(256) void graphconv_gemm(
    const float* __restrict__ agg, const float* __restrict__ xin,
    const float* __restrict__ Wr, const float* __restrict__ Wl,
    const float* __restrict__ bias, float* __restrict__ out, int n)
{
    __shared__ __align__(16) float sWr[128 * 32], sWl[128 * 32];
    __shared__ __align__(16) float sa[8 * 128], sx[8 * 128];
    int t = threadIdx.x;
    for (int i = t; i < 128 * 32; i += 256) { sWr[i] = Wr[i]; sWl[i] = Wl[i]; }
    int c = t & 31, rr = t >> 5;
    float bc = bias[c];
    for (int row0 = blockIdx.x * 8; row0 < n; row0 += gridDim.x * 8) {
        __syncthreads();
        for (int i = t; i < 8 * 128; i += 256) {
            int r = i >> 7, cc = i & 127;
            int row = row0 + r;
            sa[i] = (row < n) ? agg[row * 128 + cc] : 0.f;
            sx[i] = (row < n) ? xin[row * 128 + cc] : 0.f;
        }
        __syncthreads();
        float acc = bc;
        const float4* pa = (const float4*)&sa[rr * 128];
        const float4* px = (const float4*)&sx[rr * 128];
        #pragma unroll 8
        for (int k4 = 0; k4 < 32; ++k4) {
            float4 va = pa[k4], vx = px[k4];
            const float* wr = &sWr[(k4 * 4) * 32 + c];
            const float* wl = &sWl[(k4 * 4) * 32 + c];
            acc += va.x * wr[0] + va.y * wr[32] + va.z * wr[64] + va.w * wr[96];
            acc += vx.x * wl[0] + vx.y * wl[32] + vx.z * wl[64] + vx.w * wl[96];
        }
        int row = row0 + rr;
        if (row < n) out[row * 32 + c] = fmaxf(acc, 0.f);
    }
}

// ---------------- SAGE mean aggregation, 32 ch ----------------
__global__ __launch_bounds__(128) void mean_aggr32(
    const float* __restrict__ x, const int* __restrict__ rowptr,
    const int* __restrict__ colsrc, float* __restrict__ mean, int n)
{
    int d = blockIdx.x * 4 + (threadIdx.x >> 5);
    int c = threadIdx.x & 31;
    if (d >= n) return;
    int beg = rowptr[d], end = rowptr[d + 1];
    float acc = 0.f;
    for (int j = beg; j < end; ++j) acc += x[colsrc[j] * 32 + c];
    float invd = 1.f / fmaxf((float)(end - beg), 1.f);
    mean[d * 32 + c] = acc * invd;
}

// ---------------- SAGE GEMM: out = relu(mean@Wl + bl + x@Wr), 32->32 -----------------
__global__ __launch_bounds__(256) void sage_gemm(
    const float* __restrict__ mean, const float* __restrict__ xin,
    const float* __restrict__ Wl, const float* __restrict__ bl,
    const float* __restrict__ Wr, float* __restrict__ out, int n)
{
    __shared__ __align__(16) float sWl[32 * 32], sWr[32 * 32];
    __shared__ __align__(16) float sm[8 * 32], sx[8 * 32];
    int t = threadIdx.x;
    for (int i = t; i < 1024; i += 256) { sWl[i] = Wl[i]; sWr[i] = Wr[i]; }
    int c = t & 31, rr = t >> 5;
    float bc = bl[c];
    for (int row0 = blockIdx.x * 8; row0 < n; row0 += gridDim.x * 8) {
        __syncthreads();
        {
            int i = t;  // 256 elems, 1 per thread
            int r = i >> 5, cc = i & 31;
            int row = row0 + r;
            sm[i] = (row < n) ? mean[row * 32 + cc] : 0.f;
            sx[i] = (row < n) ? xin[row * 32 + cc] : 0.f;
        }
        __syncthreads();
        float acc = bc;
        const float4* pm = (const float4*)&sm[rr * 32];
        const float4* px = (const float4*)&sx[rr * 32];
        #pragma unroll
        for (int k4 = 0; k4 < 8; ++k4) {
            float4 vm = pm[k4], vx = px[k4];
            const float* wl = &sWl[(k4 * 4) * 32 + c];
            const float* wr = &sWr[(k4 * 4) * 32 + c];
            acc += vm.x * wl[0] + vm.y * wl[32] + vm.z * wl[64] + vm.w * wl[96];
            acc += vx.x * wr[0] + vx.y * wr[32] + vx.z * wr[64] + vx.w * wr[96];
        }
        int row = row0 + rr;
        if (row < n) out[row * 32 + c] = fmaxf(acc, 0.f);
    }
}

// ---------------- global mean pool (batch sorted) ----------------
__device__ __forceinline__ int lower_bound_i(const int* a, int n, int key) {
    int lo = 0, hi = n;
    while (lo < hi) { int mid = (lo + hi) >> 1; if (a[mid] < key) lo = mid + 1; else hi = mid; }
    return lo;
}

__global__ __launch_bounds__(256) void pool_kernel(
    const float* __restrict__ x, const int* __restrict__ batch,
    float* __restrict__ gpool, int n)
{
    int g = blockIdx.x;
    int lo = lower_bound_i(batch, n, g);
    int hi = lower_bound_i(batch, n, g + 1);
    int t = threadIdx.x;
    int c = t & 31, rr = t >> 5;
    float acc = 0.f;
    for (int i = lo + rr; i < hi; i += 8) acc += x[i * 32 + c];
    __shared__ float sred[256];
    sred[t] = acc;
    __syncthreads();
    if (t < 128) sred[t] += sred[t + 128];
    __syncthreads();
    if (t < 64) sred[t] += sred[t + 64];
    __syncthreads();
    if (t < 32) {
        float v = sred[t] + sred[t + 32];
        gpool[g * 32 + t] = v / fmaxf((float)(hi - lo), 1.f);
    }
}

// ---------------- MLP head ----------------
__global__ __launch_bounds__(256) void head_kernel(
    const float* __restrict__ gpool, const float* __restrict__ Wf1, const float* __restrict__ bf1,
    const float* __restrict__ Wf2, const float* __restrict__ bf2, float* __restrict__ out)
{
    __shared__ float sg[64 * 32], st[64 * 32];
    __shared__ float sW1[32 * 32], sW2[32 * 10];
    int t = threadIdx.x;
    for (int i = t; i < 2048; i += 256) sg[i] = gpool[i];
    for (int i = t; i < 1024; i += 256) sW1[i] = Wf1[i];
    for (int i = t; i < 320; i += 256) sW2[i] = Wf2[i];
    __syncthreads();
    for (int i = t; i < 2048; i += 256) {
        int g = i >> 5, c = i & 31;
        float acc = bf1[c];
        #pragma unroll
        for (int k = 0; k < 32; ++k) acc += sg[g * 32 + k] * sW1[k * 32 + c];
        st[i] = fmaxf(acc, 0.f);
    }
    __syncthreads();
    for (int i = t; i < 640; i += 256) {
        int g = i / 10, o = i - g * 10;
        float acc = bf2[o];
        #pragma unroll
        for (int k = 0; k < 32; ++k) acc += st[g * 32 + k] * sW2[k * 10 + o];
        out[i] = acc;
    }
}

extern "C" void kernel_launch(void* const* d_in, const int* in_sizes, int n_in,
                              void* d_out, int out_size, void* d_ws, size_t ws_size,
                              hipStream_t stream) {
    const float* x    = (const float*)d_in[0];
    const int*   ei   = (const int*)d_in[1];
    const int*   batch= (const int*)d_in[2];
    const float* W1   = (const float*)d_in[3];
    const float* as1  = (const float*)d_in[4];
    const float* ad1  = (const float*)d_in[5];
    const float* b1   = (const float*)d_in[6];
    const float* W2   = (const float*)d_in[7];
    const float* as2  = (const float*)d_in[8];
    const float* ad2  = (const float*)d_in[9];
    const float* b2   = (const float*)d_in[10];
    const float* W3r  = (const float*)d_in[11];
    const float* W3l  = (const float*)d_in[12];
    const float* b3   = (const float*)d_in[13];
    const float* W4l  = (const float*)d_in[14];
    const float* b4l  = (const float*)d_in[15];
    const float* W4r  = (const float*)d_in[16];
    const float* Wf1  = (const float*)d_in[17];
    const float* bf1  = (const float*)d_in[18];
    const float* Wf2  = (const float*)d_in[19];
    const float* bf2  = (const float*)d_in[20];

    const int N = in_sizes[0] / 128;
    const int E = in_sizes[1] / 2;
    const int* src = ei;
    const int* dst = ei + E;

    // workspace carve (256B aligned)
    char* p = (char*)d_ws;
    auto alloc = [&](size_t bytes) -> void* {
        void* r = (void*)p;
        p += (bytes + 255) & ~(size_t)255;
        return r;
    };
    float* A      = (float*)alloc((size_t)N * 128 * 4);   // h / agg / mean
    float* B      = (float*)alloc((size_t)N * 128 * 4);   // x1 / x2 / x4
    float* D      = (float*)alloc((size_t)N * 32 * 4);    // x3
    float* aS     = (float*)alloc((size_t)N * 4 * 4);
    float* aD     = (float*)alloc((size_t)N * 4 * 4);
    int*   deg    = (int*)alloc((size_t)N * 4);
    int*   rowptr = (int*)alloc((size_t)(N + 1) * 4);
    int*   cur    = (int*)alloc((size_t)N * 4);
    int*   colsrc = (int*)alloc((size_t)E * 4);
    float* gpool  = (float*)alloc(64 * 32 * 4);

    // CSR build (reused by all 4 message-passing layers)
    hipMemsetAsync(deg, 0, (size_t)N * 4, stream);
    hist_kernel<<<(E + 255) / 256, 256, 0, stream>>>(dst, deg, E);
    scan_kernel<<<1, 1024, 0, stream>>>(deg, rowptr, cur, N, E);
    fill_kernel<<<(E + 255) / 256, 256, 0, stream>>>(src, dst, cur, colsrc, E);

    // GAT layer 1
    gemm_att<<<2048, 256, 0, stream>>>(x, W1, as1, ad1, A, aS, aD, N);
    gat_aggr<<<N, 128, 0, stream>>>(A, aS, aD, rowptr, colsrc, b1, B, N);
    // GAT layer 2
    gemm_att<<<2048, 256, 0, stream>>>(B, W2, as2, ad2, A, aS, aD, N);
    gat_aggr<<<N, 128, 0, stream>>>(A, aS, aD, rowptr, colsrc, b2, B, N);
    // GraphConv
    sum_aggr128<<<N, 128, 0, stream>>>(B, rowptr, colsrc, A, N);
    graphconv_gemm<<<1024, 256, 0, stream>>>(A, B, W3r, W3l, b3, D, N);
    // SAGE
    mean_aggr32<<<(N + 3) / 4, 128, 0, stream>>>(D, rowptr, colsrc, A, N);
    sage_gemm<<<1024, 256, 0, stream>>>(A, D, W4l, b4l, W4r, B, N);
    // pool + head
    pool_kernel<<<64, 256, 0, stream>>>(B, batch, gpool, N);
    head_kernel<<<1, 256, 0, stream>>>(gpool, Wf1, bf1, Wf2, bf2, (float*)d_out);
}

// Round 2
// 781.858 us; speedup vs baseline: 1.2072x; 1.2072x over previous
//
#include <hip/hip_runtime.h>
#include <hip/hip_bf16.h>
#include <type_traits>

// GNN: GAT(128->4x32) -> GAT(128->4x32) -> GraphConv(128->32) -> SAGE(32->32)
//      -> global mean pool (64 graphs) -> MLP(32->32->10)
// R1: CSR gather aggregation, fp32 everywhere.            944 us
// R2: bf16 node features (halve gather traffic) + cooperative alpha in LDS
//     (expf per (edge,head) instead of per (edge,channel): 32x fewer).

__device__ __forceinline__ float lrelu(float x) { return x > 0.f ? x : 0.2f * x; }

__device__ __forceinline__ float bf2f(__hip_bfloat16 b) {
    unsigned short u = *(const unsigned short*)&b;
    return __uint_as_float((unsigned)u << 16);
}
__device__ __forceinline__ unsigned short f2bf(float f) {
    unsigned u = __float_as_uint(f);
    unsigned r = (u + 0x7FFF + ((u >> 16) & 1)) >> 16;   // RNE
    return (unsigned short)r;
}
__device__ __forceinline__ float4 load_bf16x4(const __hip_bfloat16* p) {
    ushort4 u = *(const ushort4*)p;
    float4 f;
    f.x = __uint_as_float((unsigned)u.x << 16);
    f.y = __uint_as_float((unsigned)u.y << 16);
    f.z = __uint_as_float((unsigned)u.z << 16);
    f.w = __uint_as_float((unsigned)u.w << 16);
    return f;
}

// ---------------- CSR build ----------------
__global__ void hist_kernel(const int* __restrict__ dst, int* __restrict__ deg, int E) {
    int e = blockIdx.x * 256 + threadIdx.x;
    if (e < E) atomicAdd(&deg[dst[e]], 1);
}

__global__ __launch_bounds__(1024) void scan_kernel(const int* __restrict__ deg,
                                                    int* __restrict__ rowptr,
                                                    int* __restrict__ cur, int n, int E) {
    __shared__ int part[1024];
    int t = threadIdx.x;
    int chunk = (n + 1023) >> 10;
    int b = t * chunk;
    int e = b + chunk; if (e > n) e = n;
    int s = 0;
    for (int i = b; i < e; ++i) s += deg[i];
    part[t] = s;
    __syncthreads();
    for (int off = 1; off < 1024; off <<= 1) {
        int v = (t >= off) ? part[t - off] : 0;
        __syncthreads();
        part[t] += v;
        __syncthreads();
    }
    int run = (t == 0) ? 0 : part[t - 1];
    for (int i = b; i < e; ++i) { rowptr[i] = run; cur[i] = run; run += deg[i]; }
    if (t == 1023) rowptr[n] = part[1023];
}

__global__ void fill_kernel(const int* __restrict__ src, const int* __restrict__ dst,
                            int* __restrict__ cur, int* __restrict__ colsrc, int E) {
    int e = blockIdx.x * 256 + threadIdx.x;
    if (e < E) {
        int d = dst[e];
        int p = atomicAdd(&cur[d], 1);
        colsrc[p] = src[e];
    }
}

// ---------------- GAT: h = x@W (bf16 out), a_s/a_d attention dots (fp32) ----------
// Grid = 2*G blocks; even/odd blocks handle column halves [0,64)/[64,128).
template <typename T>
__global__ __launch_bounds__(256) void gemm_att(
    const T* __restrict__ xin, const float* __restrict__ W,
    const float* __restrict__ att_s, const float* __restrict__ att_d,
    __hip_bfloat16* __restrict__ h, float* __restrict__ a_s, float* __restrict__ a_d, int n)
{
    __shared__ __align__(16) float sW[128 * 64];
    __shared__ __align__(16) float sx[8 * 128];
    int t = threadIdx.x;
    int colbase = (blockIdx.x & 1) << 6;
    for (int i = t; i < 128 * 64; i += 256) {
        int k = i >> 6, c = i & 63;
        sW[i] = W[k * 128 + colbase + c];
    }
    int cl = t & 63;
    int col = colbase + cl;
    int r0 = (t >> 6) * 2;           // 0,2,4,6
    float asv = att_s[col], adv = att_d[col];
    int hh = col >> 5;
    int rowstep = (gridDim.x >> 1) * 8;
    for (int row0 = (blockIdx.x >> 1) * 8; row0 < n; row0 += rowstep) {
        __syncthreads();
        if constexpr (std::is_same<T, float>::value) {
            for (int i = t; i < 8 * 128; i += 256) {
                int rr = i >> 7, cc = i & 127;
                int row = row0 + rr;
                sx[i] = (row < n) ? xin[row * 128 + cc] : 0.f;
            }
        } else {
            for (int i = t; i < 8 * 64; i += 256) {   // bf16x2 loads
                int rr = i >> 6, cp = i & 63;
                int row = row0 + rr;
                float vx = 0.f, vy = 0.f;
                if (row < n) {
                    ushort2 u = *(const ushort2*)&xin[row * 128 + cp * 2];
                    vx = __uint_as_float((unsigned)u.x << 16);
                    vy = __uint_as_float((unsigned)u.y << 16);
                }
                sx[rr * 128 + cp * 2]     = vx;
                sx[rr * 128 + cp * 2 + 1] = vy;
            }
        }
        __syncthreads();
        float acc0 = 0.f, acc1 = 0.f;
        const float4* xa4 = (const float4*)&sx[r0 * 128];
        const float4* xb4 = (const float4*)&sx[(r0 + 1) * 128];
        #pragma unroll 8
        for (int k4 = 0; k4 < 32; ++k4) {
            float4 xa = xa4[k4], xb = xb4[k4];
            const float* wp = &sW[(k4 * 4) * 64 + cl];
            float w0 = wp[0], w1 = wp[64], w2 = wp[128], w3 = wp[192];
            acc0 += xa.x * w0 + xa.y * w1 + xa.z * w2 + xa.w * w3;
            acc1 += xb.x * w0 + xb.y * w1 + xb.z * w2 + xb.w * w3;
        }
        int ra = row0 + r0, rb = ra + 1;
        if (ra < n) *(unsigned short*)&h[ra * 128 + col] = f2bf(acc0);
        if (rb < n) *(unsigned short*)&h[rb * 128 + col] = f2bf(acc1);
        float ps0 = acc0 * asv, pd0 = acc0 * adv;
        float ps1 = acc1 * asv, pd1 = acc1 * adv;
        for (int off = 16; off; off >>= 1) {
            ps0 += __shfl_xor(ps0, off, 32);
            pd0 += __shfl_xor(pd0, off, 32);
            ps1 += __shfl_xor(ps1, off, 32);
            pd1 += __shfl_xor(pd1, off, 32);
        }
        if ((cl & 31) == 0) {
            if (ra < n) { a_s[ra * 4 + hh] = ps0; a_d[ra * 4 + hh] = pd0; }
            if (rb < n) { a_s[rb * 4 + hh] = ps1; a_d[rb * 4 + hh] = pd1; }
        }
    }
}

// ---------------- GAT: per-dst softmax + aggregation (incl. self-loop) -------------
// Block = 128 (one dst). Phase A (wave0): 2-pass max/sum per head.
// Phase B: chunks of 32 edges; 128 threads compute 32x4 alphas into LDS (1 expf
// per (edge,head)), then 4 edge-groups x 32 lanes accumulate bf16x4 rows.
__global__ __launch_bounds__(128) void gat_aggr(
    const __hip_bfloat16* __restrict__ h, const float* __restrict__ a_s,
    const float* __restrict__ a_d,
    const int* __restrict__ rowptr, const int* __restrict__ colsrc,
    const float* __restrict__ bias, __hip_bfloat16* __restrict__ out, int n)
{
    int d = blockIdx.x;
    int t = threadIdx.x;
    __shared__ float s_m[4], s_zinv[4], s_ws[4];
    __shared__ int   s_src[32];
    __shared__ float s_alpha[32 * 4];
    __shared__ float s_red[4 * 128];
    int beg = rowptr[d], end = rowptr[d + 1];
    int cnt = end - beg;

    if (t < 64) {
        float4 ad4 = *(const float4*)&a_d[d * 4];
        float4 av  = *(const float4*)&a_s[d * 4];
        float es0 = lrelu(av.x + ad4.x), es1 = lrelu(av.y + ad4.y);
        float es2 = lrelu(av.z + ad4.z), es3 = lrelu(av.w + ad4.w);
        float m0 = es0, m1 = es1, m2 = es2, m3 = es3;
        for (int j = t; j < cnt; j += 64) {
            int s = colsrc[beg + j];
            float4 sv = *(const float4*)&a_s[s * 4];
            m0 = fmaxf(m0, lrelu(sv.x + ad4.x));
            m1 = fmaxf(m1, lrelu(sv.y + ad4.y));
            m2 = fmaxf(m2, lrelu(sv.z + ad4.z));
            m3 = fmaxf(m3, lrelu(sv.w + ad4.w));
        }
        for (int off = 32; off; off >>= 1) {
            m0 = fmaxf(m0, __shfl_xor(m0, off));
            m1 = fmaxf(m1, __shfl_xor(m1, off));
            m2 = fmaxf(m2, __shfl_xor(m2, off));
            m3 = fmaxf(m3, __shfl_xor(m3, off));
        }
        float z0 = 0.f, z1 = 0.f, z2 = 0.f, z3 = 0.f;
        for (int j = t; j < cnt; j += 64) {
            int s = colsrc[beg + j];
            float4 sv = *(const float4*)&a_s[s * 4];
            z0 += __expf(lrelu(sv.x + ad4.x) - m0);
            z1 += __expf(lrelu(sv.y + ad4.y) - m1);
            z2 += __expf(lrelu(sv.z + ad4.z) - m2);
            z3 += __expf(lrelu(sv.w + ad4.w) - m3);
        }
        for (int off = 32; off; off >>= 1) {
            z0 += __shfl_xor(z0, off);
            z1 += __shfl_xor(z1, off);
            z2 += __shfl_xor(z2, off);
            z3 += __shfl_xor(z3, off);
        }
        if (t == 0) {
            float w0 = __expf(es0 - m0), w1 = __expf(es1 - m1);
            float w2 = __expf(es2 - m2), w3 = __expf(es3 - m3);
            s_m[0] = m0; s_m[1] = m1; s_m[2] = m2; s_m[3] = m3;
            s_ws[0] = w0; s_ws[1] = w1; s_ws[2] = w2; s_ws[3] = w3;
            s_zinv[0] = 1.f / (z0 + w0 + 1e-16f);
            s_zinv[1] = 1.f / (z1 + w1 + 1e-16f);
            s_zinv[2] = 1.f / (z2 + w2 + 1e-16f);
            s_zinv[3] = 1.f / (z3 + w3 + 1e-16f);
        }
    }
    __syncthreads();

    // Phase B
    int hh4  = t & 3;         // head for alpha compute
    int eloc = t >> 2;        // edge slot in chunk (0..31)
    int c    = t & 31;        // channel-group lane (channels 4c..4c+3)
    int g    = t >> 5;        // edge group (0..3)
    int head = c >> 3;        // head for accumulation
    float adh_c = a_d[d * 4 + hh4];
    float m_c   = s_m[hh4];
    float4 acc = {0.f, 0.f, 0.f, 0.f};
    for (int j0 = 0; j0 < cnt; j0 += 32) {
        int nedge = min(32, cnt - j0);
        __syncthreads();
        if (eloc < nedge) {
            int s = colsrc[beg + j0 + eloc];
            if (hh4 == 0) s_src[eloc] = s;
            float e = lrelu(a_s[s * 4 + hh4] + adh_c);
            s_alpha[eloc * 4 + hh4] = __expf(e - m_c);
        }
        __syncthreads();
        for (int j = g; j < nedge; j += 4) {
            int s = s_src[j];
            float a = s_alpha[j * 4 + head];
            float4 hv = load_bf16x4(&h[s * 128 + c * 4]);
            acc.x += a * hv.x; acc.y += a * hv.y;
            acc.z += a * hv.z; acc.w += a * hv.w;
        }
    }
    *(float4*)&s_red[(g * 32 + c) * 4] = acc;
    __syncthreads();
    // thread t owns channel t
    float tot = s_red[t] + s_red[128 + t] + s_red[256 + t] + s_red[384 + t];
    int hd_head = t >> 5;
    tot += s_ws[hd_head] * bf2f(h[d * 128 + t]);          // self-loop
    tot = tot * s_zinv[hd_head] + bias[t];
    *(unsigned short*)&out[d * 128 + t] = f2bf(fmaxf(tot, 0.f));
}

// ---------------- GraphConv aggregation: agg[d] = sum_{src->d} x[src], 128 ch ------
__global__ __launch_bounds__(128) void sum_aggr128(
    const __hip_bfloat16* __restrict__ x, const int* __restrict__ rowptr,
    const int* __restrict__ colsrc, float* __restrict__ agg, int n)
{
    __shared__ float s_red[4 * 128];
    int d = blockIdx.x;
    int t = threadIdx.x;
    int c = t & 31, g = t >> 5;
    int beg = rowptr[d], end = rowptr[d + 1];
    float4 acc = {0.f, 0.f, 0.f, 0.f};
    for (int j = beg + g; j < end; j += 4) {
        int s = colsrc[j];
        float4 v = load_bf16x4(&x[s * 128 + c * 4]);
        acc.x += v.x; acc.y += v.y; acc.z += v.z; acc.w += v.w;
    }
    *(float4*)&s_red[(g * 32 + c) * 4] = acc;
    __syncthreads();
    agg[d * 128 + t] = s_red[t] + s_red[128 + t] + s_red[256 + t] + s_red[384 + t];
}

// ---------------- GraphConv GEMM: out = relu(agg@Wr + b + x@Wl), 128->32 (bf16 out)
__global__ __launch_bounds__(256) void graphconv_gemm(
    const float* __restrict__ agg, const __hip_bfloat16* __restrict__ xin,
    const float* __restrict__ Wr, const float* __restrict__ Wl,
    const float* __restrict__ bias, __hip_bfloat16* __restrict__ out, int n)
{
    __shared__ __align__(16) float sWr[128 * 32], sWl[128 * 32];
    __shared__ __align__(16) float sa[8 * 128], sx[8 * 128];
    int t = threadIdx.x;
    for (int i = t; i < 128 * 32; i += 256) { sWr[i] = Wr[i]; sWl[i] = Wl[i]; }
    int c = t & 31, rr = t >> 5;
    float bc = bias[c];
    for (int row0 = blockIdx.x * 8; row0 < n; row0 += gridDim.x * 8) {
        __syncthreads();
        for (int i = t; i < 8 * 128; i += 256) {
            int r = i >> 7, cc = i & 127;
            int row = row0 + r;
            sa[i] = (row < n) ? agg[row * 128 + cc] : 0.f;
        }
        for (int i = t; i < 8 * 64; i += 256) {
            int r = i >> 6, cp = i & 63;
            int row = row0 + r;
            float vx = 0.f, vy = 0.f;
            if (row < n) {
                ushort2 u = *(const ushort2*)&xin[row * 128 + cp * 2];
                vx = __uint_as_float((unsigned)u.x << 16);
                vy = __uint_as_float((unsigned)u.y << 16);
            }
            sx[r * 128 + cp * 2]     = vx;
            sx[r * 128 + cp * 2 + 1] = vy;
        }
        __syncthreads();
        float acc = bc;
        const float4* pa = (const float4*)&sa[rr * 128];
        const float4* px = (const float4*)&sx[rr * 128];
        #pragma unroll 8
        for (int k4 = 0; k4 < 32; ++k4) {
            float4 va = pa[k4], vx = px[k4];
            const float* wr = &sWr[(k4 * 4) * 32 + c];
            const float* wl = &sWl[(k4 * 4) * 32 + c];
            acc += va.x * wr[0] + va.y * wr[32] + va.z * wr[64] + va.w * wr[96];
            acc += vx.x * wl[0] + vx.y * wl[32] + vx.z * wl[64] + vx.w * wl[96];
        }
        int row = row0 + rr;
        if (row < n) *(unsigned short*)&out[row * 32 + c] = f2bf(fmaxf(acc, 0.f));
    }
}

// ---------------- SAGE mean aggregation, 32 ch, bf16 in / fp32 out ----------------
__global__ __launch_bounds__(128) void mean_aggr32(
    const __hip_bfloat16* __restrict__ x, const int* __restrict__ rowptr,
    const int* __restrict__ colsrc, float* __restrict__ mean, int n)
{
    int d = blockIdx.x * 4 + (threadIdx.x >> 5);
    if (d >= n) return;
    int lane = threadIdx.x & 31;
    int c = lane & 7;        // channels 4c..4c+3
    int g = lane >> 3;       // edge offset 0..3
    int beg = rowptr[d], end = rowptr[d + 1];
    float4 acc = {0.f, 0.f, 0.f, 0.f};
    for (int j = beg + g; j < end; j += 4) {
        int s = colsrc[j];
        float4 v = load_bf16x4(&x[s * 32 + c * 4]);
        acc.x += v.x; acc.y += v.y; acc.z += v.z; acc.w += v.w;
    }
    acc.x += __shfl_xor(acc.x, 8);  acc.y += __shfl_xor(acc.y, 8);
    acc.z += __shfl_xor(acc.z, 8);  acc.w += __shfl_xor(acc.w, 8);
    acc.x += __shfl_xor(acc.x, 16); acc.y += __shfl_xor(acc.y, 16);
    acc.z += __shfl_xor(acc.z, 16); acc.w += __shfl_xor(acc.w, 16);
    if (g == 0) {
        float invd = 1.f / fmaxf((float)(end - beg), 1.f);
        acc.x *= invd; acc.y *= invd; acc.z *= invd; acc.w *= invd;
        *(float4*)&mean[d * 32 + c * 4] = acc;
    }
}

// ---------------- SAGE GEMM: out = relu(mean@Wl + bl + x@Wr), 32->32 --------------
__global__ __launch_bounds__(256) void sage_gemm(
    const float* __restrict__ mean, const __hip_bfloat16* __restrict__ xin,
    const float* __restrict__ Wl, const float* __restrict__ bl,
    const float* __restrict__ Wr, float* __restrict__ out, int n)
{
    __shared__ __align__(16) float sWl[32 * 32], sWr[32 * 32];
    __shared__ __align__(16) float sm[8 * 32], sx[8 * 32];
    int t = threadIdx.x;
    for (int i = t; i < 1024; i += 256) { sWl[i] = Wl[i]; sWr[i] = Wr[i]; }
    int c = t & 31, rr = t >> 5;
    float bc = bl[c];
    for (int row0 = blockIdx.x * 8; row0 < n; row0 += gridDim.x * 8) {
        __syncthreads();
        {
            int i = t;
            int r = i >> 5, cc = i & 31;
            int row = row0 + r;
            sm[i] = (row < n) ? mean[row * 32 + cc] : 0.f;
            sx[i] = (row < n) ? bf2f(xin[row * 32 + cc]) : 0.f;
        }
        __syncthreads();
        float acc = bc;
        const float4* pm = (const float4*)&sm[rr * 32];
        const float4* px = (const float4*)&sx[rr * 32];
        #pragma unroll
        for (int k4 = 0; k4 < 8; ++k4) {
            float4 vm = pm[k4], vx = px[k4];
            const float* wl = &sWl[(k4 * 4) * 32 + c];
            const float* wr = &sWr[(k4 * 4) * 32 + c];
            acc += vm.x * wl[0] + vm.y * wl[32] + vm.z * wl[64] + vm.w * wl[96];
            acc += vx.x * wr[0] + vx.y * wr[32] + vx.z * wr[64] + vx.w * wr[96];
        }
        int row = row0 + rr;
        if (row < n) out[row * 32 + c] = fmaxf(acc, 0.f);
    }
}

// ---------------- global mean pool (batch sorted) ----------------
__device__ __forceinline__ int lower_bound_i(const int* a, int n, int key) {
    int lo = 0, hi = n;
    while (lo < hi) { int mid = (lo + hi) >> 1; if (a[mid] < key) lo = mid + 1; else hi = mid; }
    return lo;
}

__global__ __launch_bounds__(256) void pool_kernel(
    const float* __restrict__ x, const int* __restrict__ batch,
    float* __restrict__ gpool, int n)
{
    int g = blockIdx.x;
    int lo = lower_bound_i(batch, n, g);
    int hi = lower_bound_i(batch, n, g + 1);
    int t = threadIdx.x;
    int c = t & 31, rr = t >> 5;
    float acc = 0.f;
    for (int i = lo + rr; i < hi; i += 8) acc += x[i * 32 + c];
    __shared__ float sred[256];
    sred[t] = acc;
    __syncthreads();
    if (t < 128) sred[t] += sred[t + 128];
    __syncthreads();
    if (t < 64) sred[t] += sred[t + 64];
    __syncthreads();
    if (t < 32) {
        float v = sred[t] + sred[t + 32];
        gpool[g * 32 + t] = v / fmaxf((float)(hi - lo), 1.f);
    }
}

// ---------------- MLP head ----------------
__global__ __launch_bounds__(256) void head_kernel(
    const float* __restrict__ gpool, const float* __restrict__ Wf1, const float* __restrict__ bf1,
    const float* __restrict__ Wf2, const float* __restrict__ bf2, float* __restrict__ out)
{
    __shared__ float sg[64 * 32], st[64 * 32];
    __shared__ float sW1[32 * 32], sW2[32 * 10];
    int t = threadIdx.x;
    for (int i = t; i < 2048; i += 256) sg[i] = gpool[i];
    for (int i = t; i < 1024; i += 256) sW1[i] = Wf1[i];
    for (int i = t; i < 320; i += 256) sW2[i] = Wf2[i];
    __syncthreads();
    for (int i = t; i < 2048; i += 256) {
        int g = i >> 5, c = i & 31;
        float acc = bf1[c];
        #pragma unroll
        for (int k = 0; k < 32; ++k) acc += sg[g * 32 + k] * sW1[k * 32 + c];
        st[i] = fmaxf(acc, 0.f);
    }
    __syncthreads();
    for (int i = t; i < 640; i += 256) {
        int g = i / 10, o = i - g * 10;
        float acc = bf2[o];
        #pragma unroll
        for (int k = 0; k < 32; ++k) acc += st[g * 32 + k] * sW2[k * 10 + o];
        out[i] = acc;
    }
}

extern "C" void kernel_launch(void* const* d_in, const int* in_sizes, int n_in,
                              void* d_out, int out_size, void* d_ws, size_t ws_size,
                              hipStream_t stream) {
    const float* x    = (const float*)d_in[0];
    const int*   ei   = (const int*)d_in[1];
    const int*   batch= (const int*)d_in[2];
    const float* W1   = (const float*)d_in[3];
    const float* as1  = (const float*)d_in[4];
    const float* ad1  = (const float*)d_in[5];
    const float* b1   = (const float*)d_in[6];
    const float* W2   = (const float*)d_in[7];
    const float* as2  = (const float*)d_in[8];
    const float* ad2  = (const float*)d_in[9];
    const float* b2   = (const float*)d_in[10];
    const float* W3r  = (const float*)d_in[11];
    const float* W3l  = (const float*)d_in[12];
    const float* b3   = (const float*)d_in[13];
    const float* W4l  = (const float*)d_in[14];
    const float* b4l  = (const float*)d_in[15];
    const float* W4r  = (const float*)d_in[16];
    const float* Wf1  = (const float*)d_in[17];
    const float* bf1  = (const float*)d_in[18];
    const float* Wf2  = (const float*)d_in[19];
    const float* bf2  = (const float*)d_in[20];

    const int N = in_sizes[0] / 128;
    const int E = in_sizes[1] / 2;
    const int* src = ei;
    const int* dst = ei + E;

    // workspace carve (256B aligned)
    char* p = (char*)d_ws;
    auto alloc = [&](size_t bytes) -> void* {
        void* r = (void*)p;
        p += (bytes + 255) & ~(size_t)255;
        return r;
    };
    __hip_bfloat16* Hb  = (__hip_bfloat16*)alloc((size_t)N * 128 * 2);  // h1/h2
    __hip_bfloat16* Xb  = (__hip_bfloat16*)alloc((size_t)N * 128 * 2);  // x1/x2
    float*          AGG = (float*)alloc((size_t)N * 128 * 4);           // graphconv agg
    __hip_bfloat16* X3b = (__hip_bfloat16*)alloc((size_t)N * 32 * 2);   // x3
    float*          MEAN= (float*)alloc((size_t)N * 32 * 4);
    float*          X4  = (float*)alloc((size_t)N * 32 * 4);
    float* aS     = (float*)alloc((size_t)N * 4 * 4);
    float* aD     = (float*)alloc((size_t)N * 4 * 4);
    int*   deg    = (int*)alloc((size_t)N * 4);
    int*   rowptr = (int*)alloc((size_t)(N + 1) * 4);
    int*   cur    = (int*)alloc((size_t)N * 4);
    int*   colsrc = (int*)alloc((size_t)E * 4);
    float* gpool  = (float*)alloc(64 * 32 * 4);

    // CSR build (reused by all 4 message-passing layers)
    hipMemsetAsync(deg, 0, (size_t)N * 4, stream);
    hist_kernel<<<(E + 255) / 256, 256, 0, stream>>>(dst, deg, E);
    scan_kernel<<<1, 1024, 0, stream>>>(deg, rowptr, cur, N, E);
    fill_kernel<<<(E + 255) / 256, 256, 0, stream>>>(src, dst, cur, colsrc, E);

    // GAT layer 1
    gemm_att<float><<<2048, 256, 0, stream>>>(x, W1, as1, ad1, Hb, aS, aD, N);
    gat_aggr<<<N, 128, 0, stream>>>(Hb, aS, aD, rowptr, colsrc, b1, Xb, N);
    // GAT layer 2
    gemm_att<__hip_bfloat16><<<2048, 256, 0, stream>>>(Xb, W2, as2, ad2, Hb, aS, aD, N);
    gat_aggr<<<N, 128, 0, stream>>>(Hb, aS, aD, rowptr, colsrc, b2, Xb, N);
    // GraphConv
    sum_aggr128<<<N, 128, 0, stream>>>(Xb, rowptr, colsrc, AGG, N);
    graphconv_gemm<<<1024, 256, 0, stream>>>(AGG, Xb, W3r, W3l, b3, X3b, N);
    // SAGE
    mean_aggr32<<<(N + 3) / 4, 128, 0, stream>>>(X3b, rowptr, colsrc, MEAN, N);
    sage_gemm<<<1024, 256, 0, stream>>>(MEAN, X3b, W4l, b4l, W4r, X4, N);
    // pool + head
    pool_kernel<<<64, 256, 0, stream>>>(X4, batch, gpool, N);
    head_kernel<<<1, 256, 0, stream>>>(gpool, Wf1, bf1, Wf2, bf2, (float*)d_out);
}

// Round 3
// 522.829 us; speedup vs baseline: 1.8053x; 1.4954x over previous
//
#include <hip/hip_runtime.h>
#include <hip/hip_bf16.h>

// GNN: GAT(128->4x32) -> GAT(128->4x32) -> GraphConv(128->32) -> SAGE(32->32)
//      -> global mean pool (64 graphs) -> MLP(32->32->10)
// R1: CSR gather aggregation, fp32.                         944 us
// R2: bf16 features + cooperative alpha.                    782 us
// R3: parallel 3-phase scan (113us -> ~6us) + MFMA bf16 GEMMs for
//     gemm_att and graphconv (LDS-issue-bound VALU -> matrix cores).

typedef __bf16 v8bf __attribute__((ext_vector_type(8)));
typedef float  v4f  __attribute__((ext_vector_type(4)));

__device__ __forceinline__ float lrelu(float x) { return x > 0.f ? x : 0.2f * x; }

__device__ __forceinline__ float bf2f(__hip_bfloat16 b) {
    unsigned short u = *(const unsigned short*)&b;
    return __uint_as_float((unsigned)u << 16);
}
__device__ __forceinline__ unsigned short f2bf(float f) {
    unsigned u = __float_as_uint(f);
    unsigned r = (u + 0x7FFF + ((u >> 16) & 1)) >> 16;   // RNE
    return (unsigned short)r;
}
__device__ __forceinline__ float4 load_bf16x4(const __hip_bfloat16* p) {
    ushort4 u = *(const ushort4*)p;
    float4 f;
    f.x = __uint_as_float((unsigned)u.x << 16);
    f.y = __uint_as_float((unsigned)u.y << 16);
    f.z = __uint_as_float((unsigned)u.z << 16);
    f.w = __uint_as_float((unsigned)u.w << 16);
    return f;
}

// ---------------- CSR build ----------------
__global__ void hist_kernel(const int* __restrict__ dst, int* __restrict__ deg, int E) {
    int e = blockIdx.x * 256 + threadIdx.x;
    if (e < E) atomicAdd(&deg[dst[e]], 1);
}

// phase 1: per-block (1024 elems) sums
__global__ __launch_bounds__(256) void scan_partial(const int* __restrict__ deg,
                                                    int* __restrict__ bsum, int n) {
    __shared__ int red[256];
    int t = threadIdx.x;
    int base = blockIdx.x * 1024 + t * 4;
    int s = 0;
    if (base + 3 < n) { int4 v = *(const int4*)&deg[base]; s = v.x + v.y + v.z + v.w; }
    else { for (int j = 0; j < 4; ++j) if (base + j < n) s += deg[base + j]; }
    red[t] = s;
    __syncthreads();
    for (int off = 128; off; off >>= 1) { if (t < off) red[t] += red[t + off]; __syncthreads(); }
    if (t == 0) bsum[blockIdx.x] = red[0];
}

// phase 2: scan <=64 block sums in one wave
__global__ __launch_bounds__(64) void scan_block(const int* __restrict__ bsum,
                                                 int* __restrict__ boff, int nb,
                                                 int* __restrict__ rowptr, int n) {
    int t = threadIdx.x;
    int s = (t < nb) ? bsum[t] : 0;
    int v = s;
    for (int off = 1; off < 64; off <<= 1) {
        int u = __shfl_up(v, off);
        if (t >= off) v += u;
    }
    if (t < nb) boff[t] = v - s;
    if (t == nb - 1) rowptr[n] = v;
}

// phase 3: per-block exclusive prefix -> rowptr/cur
__global__ __launch_bounds__(256) void scan_final(const int* __restrict__ deg,
                                                  const int* __restrict__ boff,
                                                  int* __restrict__ rowptr,
                                                  int* __restrict__ cur, int n) {
    __shared__ int red[256];
    int t = threadIdx.x;
    int base = blockIdx.x * 1024 + t * 4;
    int d0 = 0, d1 = 0, d2 = 0, d3 = 0;
    if (base + 3 < n) { int4 v = *(const int4*)&deg[base]; d0 = v.x; d1 = v.y; d2 = v.z; d3 = v.w; }
    else {
        if (base < n)     d0 = deg[base];
        if (base + 1 < n) d1 = deg[base + 1];
        if (base + 2 < n) d2 = deg[base + 2];
        if (base + 3 < n) d3 = deg[base + 3];
    }
    int s = d0 + d1 + d2 + d3;
    red[t] = s;
    __syncthreads();
    for (int off = 1; off < 256; off <<= 1) {
        int v = (t >= off) ? red[t - off] : 0;
        __syncthreads();
        red[t] += v;
        __syncthreads();
    }
    int pre = boff[blockIdx.x] + red[t] - s;
    if (base < n)     { rowptr[base]     = pre; cur[base]     = pre; } pre += d0;
    if (base + 1 < n) { rowptr[base + 1] = pre; cur[base + 1] = pre; } pre += d1;
    if (base + 2 < n) { rowptr[base + 2] = pre; cur[base + 2] = pre; }
    pre += d2;
    if (base + 3 < n) { rowptr[base + 3] = pre; cur[base + 3] = pre; }
}

__global__ void fill_kernel(const int* __restrict__ src, const int* __restrict__ dst,
                            int* __restrict__ cur, int* __restrict__ colsrc, int E) {
    int e = blockIdx.x * 256 + threadIdx.x;
    if (e < E) {
        int d = dst[e];
        int p = atomicAdd(&cur[d], 1);
        colsrc[p] = src[e];
    }
}

// ---------------- dtype prep ----------------
__global__ void convert_x(const float* __restrict__ x, __hip_bfloat16* __restrict__ xb, int total4) {
    int i = blockIdx.x * 256 + threadIdx.x;
    if (i < total4) {
        float4 v = *(const float4*)&x[i * 4];
        ushort4 u;
        u.x = f2bf(v.x); u.y = f2bf(v.y); u.z = f2bf(v.z); u.w = f2bf(v.w);
        *(ushort4*)&xb[i * 4] = u;
    }
}

// W[k][c] fp32 -> Wt[c][k] bf16
__global__ void convert_w_t(const float* __restrict__ W, __hip_bfloat16* __restrict__ Wt,
                            int K, int C) {
    int i = blockIdx.x * 256 + threadIdx.x;
    if (i >= K * C) return;
    int k = i / C, c = i - k * C;
    *(unsigned short*)&Wt[c * K + k] = f2bf(W[i]);
}

// ---------------- GAT GEMM via MFMA: h = X@W (bf16), a_s/a_d dots -----------------
// Block = 256 (4 waves); each wave computes one 16-row x 128-col strip.
__global__ __launch_bounds__(256) void gemm_att_mfma(
    const __hip_bfloat16* __restrict__ X, const __hip_bfloat16* __restrict__ Wt,
    const float* __restrict__ att_s, const float* __restrict__ att_d,
    __hip_bfloat16* __restrict__ h, float* __restrict__ a_s, float* __restrict__ a_d, int n)
{
    __shared__ __align__(16) __hip_bfloat16 sWt[128 * 136];   // [col][k], +8 pad
    int t = threadIdx.x;
    for (int i = t; i < 128 * 16; i += 256) {                 // 16B chunks
        int row = i >> 4, ch = i & 15;
        *(int4*)&sWt[row * 136 + ch * 8] = *(const int4*)&Wt[row * 128 + ch * 8];
    }
    __syncthreads();
    int wave = t >> 6, lane = t & 63, quad = lane >> 4, l16 = lane & 15;
    int rowbase = (blockIdx.x * 4 + wave) * 16;
    if (rowbase >= n) return;

    v8bf z;
    #pragma unroll
    for (int i = 0; i < 8; ++i) z[i] = (__bf16)0.f;
    int arow = rowbase + l16;
    bool ok = arow < n;
    const v8bf* px = (const v8bf*)(X + (size_t)(ok ? arow : 0) * 128);
    v8bf af[4];
    #pragma unroll
    for (int ks = 0; ks < 4; ++ks) af[ks] = ok ? px[ks * 4 + quad] : z;

    v4f acc[8];
    #pragma unroll
    for (int ct = 0; ct < 8; ++ct) acc[ct] = (v4f){0.f, 0.f, 0.f, 0.f};
    #pragma unroll
    for (int ct = 0; ct < 8; ++ct) {
        #pragma unroll
        for (int ks = 0; ks < 4; ++ks) {
            v8bf b = *(const v8bf*)&sWt[(ct * 16 + l16) * 136 + ks * 32 + quad * 8];
            acc[ct] = __builtin_amdgcn_mfma_f32_16x16x32_bf16(af[ks], b, acc[ct], 0, 0, 0);
        }
    }

    // attention partials: a_s[row,head] = sum_col h*att_s (head = col>>5)
    float sas[4][4], sad[4][4];
    #pragma unroll
    for (int r = 0; r < 4; ++r)
        #pragma unroll
        for (int hd = 0; hd < 4; ++hd) { sas[r][hd] = 0.f; sad[r][hd] = 0.f; }
    #pragma unroll
    for (int ct = 0; ct < 8; ++ct) {
        float sa = att_s[ct * 16 + l16];
        float da = att_d[ct * 16 + l16];
        int hd = ct >> 1;
        #pragma unroll
        for (int r = 0; r < 4; ++r) {
            float v = acc[ct][r];
            sas[r][hd] += v * sa;
            sad[r][hd] += v * da;
        }
    }
    // store h (bf16): C layout col=l16, row=quad*4+reg
    #pragma unroll
    for (int reg = 0; reg < 4; ++reg) {
        int r = rowbase + quad * 4 + reg;
        if (r < n) {
            #pragma unroll
            for (int ct = 0; ct < 8; ++ct)
                *(unsigned short*)&h[(size_t)r * 128 + ct * 16 + l16] = f2bf(acc[ct][reg]);
        }
    }
    // reduce dots over the 16 lanes sharing a row-quad
    #pragma unroll
    for (int off = 1; off < 16; off <<= 1) {
        #pragma unroll
        for (int r = 0; r < 4; ++r)
            #pragma unroll
            for (int hd = 0; hd < 4; ++hd) {
                sas[r][hd] += __shfl_xor(sas[r][hd], off);
                sad[r][hd] += __shfl_xor(sad[r][hd], off);
            }
    }
    if (l16 == 0) {
        #pragma unroll
        for (int reg = 0; reg < 4; ++reg) {
            int r = rowbase + quad * 4 + reg;
            if (r < n) {
                float4 vs = {sas[reg][0], sas[reg][1], sas[reg][2], sas[reg][3]};
                float4 vd = {sad[reg][0], sad[reg][1], sad[reg][2], sad[reg][3]};
                *(float4*)&a_s[r * 4] = vs;
                *(float4*)&a_d[r * 4] = vd;
            }
        }
    }
}

// ---------------- GAT: per-dst softmax + aggregation (incl. self-loop) -------------
__global__ __launch_bounds__(128) void gat_aggr(
    const __hip_bfloat16* __restrict__ h, const float* __restrict__ a_s,
    const float* __restrict__ a_d,
    const int* __restrict__ rowptr, const int* __restrict__ colsrc,
    const float* __restrict__ bias, __hip_bfloat16* __restrict__ out, int n)
{
    int d = blockIdx.x;
    int t = threadIdx.x;
    __shared__ float s_m[4], s_zinv[4], s_ws[4];
    __shared__ int   s_src[32];
    __shared__ float s_alpha[32 * 4];
    __shared__ float s_red[4 * 128];
    int beg = rowptr[d], end = rowptr[d + 1];
    int cnt = end - beg;

    if (t < 64) {
        float4 ad4 = *(const float4*)&a_d[d * 4];
        float4 av  = *(const float4*)&a_s[d * 4];
        float es0 = lrelu(av.x + ad4.x), es1 = lrelu(av.y + ad4.y);
        float es2 = lrelu(av.z + ad4.z), es3 = lrelu(av.w + ad4.w);
        float m0 = es0, m1 = es1, m2 = es2, m3 = es3;
        for (int j = t; j < cnt; j += 64) {
            int s = colsrc[beg + j];
            float4 sv = *(const float4*)&a_s[s * 4];
            m0 = fmaxf(m0, lrelu(sv.x + ad4.x));
            m1 = fmaxf(m1, lrelu(sv.y + ad4.y));
            m2 = fmaxf(m2, lrelu(sv.z + ad4.z));
            m3 = fmaxf(m3, lrelu(sv.w + ad4.w));
        }
        for (int off = 32; off; off >>= 1) {
            m0 = fmaxf(m0, __shfl_xor(m0, off));
            m1 = fmaxf(m1, __shfl_xor(m1, off));
            m2 = fmaxf(m2, __shfl_xor(m2, off));
            m3 = fmaxf(m3, __shfl_xor(m3, off));
        }
        float z0 = 0.f, z1 = 0.f, z2 = 0.f, z3 = 0.f;
        for (int j = t; j < cnt; j += 64) {
            int s = colsrc[beg + j];
            float4 sv = *(const float4*)&a_s[s * 4];
            z0 += __expf(lrelu(sv.x + ad4.x) - m0);
            z1 += __expf(lrelu(sv.y + ad4.y) - m1);
            z2 += __expf(lrelu(sv.z + ad4.z) - m2);
            z3 += __expf(lrelu(sv.w + ad4.w) - m3);
        }
        for (int off = 32; off; off >>= 1) {
            z0 += __shfl_xor(z0, off);
            z1 += __shfl_xor(z1, off);
            z2 += __shfl_xor(z2, off);
            z3 += __shfl_xor(z3, off);
        }
        if (t == 0) {
            float w0 = __expf(es0 - m0), w1 = __expf(es1 - m1);
            float w2 = __expf(es2 - m2), w3 = __expf(es3 - m3);
            s_m[0] = m0; s_m[1] = m1; s_m[2] = m2; s_m[3] = m3;
            s_ws[0] = w0; s_ws[1] = w1; s_ws[2] = w2; s_ws[3] = w3;
            s_zinv[0] = 1.f / (z0 + w0 + 1e-16f);
            s_zinv[1] = 1.f / (z1 + w1 + 1e-16f);
            s_zinv[2] = 1.f / (z2 + w2 + 1e-16f);
            s_zinv[3] = 1.f / (z3 + w3 + 1e-16f);
        }
    }
    __syncthreads();

    int hh4  = t & 3;
    int eloc = t >> 2;
    int c    = t & 31;
    int g    = t >> 5;
    int head = c >> 3;
    float adh_c = a_d[d * 4 + hh4];
    float m_c   = s_m[hh4];
    float4 acc = {0.f, 0.f, 0.f, 0.f};
    for (int j0 = 0; j0 < cnt; j0 += 32) {
        int nedge = min(32, cnt - j0);
        __syncthreads();
        if (eloc < nedge) {
            int s = colsrc[beg + j0 + eloc];
            if (hh4 == 0) s_src[eloc] = s;
            float e = lrelu(a_s[s * 4 + hh4] + adh_c);
            s_alpha[eloc * 4 + hh4] = __expf(e - m_c);
        }
        __syncthreads();
        for (int j = g; j < nedge; j += 4) {
            int s = s_src[j];
            float a = s_alpha[j * 4 + head];
            float4 hv = load_bf16x4(&h[(size_t)s * 128 + c * 4]);
            acc.x += a * hv.x; acc.y += a * hv.y;
            acc.z += a * hv.z; acc.w += a * hv.w;
        }
    }
    *(float4*)&s_red[(g * 32 + c) * 4] = acc;
    __syncthreads();
    float tot = s_red[t] + s_red[128 + t] + s_red[256 + t] + s_red[384 + t];
    int hd_head = t >> 5;
    tot += s_ws[hd_head] * bf2f(h[(size_t)d * 128 + t]);
    tot = tot * s_zinv[hd_head] + bias[t];
    *(unsigned short*)&out[(size_t)d * 128 + t] = f2bf(fmaxf(tot, 0.f));
}

// ---------------- GraphConv aggregation: agg[d] = sum x[src], 128ch, bf16 out ------
__global__ __launch_bounds__(128) void sum_aggr128(
    const __hip_bfloat16* __restrict__ x, const int* __restrict__ rowptr,
    const int* __restrict__ colsrc, __hip_bfloat16* __restrict__ agg, int n)
{
    __shared__ float s_red[4 * 128];
    int d = blockIdx.x;
    int t = threadIdx.x;
    int c = t & 31, g = t >> 5;
    int beg = rowptr[d], end = rowptr[d + 1];
    float4 acc = {0.f, 0.f, 0.f, 0.f};
    for (int j = beg + g; j < end; j += 4) {
        int s = colsrc[j];
        float4 v = load_bf16x4(&x[(size_t)s * 128 + c * 4]);
        acc.x += v.x; acc.y += v.y; acc.z += v.z; acc.w += v.w;
    }
    *(float4*)&s_red[(g * 32 + c) * 4] = acc;
    __syncthreads();
    float tot = s_red[t] + s_red[128 + t] + s_red[256 + t] + s_red[384 + t];
    *(unsigned short*)&agg[(size_t)d * 128 + t] = f2bf(tot);
}

// ---------------- GraphConv via MFMA: out = relu(agg@Wr + b + x@Wl), 128->32 -------
__global__ __launch_bounds__(256) void graphconv_mfma(
    const __hip_bfloat16* __restrict__ AGGb, const __hip_bfloat16* __restrict__ Xb,
    const __hip_bfloat16* __restrict__ Wrt, const __hip_bfloat16* __restrict__ Wlt,
    const float* __restrict__ bias, __hip_bfloat16* __restrict__ out, int n)
{
    __shared__ __align__(16) __hip_bfloat16 sWr[32 * 136], sWl[32 * 136];
    int t = threadIdx.x;
    for (int i = t; i < 32 * 16; i += 256) {
        int row = i >> 4, ch = i & 15;
        *(int4*)&sWr[row * 136 + ch * 8] = *(const int4*)&Wrt[row * 128 + ch * 8];
        *(int4*)&sWl[row * 136 + ch * 8] = *(const int4*)&Wlt[row * 128 + ch * 8];
    }
    __syncthreads();
    int wave = t >> 6, lane = t & 63, quad = lane >> 4, l16 = lane & 15;
    int rowbase = (blockIdx.x * 4 + wave) * 16;
    if (rowbase >= n) return;

    v8bf z;
    #pragma unroll
    for (int i = 0; i < 8; ++i) z[i] = (__bf16)0.f;
    int arow = rowbase + l16;
    bool ok = arow < n;
    const v8bf* pr = (const v8bf*)(AGGb + (size_t)(ok ? arow : 0) * 128);
    const v8bf* px = (const v8bf*)(Xb   + (size_t)(ok ? arow : 0) * 128);
    v8bf fr[4], fx[4];
    #pragma unroll
    for (int ks = 0; ks < 4; ++ks) {
        fr[ks] = ok ? pr[ks * 4 + quad] : z;
        fx[ks] = ok ? px[ks * 4 + quad] : z;
    }
    v4f acc[2];
    acc[0] = (v4f){0.f, 0.f, 0.f, 0.f};
    acc[1] = (v4f){0.f, 0.f, 0.f, 0.f};
    #pragma unroll
    for (int ct = 0; ct < 2; ++ct) {
        #pragma unroll
        for (int ks = 0; ks < 4; ++ks) {
            v8bf br = *(const v8bf*)&sWr[(ct * 16 + l16) * 136 + ks * 32 + quad * 8];
            acc[ct] = __builtin_amdgcn_mfma_f32_16x16x32_bf16(fr[ks], br, acc[ct], 0, 0, 0);
            v8bf bl = *(const v8bf*)&sWl[(ct * 16 + l16) * 136 + ks * 32 + quad * 8];
            acc[ct] = __builtin_amdgcn_mfma_f32_16x16x32_bf16(fx[ks], bl, acc[ct], 0, 0, 0);
        }
    }
    #pragma unroll
    for (int ct = 0; ct < 2; ++ct) {
        float bcol = bias[ct * 16 + l16];
        #pragma unroll
        for (int reg = 0; reg < 4; ++reg) {
            int r = rowbase + quad * 4 + reg;
            if (r < n)
                *(unsigned short*)&out[(size_t)r * 32 + ct * 16 + l16] =
                    f2bf(fmaxf(acc[ct][reg] + bcol, 0.f));
        }
    }
}

// ---------------- SAGE mean aggregation, 32 ch, bf16 in / fp32 out ----------------
__global__ __launch_bounds__(128) void mean_aggr32(
    const __hip_bfloat16* __restrict__ x, const int* __restrict__ rowptr,
    const int* __restrict__ colsrc, float* __restrict__ mean, int n)
{
    int d = blockIdx.x * 4 + (threadIdx.x >> 5);
    if (d >= n) return;
    int lane = threadIdx.x & 31;
    int c = lane & 7;
    int g = lane >> 3;
    int beg = rowptr[d], end = rowptr[d + 1];
    float4 acc = {0.f, 0.f, 0.f, 0.f};
    for (int j = beg + g; j < end; j += 4) {
        int s = colsrc[j];
        float4 v = load_bf16x4(&x[(size_t)s * 32 + c * 4]);
        acc.x += v.x; acc.y += v.y; acc.z += v.z; acc.w += v.w;
    }
    acc.x += __shfl_xor(acc.x, 8);  acc.y += __shfl_xor(acc.y, 8);
    acc.z += __shfl_xor(acc.z, 8);  acc.w += __shfl_xor(acc.w, 8);
    acc.x += __shfl_xor(acc.x, 16); acc.y += __shfl_xor(acc.y, 16);
    acc.z += __shfl_xor(acc.z, 16); acc.w += __shfl_xor(acc.w, 16);
    if (g == 0) {
        float invd = 1.f / fmaxf((float)(end - beg), 1.f);
        acc.x *= invd; acc.y *= invd; acc.z *= invd; acc.w *= invd;
        *(float4*)&mean[(size_t)d * 32 + c * 4] = acc;
    }
}

// ---------------- SAGE GEMM: out = relu(mean@Wl + bl + x@Wr), 32->32 --------------
__global__ __launch_bounds__(256) void sage_gemm(
    const float* __restrict__ mean, const __hip_bfloat16* __restrict__ xin,
    const float* __restrict__ Wl, const float* __restrict__ bl,
    const float* __restrict__ Wr, float* __restrict__ out, int n)
{
    __shared__ __align__(16) float sWl[32 * 32], sWr[32 * 32];
    __shared__ __align__(16) float sm[8 * 32], sx[8 * 32];
    int t = threadIdx.x;
    for (int i = t; i < 1024; i += 256) { sWl[i] = Wl[i]; sWr[i] = Wr[i]; }
    int c = t & 31, rr = t >> 5;
    float bc = bl[c];
    for (int row0 = blockIdx.x * 8; row0 < n; row0 += gridDim.x * 8) {
        __syncthreads();
        {
            int i = t;
            int r = i >> 5, cc = i & 31;
            int row = row0 + r;
            sm[i] = (row < n) ? mean[row * 32 + cc] : 0.f;
            sx[i] = (row < n) ? bf2f(xin[row * 32 + cc]) : 0.f;
        }
        __syncthreads();
        float acc = bc;
        const float4* pm = (const float4*)&sm[rr * 32];
        const float4* px = (const float4*)&sx[rr * 32];
        #pragma unroll
        for (int k4 = 0; k4 < 8; ++k4) {
            float4 vm = pm[k4], vx = px[k4];
            const float* wl = &sWl[(k4 * 4) * 32 + c];
            const float* wr = &sWr[(k4 * 4) * 32 + c];
            acc += vm.x * wl[0] + vm.y * wl[32] + vm.z * wl[64] + vm.w * wl[96];
            acc += vx.x * wr[0] + vx.y * wr[32] + vx.z * wr[64] + vx.w * wr[96];
        }
        int row = row0 + rr;
        if (row < n) out[row * 32 + c] = fmaxf(acc, 0.f);
    }
}

// ---------------- global mean pool (batch sorted) ----------------
__device__ __forceinline__ int lower_bound_i(const int* a, int n, int key) {
    int lo = 0, hi = n;
    while (lo < hi) { int mid = (lo + hi) >> 1; if (a[mid] < key) lo = mid + 1; else hi = mid; }
    return lo;
}

__global__ __launch_bounds__(256) void pool_kernel(
    const float* __restrict__ x, const int* __restrict__ batch,
    float* __restrict__ gpool, int n)
{
    int g = blockIdx.x;
    int lo = lower_bound_i(batch, n, g);
    int hi = lower_bound_i(batch, n, g + 1);
    int t = threadIdx.x;
    int c = t & 31, rr = t >> 5;
    float acc = 0.f;
    for (int i = lo + rr; i < hi; i += 8) acc += x[i * 32 + c];
    __shared__ float sred[256];
    sred[t] = acc;
    __syncthreads();
    if (t < 128) sred[t] += sred[t + 128];
    __syncthreads();
    if (t < 64) sred[t] += sred[t + 64];
    __syncthreads();
    if (t < 32) {
        float v = sred[t] + sred[t + 32];
        gpool[g * 32 + t] = v / fmaxf((float)(hi - lo), 1.f);
    }
}

// ---------------- MLP head ----------------
__global__ __launch_bounds__(256) void head_kernel(
    const float* __restrict__ gpool, const float* __restrict__ Wf1, const float* __restrict__ bf1,
    const float* __restrict__ Wf2, const float* __restrict__ bf2, float* __restrict__ out)
{
    __shared__ float sg[64 * 32], st[64 * 32];
    __shared__ float sW1[32 * 32], sW2[32 * 10];
    int t = threadIdx.x;
    for (int i = t; i < 2048; i += 256) sg[i] = gpool[i];
    for (int i = t; i < 1024; i += 256) sW1[i] = Wf1[i];
    for (int i = t; i < 320; i += 256) sW2[i] = Wf2[i];
    __syncthreads();
    for (int i = t; i < 2048; i += 256) {
        int g = i >> 5, c = i & 31;
        float acc = bf1[c];
        #pragma unroll
        for (int k = 0; k < 32; ++k) acc += sg[g * 32 + k] * sW1[k * 32 + c];
        st[i] = fmaxf(acc, 0.f);
    }
    __syncthreads();
    for (int i = t; i < 640; i += 256) {
        int g = i / 10, o = i - g * 10;
        float acc = bf2[o];
        #pragma unroll
        for (int k = 0; k < 32; ++k) acc += st[g * 32 + k] * sW2[k * 10 + o];
        out[i] = acc;
    }
}

extern "C" void kernel_launch(void* const* d_in, const int* in_sizes, int n_in,
                              void* d_out, int out_size, void* d_ws, size_t ws_size,
                              hipStream_t stream) {
    const float* x    = (const float*)d_in[0];
    const int*   ei   = (const int*)d_in[1];
    const int*   batch= (const int*)d_in[2];
    const float* W1   = (const float*)d_in[3];
    const float* as1  = (const float*)d_in[4];
    const float* ad1  = (const float*)d_in[5];
    const float* b1   = (const float*)d_in[6];
    const float* W2   = (const float*)d_in[7];
    const float* as2  = (const float*)d_in[8];
    const float* ad2  = (const float*)d_in[9];
    const float* b2   = (const float*)d_in[10];
    const float* W3r  = (const float*)d_in[11];
    const float* W3l  = (const float*)d_in[12];
    const float* b3   = (const float*)d_in[13];
    const float* W4l  = (const float*)d_in[14];
    const float* b4l  = (const float*)d_in[15];
    const float* W4r  = (const float*)d_in[16];
    const float* Wf1  = (const float*)d_in[17];
    const float* bf1  = (const float*)d_in[18];
    const float* Wf2  = (const float*)d_in[19];
    const float* bf2  = (const float*)d_in[20];

    const int N = in_sizes[0] / 128;
    const int E = in_sizes[1] / 2;
    const int* src = ei;
    const int* dst = ei + E;

    char* p = (char*)d_ws;
    auto alloc = [&](size_t bytes) -> void* {
        void* r = (void*)p;
        p += (bytes + 255) & ~(size_t)255;
        return r;
    };
    __hip_bfloat16* buf1 = (__hip_bfloat16*)alloc((size_t)N * 128 * 2);  // xb / x2 / X4
    __hip_bfloat16* buf2 = (__hip_bfloat16*)alloc((size_t)N * 128 * 2);  // x1 / x3+mean
    __hip_bfloat16* buf3 = (__hip_bfloat16*)alloc((size_t)N * 128 * 2);  // h1,h2 / aggb
    float* aS     = (float*)alloc((size_t)N * 4 * 4);
    float* aD     = (float*)alloc((size_t)N * 4 * 4);
    int*   deg    = (int*)alloc((size_t)N * 4);
    int*   rowptr = (int*)alloc((size_t)(N + 1) * 4);
    int*   cur    = (int*)alloc((size_t)N * 4);
    int*   colsrc = (int*)alloc((size_t)E * 4);
    int*   bsum   = (int*)alloc(64 * 4);
    int*   boff   = (int*)alloc(64 * 4);
    __hip_bfloat16* W1t  = (__hip_bfloat16*)alloc(128 * 128 * 2);
    __hip_bfloat16* W2t  = (__hip_bfloat16*)alloc(128 * 128 * 2);
    __hip_bfloat16* W3rt = (__hip_bfloat16*)alloc(32 * 128 * 2);
    __hip_bfloat16* W3lt = (__hip_bfloat16*)alloc(32 * 128 * 2);
    float* gpool  = (float*)alloc(64 * 32 * 4);

    // aliased views
    __hip_bfloat16* X3b  = buf2;                                        // N*32 bf16
    float*          MEAN = (float*)((char*)buf2 + (((size_t)N * 32 * 2 + 255) & ~(size_t)255));
    float*          X4   = (float*)buf1;                                // N*32 fp32

    const int nb = (N + 1023) / 1024;

    // CSR build
    hipMemsetAsync(deg, 0, (size_t)N * 4, stream);
    hist_kernel<<<(E + 255) / 256, 256, 0, stream>>>(dst, deg, E);
    scan_partial<<<nb, 256, 0, stream>>>(deg, bsum, N);
    scan_block<<<1, 64, 0, stream>>>(bsum, boff, nb, rowptr, N);
    scan_final<<<nb, 256, 0, stream>>>(deg, boff, rowptr, cur, N);
    fill_kernel<<<(E + 255) / 256, 256, 0, stream>>>(src, dst, cur, colsrc, E);

    // dtype prep
    convert_x<<<(N * 32 + 255) / 256, 256, 0, stream>>>(x, buf1, N * 32);
    convert_w_t<<<(128 * 128 + 255) / 256, 256, 0, stream>>>(W1, W1t, 128, 128);
    convert_w_t<<<(128 * 128 + 255) / 256, 256, 0, stream>>>(W2, W2t, 128, 128);
    convert_w_t<<<(128 * 32 + 255) / 256, 256, 0, stream>>>(W3r, W3rt, 128, 32);
    convert_w_t<<<(128 * 32 + 255) / 256, 256, 0, stream>>>(W3l, W3lt, 128, 32);

    const int gmm = (N + 63) / 64;
    // GAT layer 1
    gemm_att_mfma<<<gmm, 256, 0, stream>>>(buf1, W1t, as1, ad1, buf3, aS, aD, N);
    gat_aggr<<<N, 128, 0, stream>>>(buf3, aS, aD, rowptr, colsrc, b1, buf2, N);
    // GAT layer 2
    gemm_att_mfma<<<gmm, 256, 0, stream>>>(buf2, W2t, as2, ad2, buf3, aS, aD, N);
    gat_aggr<<<N, 128, 0, stream>>>(buf3, aS, aD, rowptr, colsrc, b2, buf1, N);
    // GraphConv
    sum_aggr128<<<N, 128, 0, stream>>>(buf1, rowptr, colsrc, buf3, N);
    graphconv_mfma<<<gmm, 256, 0, stream>>>(buf3, buf1, W3rt, W3lt, b3, X3b, N);
    // SAGE
    mean_aggr32<<<(N + 3) / 4, 128, 0, stream>>>(X3b, rowptr, colsrc, MEAN, N);
    sage_gemm<<<1024, 256, 0, stream>>>(MEAN, X3b, W4l, b4l, W4r, X4, N);
    // pool + head
    pool_kernel<<<64, 256, 0, stream>>>(X4, batch, gpool, N);
    head_kernel<<<1, 256, 0, stream>>>(gpool, Wf1, bf1, Wf2, bf2, (float*)d_out);
}

// Round 5
// 459.728 us; speedup vs baseline: 2.0531x; 1.1373x over previous
//
#include <hip/hip_runtime.h>
#include <hip/hip_bf16.h>
#include <type_traits>

// GNN: GAT(128->4x32) -> GAT(128->4x32) -> GraphConv(128->32) -> SAGE(32->32)
//      -> global mean pool (64 graphs) -> MLP(32->32->10)
// R1: CSR gather aggregation, fp32.                         944 us
// R2: bf16 features + cooperative alpha.                    782 us
// R3: parallel scan + MFMA bf16 GEMMs.                      523 us
// R4: wave-per-dst single-pass aggr — FAILED: __shfl from exec-inactive lane
//     (divergent trip counts per quarter-wave) returned garbage src indices.
// R5: fix = uniform trip count + clamped shuffle index + predicated load.

typedef __bf16 v8bf __attribute__((ext_vector_type(8)));
typedef float  v4f  __attribute__((ext_vector_type(4)));

__device__ __forceinline__ float lrelu(float x) { return x > 0.f ? x : 0.2f * x; }

__device__ __forceinline__ float bf2f(__hip_bfloat16 b) {
    unsigned short u = *(const unsigned short*)&b;
    return __uint_as_float((unsigned)u << 16);
}
__device__ __forceinline__ unsigned short f2bf(float f) {
    unsigned u = __float_as_uint(f);
    unsigned r = (u + 0x7FFF + ((u >> 16) & 1)) >> 16;   // RNE
    return (unsigned short)r;
}
__device__ __forceinline__ float bflo(int v) { return __uint_as_float((unsigned)v << 16); }
__device__ __forceinline__ float bfhi(int v) { return __uint_as_float((unsigned)v & 0xffff0000u); }
__device__ __forceinline__ int packbf2(float a, float b) {
    return (int)f2bf(a) | ((int)f2bf(b) << 16);
}

// ---------------- CSR build ----------------
__global__ void hist_kernel(const int* __restrict__ dst, int* __restrict__ deg, int E) {
    int e = blockIdx.x * 256 + threadIdx.x;
    if (e < E) atomicAdd(&deg[dst[e]], 1);
}

__global__ __launch_bounds__(256) void scan_partial(const int* __restrict__ deg,
                                                    int* __restrict__ bsum, int n) {
    __shared__ int red[256];
    int t = threadIdx.x;
    int base = blockIdx.x * 1024 + t * 4;
    int s = 0;
    if (base + 3 < n) { int4 v = *(const int4*)&deg[base]; s = v.x + v.y + v.z + v.w; }
    else { for (int j = 0; j < 4; ++j) if (base + j < n) s += deg[base + j]; }
    red[t] = s;
    __syncthreads();
    for (int off = 128; off; off >>= 1) { if (t < off) red[t] += red[t + off]; __syncthreads(); }
    if (t == 0) bsum[blockIdx.x] = red[0];
}

__global__ __launch_bounds__(64) void scan_block(const int* __restrict__ bsum,
                                                 int* __restrict__ boff, int nb,
                                                 int* __restrict__ rowptr, int n) {
    int t = threadIdx.x;
    int s = (t < nb) ? bsum[t] : 0;
    int v = s;
    for (int off = 1; off < 64; off <<= 1) {
        int u = __shfl_up(v, off);
        if (t >= off) v += u;
    }
    if (t < nb) boff[t] = v - s;
    if (t == nb - 1) rowptr[n] = v;
}

__global__ __launch_bounds__(256) void scan_final(const int* __restrict__ deg,
                                                  const int* __restrict__ boff,
                                                  int* __restrict__ rowptr,
                                                  int* __restrict__ cur, int n) {
    __shared__ int red[256];
    int t = threadIdx.x;
    int base = blockIdx.x * 1024 + t * 4;
    int d0 = 0, d1 = 0, d2 = 0, d3 = 0;
    if (base + 3 < n) { int4 v = *(const int4*)&deg[base]; d0 = v.x; d1 = v.y; d2 = v.z; d3 = v.w; }
    else {
        if (base < n)     d0 = deg[base];
        if (base + 1 < n) d1 = deg[base + 1];
        if (base + 2 < n) d2 = deg[base + 2];
        if (base + 3 < n) d3 = deg[base + 3];
    }
    int s = d0 + d1 + d2 + d3;
    red[t] = s;
    __syncthreads();
    for (int off = 1; off < 256; off <<= 1) {
        int v = (t >= off) ? red[t - off] : 0;
        __syncthreads();
        red[t] += v;
        __syncthreads();
    }
    int pre = boff[blockIdx.x] + red[t] - s;
    if (base < n)     { rowptr[base]     = pre; cur[base]     = pre; } pre += d0;
    if (base + 1 < n) { rowptr[base + 1] = pre; cur[base + 1] = pre; } pre += d1;
    if (base + 2 < n) { rowptr[base + 2] = pre; cur[base + 2] = pre; }
    pre += d2;
    if (base + 3 < n) { rowptr[base + 3] = pre; cur[base + 3] = pre; }
}

__global__ void fill_kernel(const int* __restrict__ src, const int* __restrict__ dst,
                            int* __restrict__ cur, int* __restrict__ colsrc, int E) {
    int e = blockIdx.x * 256 + threadIdx.x;
    if (e < E) {
        int d = dst[e];
        int p = atomicAdd(&cur[d], 1);
        colsrc[p] = src[e];
    }
}

// ---------------- dtype prep: W[k][c] fp32 -> Wt[c][k] bf16 ----------------
__global__ void convert_w_t(const float* __restrict__ W, __hip_bfloat16* __restrict__ Wt,
                            int K, int C) {
    int i = blockIdx.x * 256 + threadIdx.x;
    if (i >= K * C) return;
    int k = i / C, c = i - k * C;
    *(unsigned short*)&Wt[c * K + k] = f2bf(W[i]);
}

// ---------------- GAT GEMM via MFMA: h = X@W (bf16), a_s/a_d dots -----------------
template <typename T>
__global__ __launch_bounds__(256) void gemm_att_mfma(
    const T* __restrict__ X, const __hip_bfloat16* __restrict__ Wt,
    const float* __restrict__ att_s, const float* __restrict__ att_d,
    __hip_bfloat16* __restrict__ h, float* __restrict__ a_s, float* __restrict__ a_d, int n)
{
    __shared__ __align__(16) __hip_bfloat16 sWt[128 * 136];   // [col][k], +8 pad
    int t = threadIdx.x;
    for (int i = t; i < 128 * 16; i += 256) {
        int row = i >> 4, ch = i & 15;
        *(int4*)&sWt[row * 136 + ch * 8] = *(const int4*)&Wt[row * 128 + ch * 8];
    }
    __syncthreads();
    int wave = t >> 6, lane = t & 63, quad = lane >> 4, l16 = lane & 15;
    int rowbase = (blockIdx.x * 4 + wave) * 16;
    if (rowbase >= n) return;

    v8bf z;
    #pragma unroll
    for (int i = 0; i < 8; ++i) z[i] = (__bf16)0.f;
    int arow = rowbase + l16;
    bool ok = arow < n;
    v8bf af[4];
    if constexpr (std::is_same<T, float>::value) {
        const float* xf = X + (size_t)(ok ? arow : 0) * 128;
        #pragma unroll
        for (int ks = 0; ks < 4; ++ks) {
            if (ok) {
                float4 u = *(const float4*)&xf[ks * 32 + quad * 8];
                float4 v = *(const float4*)&xf[ks * 32 + quad * 8 + 4];
                v8bf a;
                unsigned short r;
                r = f2bf(u.x); a[0] = *(__bf16*)&r;
                r = f2bf(u.y); a[1] = *(__bf16*)&r;
                r = f2bf(u.z); a[2] = *(__bf16*)&r;
                r = f2bf(u.w); a[3] = *(__bf16*)&r;
                r = f2bf(v.x); a[4] = *(__bf16*)&r;
                r = f2bf(v.y); a[5] = *(__bf16*)&r;
                r = f2bf(v.z); a[6] = *(__bf16*)&r;
                r = f2bf(v.w); a[7] = *(__bf16*)&r;
                af[ks] = a;
            } else af[ks] = z;
        }
    } else {
        const v8bf* px = (const v8bf*)(X + (size_t)(ok ? arow : 0) * 128);
        #pragma unroll
        for (int ks = 0; ks < 4; ++ks) af[ks] = ok ? px[ks * 4 + quad] : z;
    }

    v4f acc[8];
    #pragma unroll
    for (int ct = 0; ct < 8; ++ct) acc[ct] = (v4f){0.f, 0.f, 0.f, 0.f};
    #pragma unroll
    for (int ct = 0; ct < 8; ++ct) {
        #pragma unroll
        for (int ks = 0; ks < 4; ++ks) {
            v8bf b = *(const v8bf*)&sWt[(ct * 16 + l16) * 136 + ks * 32 + quad * 8];
            acc[ct] = __builtin_amdgcn_mfma_f32_16x16x32_bf16(af[ks], b, acc[ct], 0, 0, 0);
        }
    }

    float sas[4][4], sad[4][4];
    #pragma unroll
    for (int r = 0; r < 4; ++r)
        #pragma unroll
        for (int hd = 0; hd < 4; ++hd) { sas[r][hd] = 0.f; sad[r][hd] = 0.f; }
    #pragma unroll
    for (int ct = 0; ct < 8; ++ct) {
        float sa = att_s[ct * 16 + l16];
        float da = att_d[ct * 16 + l16];
        int hd = ct >> 1;
        #pragma unroll
        for (int r = 0; r < 4; ++r) {
            float v = acc[ct][r];
            sas[r][hd] += v * sa;
            sad[r][hd] += v * da;
        }
    }
    #pragma unroll
    for (int reg = 0; reg < 4; ++reg) {
        int r = rowbase + quad * 4 + reg;
        if (r < n) {
            #pragma unroll
            for (int ct = 0; ct < 8; ++ct)
                *(unsigned short*)&h[(size_t)r * 128 + ct * 16 + l16] = f2bf(acc[ct][reg]);
        }
    }
    #pragma unroll
    for (int off = 1; off < 16; off <<= 1) {
        #pragma unroll
        for (int r = 0; r < 4; ++r)
            #pragma unroll
            for (int hd = 0; hd < 4; ++hd) {
                sas[r][hd] += __shfl_xor(sas[r][hd], off);
                sad[r][hd] += __shfl_xor(sad[r][hd], off);
            }
    }
    if (l16 == 0) {
        #pragma unroll
        for (int reg = 0; reg < 4; ++reg) {
            int r = rowbase + quad * 4 + reg;
            if (r < n) {
                float4 vs = {sas[reg][0], sas[reg][1], sas[reg][2], sas[reg][3]};
                float4 vd = {sad[reg][0], sad[reg][1], sad[reg][2], sad[reg][3]};
                *(float4*)&a_s[r * 4] = vs;
                *(float4*)&a_d[r * 4] = vd;
            }
        }
    }
}

// ---------------- GAT: wave-per-dst fused online-softmax aggregation --------------
// Block = 256 = 4 waves, one dst per wave. Single pass over edges.
// All shuffles execute with FULL exec (uniform trip counts, clamped indices);
// only the gather+FMA is predicated on j < ne.
__global__ __launch_bounds__(256) void gat_aggr(
    const __hip_bfloat16* __restrict__ h, const float* __restrict__ a_s,
    const float* __restrict__ a_d,
    const int* __restrict__ rowptr, const int* __restrict__ colsrc,
    const float* __restrict__ bias, __hip_bfloat16* __restrict__ out, int n)
{
    __shared__ float s_w[4][64 * 4];
    int t = threadIdx.x;
    int wave = t >> 6, lane = t & 63;
    int d = blockIdx.x * 4 + wave;
    if (d >= n) d = n - 1;                         // duplicate work, benign
    int beg = rowptr[d], end = rowptr[d + 1];
    int cnt = end - beg;
    float4 ad4 = *(const float4*)&a_d[d * 4];
    float4 asd = *(const float4*)&a_s[d * 4];
    float es0 = lrelu(asd.x + ad4.x), es1 = lrelu(asd.y + ad4.y);
    float es2 = lrelu(asd.z + ad4.z), es3 = lrelu(asd.w + ad4.w);
    float m0 = es0, m1 = es1, m2 = es2, m3 = es3;
    float z0 = 0.f, z1 = 0.f, z2 = 0.f, z3 = 0.f;

    int l16 = lane & 15, egrp = lane >> 4;
    int ch = l16 * 8;                               // channels ch..ch+7
    int head = l16 >> 2;
    float acc[8];
    #pragma unroll
    for (int i = 0; i < 8; ++i) acc[i] = 0.f;

    for (int j0 = 0; j0 < cnt; j0 += 64) {
        int ne = min(64, cnt - j0);
        float l0 = -1e30f, l1 = -1e30f, l2 = -1e30f, l3 = -1e30f;
        int s = 0;
        if (lane < ne) {
            s = colsrc[beg + j0 + lane];
            float4 sv = *(const float4*)&a_s[s * 4];
            l0 = lrelu(sv.x + ad4.x); l1 = lrelu(sv.y + ad4.y);
            l2 = lrelu(sv.z + ad4.z); l3 = lrelu(sv.w + ad4.w);
        }
        float c0 = l0, c1 = l1, c2 = l2, c3 = l3;
        #pragma unroll
        for (int off = 32; off; off >>= 1) {
            c0 = fmaxf(c0, __shfl_xor(c0, off));
            c1 = fmaxf(c1, __shfl_xor(c1, off));
            c2 = fmaxf(c2, __shfl_xor(c2, off));
            c3 = fmaxf(c3, __shfl_xor(c3, off));
        }
        float n0 = fmaxf(m0, c0), n1 = fmaxf(m1, c1);
        float n2 = fmaxf(m2, c2), n3 = fmaxf(m3, c3);
        float sc0 = __expf(m0 - n0), sc1 = __expf(m1 - n1);
        float sc2 = __expf(m2 - n2), sc3 = __expf(m3 - n3);
        z0 *= sc0; z1 *= sc1; z2 *= sc2; z3 *= sc3;
        float mysc = (head < 2) ? (head == 0 ? sc0 : sc1) : (head == 2 ? sc2 : sc3);
        #pragma unroll
        for (int i = 0; i < 8; ++i) acc[i] *= mysc;
        float w0 = __expf(l0 - n0), w1 = __expf(l1 - n1);
        float w2 = __expf(l2 - n2), w3 = __expf(l3 - n3);
        float t0 = w0, t1 = w1, t2 = w2, t3 = w3;
        #pragma unroll
        for (int off = 32; off; off >>= 1) {
            t0 += __shfl_xor(t0, off);
            t1 += __shfl_xor(t1, off);
            t2 += __shfl_xor(t2, off);
            t3 += __shfl_xor(t3, off);
        }
        z0 += t0; z1 += t1; z2 += t2; z3 += t3;
        m0 = n0; m1 = n1; m2 = n2; m3 = n3;
        float4 wv = {w0, w1, w2, w3};
        *(float4*)&s_w[wave][lane * 4] = wv;
        __asm volatile("s_waitcnt lgkmcnt(0)" ::: "memory");  // wave-sync LDS
        int kmax = (ne + 3) >> 2;                   // UNIFORM trip count
        for (int k = 0; k < kmax; ++k) {
            int j = egrp + 4 * k;
            int ss = __shfl(s, min(j, 63));         // full-exec shuffle, active src
            if (j < ne) {
                float wj = s_w[wave][j * 4 + head];
                int4 u = *(const int4*)&h[(size_t)ss * 128 + ch];
                acc[0] += wj * bflo(u.x); acc[1] += wj * bfhi(u.x);
                acc[2] += wj * bflo(u.y); acc[3] += wj * bfhi(u.y);
                acc[4] += wj * bflo(u.z); acc[5] += wj * bfhi(u.z);
                acc[6] += wj * bflo(u.w); acc[7] += wj * bfhi(u.w);
            }
        }
    }
    // reduce partials across the 4 edge groups (full exec)
    #pragma unroll
    for (int off = 16; off < 64; off <<= 1)
        #pragma unroll
        for (int i = 0; i < 8; ++i) acc[i] += __shfl_xor(acc[i], off);

    if (egrp == 0) {                                // lanes 0..15 write 16B each
        float mh = (head < 2) ? (head == 0 ? m0 : m1) : (head == 2 ? m2 : m3);
        float zh = (head < 2) ? (head == 0 ? z0 : z1) : (head == 2 ? z2 : z3);
        float eh = (head < 2) ? (head == 0 ? es0 : es1) : (head == 2 ? es2 : es3);
        float ws = __expf(eh - mh);
        float inv = 1.f / (zh + ws + 1e-16f);
        int4 hu = *(const int4*)&h[(size_t)d * 128 + ch];
        float hs[8] = {bflo(hu.x), bfhi(hu.x), bflo(hu.y), bfhi(hu.y),
                       bflo(hu.z), bfhi(hu.z), bflo(hu.w), bfhi(hu.w)};
        float4 b0 = *(const float4*)&bias[ch];
        float4 b1 = *(const float4*)&bias[ch + 4];
        float o[8];
        o[0] = fmaxf((acc[0] + ws * hs[0]) * inv + b0.x, 0.f);
        o[1] = fmaxf((acc[1] + ws * hs[1]) * inv + b0.y, 0.f);
        o[2] = fmaxf((acc[2] + ws * hs[2]) * inv + b0.z, 0.f);
        o[3] = fmaxf((acc[3] + ws * hs[3]) * inv + b0.w, 0.f);
        o[4] = fmaxf((acc[4] + ws * hs[4]) * inv + b1.x, 0.f);
        o[5] = fmaxf((acc[5] + ws * hs[5]) * inv + b1.y, 0.f);
        o[6] = fmaxf((acc[6] + ws * hs[6]) * inv + b1.z, 0.f);
        o[7] = fmaxf((acc[7] + ws * hs[7]) * inv + b1.w, 0.f);
        int4 ou;
        ou.x = packbf2(o[0], o[1]); ou.y = packbf2(o[2], o[3]);
        ou.z = packbf2(o[4], o[5]); ou.w = packbf2(o[6], o[7]);
        *(int4*)&out[(size_t)d * 128 + ch] = ou;
    }
}

// ---------------- GraphConv aggregation: wave per dst, 128ch bf16 -----------------
__global__ __launch_bounds__(256) void sum_aggr128(
    const __hip_bfloat16* __restrict__ x, const int* __restrict__ rowptr,
    const int* __restrict__ colsrc, __hip_bfloat16* __restrict__ agg, int n)
{
    int t = threadIdx.x;
    int wave = t >> 6, lane = t & 63;
    int d = blockIdx.x * 4 + wave;
    if (d >= n) d = n - 1;
    int beg = rowptr[d], end = rowptr[d + 1];
    int cnt = end - beg;
    int l16 = lane & 15, egrp = lane >> 4;
    int ch = l16 * 8;
    float acc[8];
    #pragma unroll
    for (int i = 0; i < 8; ++i) acc[i] = 0.f;
    for (int j0 = 0; j0 < cnt; j0 += 64) {
        int ne = min(64, cnt - j0);
        int s = (lane < ne) ? colsrc[beg + j0 + lane] : 0;
        int kmax = (ne + 3) >> 2;                   // UNIFORM trip count
        for (int k = 0; k < kmax; ++k) {
            int j = egrp + 4 * k;
            int ss = __shfl(s, min(j, 63));         // full-exec shuffle
            if (j < ne) {
                int4 u = *(const int4*)&x[(size_t)ss * 128 + ch];
                acc[0] += bflo(u.x); acc[1] += bfhi(u.x);
                acc[2] += bflo(u.y); acc[3] += bfhi(u.y);
                acc[4] += bflo(u.z); acc[5] += bfhi(u.z);
                acc[6] += bflo(u.w); acc[7] += bfhi(u.w);
            }
        }
    }
    #pragma unroll
    for (int off = 16; off < 64; off <<= 1)
        #pragma unroll
        for (int i = 0; i < 8; ++i) acc[i] += __shfl_xor(acc[i], off);
    if (egrp == 0) {
        int4 ou;
        ou.x = packbf2(acc[0], acc[1]); ou.y = packbf2(acc[2], acc[3]);
        ou.z = packbf2(acc[4], acc[5]); ou.w = packbf2(acc[6], acc[7]);
        *(int4*)&agg[(size_t)d * 128 + ch] = ou;
    }
}

// ---------------- GraphConv via MFMA: out = relu(agg@Wr + b + x@Wl), 128->32 -------
__global__ __launch_bounds__(256) void graphconv_mfma(
    const __hip_bfloat16* __restrict__ AGGb, const __hip_bfloat16* __restrict__ Xb,
    const __hip_bfloat16* __restrict__ Wrt, const __hip_bfloat16* __restrict__ Wlt,
    const float* __restrict__ bias, __hip_bfloat16* __restrict__ out, int n)
{
    __shared__ __align__(16) __hip_bfloat16 sWr[32 * 136], sWl[32 * 136];
    int t = threadIdx.x;
    for (int i = t; i < 32 * 16; i += 256) {
        int row = i >> 4, ch = i & 15;
        *(int4*)&sWr[row * 136 + ch * 8] = *(const int4*)&Wrt[row * 128 + ch * 8];
        *(int4*)&sWl[row * 136 + ch * 8] = *(const int4*)&Wlt[row * 128 + ch * 8];
    }
    __syncthreads();
    int wave = t >> 6, lane = t & 63, quad = lane >> 4, l16 = lane & 15;
    int rowbase = (blockIdx.x * 4 + wave) * 16;
    if (rowbase >= n) return;

    v8bf z;
    #pragma unroll
    for (int i = 0; i < 8; ++i) z[i] = (__bf16)0.f;
    int arow = rowbase + l16;
    bool ok = arow < n;
    const v8bf* pr = (const v8bf*)(AGGb + (size_t)(ok ? arow : 0) * 128);
    const v8bf* px = (const v8bf*)(Xb   + (size_t)(ok ? arow : 0) * 128);
    v8bf fr[4], fx[4];
    #pragma unroll
    for (int ks = 0; ks < 4; ++ks) {
        fr[ks] = ok ? pr[ks * 4 + quad] : z;
        fx[ks] = ok ? px[ks * 4 + quad] : z;
    }
    v4f acc[2];
    acc[0] = (v4f){0.f, 0.f, 0.f, 0.f};
    acc[1] = (v4f){0.f, 0.f, 0.f, 0.f};
    #pragma unroll
    for (int ct = 0; ct < 2; ++ct) {
        #pragma unroll
        for (int ks = 0; ks < 4; ++ks) {
            v8bf br = *(const v8bf*)&sWr[(ct * 16 + l16) * 136 + ks * 32 + quad * 8];
            acc[ct] = __builtin_amdgcn_mfma_f32_16x16x32_bf16(fr[ks], br, acc[ct], 0, 0, 0);
            v8bf bl = *(const v8bf*)&sWl[(ct * 16 + l16) * 136 + ks * 32 + quad * 8];
            acc[ct] = __builtin_amdgcn_mfma_f32_16x16x32_bf16(fx[ks], bl, acc[ct], 0, 0, 0);
        }
    }
    #pragma unroll
    for (int ct = 0; ct < 2; ++ct) {
        float bcol = bias[ct * 16 + l16];
        #pragma unroll
        for (int reg = 0; reg < 4; ++reg) {
            int r = rowbase + quad * 4 + reg;
            if (r < n)
                *(unsigned short*)&out[(size_t)r * 32 + ct * 16 + l16] =
                    f2bf(fmaxf(acc[ct][reg] + bcol, 0.f));
        }
    }
}

// ---------------- SAGE mean aggregation: wave per dst, 32 ch ----------------------
__global__ __launch_bounds__(256) void mean_aggr32(
    const __hip_bfloat16* __restrict__ x, const int* __restrict__ rowptr,
    const int* __restrict__ colsrc, float* __restrict__ mean, int n)
{
    int t = threadIdx.x;
    int wave = t >> 6, lane = t & 63;
    int d = blockIdx.x * 4 + wave;
    if (d >= n) d = n - 1;
    int beg = rowptr[d], end = rowptr[d + 1];
    int cnt = end - beg;
    int l4 = lane & 3, egrp = lane >> 2;      // 16 edges concurrent, 4 lanes/row
    int ch = l4 * 8;
    float acc[8];
    #pragma unroll
    for (int i = 0; i < 8; ++i) acc[i] = 0.f;
    for (int j0 = 0; j0 < cnt; j0 += 64) {
        int ne = min(64, cnt - j0);
        int s = (lane < ne) ? colsrc[beg + j0 + lane] : 0;
        int kmax = (ne + 15) >> 4;                  // UNIFORM trip count
        for (int k = 0; k < kmax; ++k) {
            int j = egrp + 16 * k;
            int ss = __shfl(s, min(j, 63));         // full-exec shuffle
            if (j < ne) {
                int4 u = *(const int4*)&x[(size_t)ss * 32 + ch];
                acc[0] += bflo(u.x); acc[1] += bfhi(u.x);
                acc[2] += bflo(u.y); acc[3] += bfhi(u.y);
                acc[4] += bflo(u.z); acc[5] += bfhi(u.z);
                acc[6] += bflo(u.w); acc[7] += bfhi(u.w);
            }
        }
    }
    #pragma unroll
    for (int off = 4; off < 64; off <<= 1)
        #pragma unroll
        for (int i = 0; i < 8; ++i) acc[i] += __shfl_xor(acc[i], off);
    if (egrp == 0) {                           // lanes 0..3
        float invd = 1.f / fmaxf((float)cnt, 1.f);
        float4 lo = {acc[0] * invd, acc[1] * invd, acc[2] * invd, acc[3] * invd};
        float4 hi = {acc[4] * invd, acc[5] * invd, acc[6] * invd, acc[7] * invd};
        *(float4*)&mean[(size_t)d * 32 + ch]     = lo;
        *(float4*)&mean[(size_t)d * 32 + ch + 4] = hi;
    }
}

// ---------------- SAGE GEMM: out = relu(mean@Wl + bl + x@Wr), 32->32 --------------
__global__ __launch_bounds__(256) void sage_gemm(
    const float* __restrict__ mean, const __hip_bfloat16* __restrict__ xin,
    const float* __restrict__ Wl, const float* __restrict__ bl,
    const float* __restrict__ Wr, float* __restrict__ out, int n)
{
    __shared__ __align__(16) float sWl[32 * 32], sWr[32 * 32];
    __shared__ __align__(16) float sm[8 * 32], sx[8 * 32];
    int t = threadIdx.x;
    for (int i = t; i < 1024; i += 256) { sWl[i] = Wl[i]; sWr[i] = Wr[i]; }
    int c = t & 31, rr = t >> 5;
    float bc = bl[c];
    for (int row0 = blockIdx.x * 8; row0 < n; row0 += gridDim.x * 8) {
        __syncthreads();
        {
            int i = t;
            int r = i >> 5, cc = i & 31;
            int row = row0 + r;
            sm[i] = (row < n) ? mean[row * 32 + cc] : 0.f;
            sx[i] = (row < n) ? bf2f(xin[row * 32 + cc]) : 0.f;
        }
        __syncthreads();
        float acc = bc;
        const float4* pm = (const float4*)&sm[rr * 32];
        const float4* px = (const float4*)&sx[rr * 32];
        #pragma unroll
        for (int k4 = 0; k4 < 8; ++k4) {
            float4 vm = pm[k4], vx = px[k4];
            const float* wl = &sWl[(k4 * 4) * 32 + c];
            const float* wr = &sWr[(k4 * 4) * 32 + c];
            acc += vm.x * wl[0] + vm.y * wl[32] + vm.z * wl[64] + vm.w * wl[96];
            acc += vx.x * wr[0] + vx.y * wr[32] + vx.z * wr[64] + vx.w * wr[96];
        }
        int row = row0 + rr;
        if (row < n) out[row * 32 + c] = fmaxf(acc, 0.f);
    }
}

// ---------------- global mean pool (batch sorted) ----------------
__device__ __forceinline__ int lower_bound_i(const int* a, int n, int key) {
    int lo = 0, hi = n;
    while (lo < hi) { int mid = (lo + hi) >> 1; if (a[mid] < key) lo = mid + 1; else hi = mid; }
    return lo;
}

__global__ __launch_bounds__(256) void pool_kernel(
    const float* __restrict__ x, const int* __restrict__ batch,
    float* __restrict__ gpool, int n)
{
    int g = blockIdx.x;
    int lo = lower_bound_i(batch, n, g);
    int hi = lower_bound_i(batch, n, g + 1);
    int t = threadIdx.x;
    int c = t & 31, rr = t >> 5;
    float acc = 0.f;
    for (int i = lo + rr; i < hi; i += 8) acc += x[i * 32 + c];
    __shared__ float sred[256];
    sred[t] = acc;
    __syncthreads();
    if (t < 128) sred[t] += sred[t + 128];
    __syncthreads();
    if (t < 64) sred[t] += sred[t + 64];
    __syncthreads();
    if (t < 32) {
        float v = sred[t] + sred[t + 32];
        gpool[g * 32 + t] = v / fmaxf((float)(hi - lo), 1.f);
    }
}

// ---------------- MLP head ----------------
__global__ __launch_bounds__(256) void head_kernel(
    const float* __restrict__ gpool, const float* __restrict__ Wf1, const float* __restrict__ bf1,
    const float* __restrict__ Wf2, const float* __restrict__ bf2, float* __restrict__ out)
{
    __shared__ float sg[64 * 32], st[64 * 32];
    __shared__ float sW1[32 * 32], sW2[32 * 10];
    int t = threadIdx.x;
    for (int i = t; i < 2048; i += 256) sg[i] = gpool[i];
    for (int i = t; i < 1024; i += 256) sW1[i] = Wf1[i];
    for (int i = t; i < 320; i += 256) sW2[i] = Wf2[i];
    __syncthreads();
    for (int i = t; i < 2048; i += 256) {
        int g = i >> 5, c = i & 31;
        float acc = bf1[c];
        #pragma unroll
        for (int k = 0; k < 32; ++k) acc += sg[g * 32 + k] * sW1[k * 32 + c];
        st[i] = fmaxf(acc, 0.f);
    }
    __syncthreads();
    for (int i = t; i < 640; i += 256) {
        int g = i / 10, o = i - g * 10;
        float acc = bf2[o];
        #pragma unroll
        for (int k = 0; k < 32; ++k) acc += st[g * 32 + k] * sW2[k * 10 + o];
        out[i] = acc;
    }
}

extern "C" void kernel_launch(void* const* d_in, const int* in_sizes, int n_in,
                              void* d_out, int out_size, void* d_ws, size_t ws_size,
                              hipStream_t stream) {
    const float* x    = (const float*)d_in[0];
    const int*   ei   = (const int*)d_in[1];
    const int*   batch= (const int*)d_in[2];
    const float* W1   = (const float*)d_in[3];
    const float* as1  = (const float*)d_in[4];
    const float* ad1  = (const float*)d_in[5];
    const float* b1   = (const float*)d_in[6];
    const float* W2   = (const float*)d_in[7];
    const float* as2  = (const float*)d_in[8];
    const float* ad2  = (const float*)d_in[9];
    const float* b2   = (const float*)d_in[10];
    const float* W3r  = (const float*)d_in[11];
    const float* W3l  = (const float*)d_in[12];
    const float* b3   = (const float*)d_in[13];
    const float* W4l  = (const float*)d_in[14];
    const float* b4l  = (const float*)d_in[15];
    const float* W4r  = (const float*)d_in[16];
    const float* Wf1  = (const float*)d_in[17];
    const float* bf1  = (const float*)d_in[18];
    const float* Wf2  = (const float*)d_in[19];
    const float* bf2  = (const float*)d_in[20];

    const int N = in_sizes[0] / 128;
    const int E = in_sizes[1] / 2;
    const int* src = ei;
    const int* dst = ei + E;

    char* p = (char*)d_ws;
    auto alloc = [&](size_t bytes) -> void* {
        void* r = (void*)p;
        p += (bytes + 255) & ~(size_t)255;
        return r;
    };
    __hip_bfloat16* buf1 = (__hip_bfloat16*)alloc((size_t)N * 128 * 2);  // x2 / X4
    __hip_bfloat16* buf2 = (__hip_bfloat16*)alloc((size_t)N * 128 * 2);  // x1 / x3+mean
    __hip_bfloat16* buf3 = (__hip_bfloat16*)alloc((size_t)N * 128 * 2);  // h1,h2 / aggb
    float* aS     = (float*)alloc((size_t)N * 4 * 4);
    float* aD     = (float*)alloc((size_t)N * 4 * 4);
    int*   deg    = (int*)alloc((size_t)N * 4);
    int*   rowptr = (int*)alloc((size_t)(N + 1) * 4);
    int*   cur    = (int*)alloc((size_t)N * 4);
    int*   colsrc = (int*)alloc((size_t)E * 4);
    int*   bsum   = (int*)alloc(64 * 4);
    int*   boff   = (int*)alloc(64 * 4);
    __hip_bfloat16* W1t  = (__hip_bfloat16*)alloc(128 * 128 * 2);
    __hip_bfloat16* W2t  = (__hip_bfloat16*)alloc(128 * 128 * 2);
    __hip_bfloat16* W3rt = (__hip_bfloat16*)alloc(32 * 128 * 2);
    __hip_bfloat16* W3lt = (__hip_bfloat16*)alloc(32 * 128 * 2);
    float* gpool  = (float*)alloc(64 * 32 * 4);

    __hip_bfloat16* X3b  = buf2;                                        // N*32 bf16
    float*          MEAN = (float*)((char*)buf2 + (((size_t)N * 32 * 2 + 255) & ~(size_t)255));
    float*          X4   = (float*)buf1;                                // N*32 fp32

    const int nb = (N + 1023) / 1024;

    // CSR build
    hipMemsetAsync(deg, 0, (size_t)N * 4, stream);
    hist_kernel<<<(E + 255) / 256, 256, 0, stream>>>(dst, deg, E);
    scan_partial<<<nb, 256, 0, stream>>>(deg, bsum, N);
    scan_block<<<1, 64, 0, stream>>>(bsum, boff, nb, rowptr, N);
    scan_final<<<nb, 256, 0, stream>>>(deg, boff, rowptr, cur, N);
    fill_kernel<<<(E + 255) / 256, 256, 0, stream>>>(src, dst, cur, colsrc, E);

    // weight prep
    convert_w_t<<<(128 * 128 + 255) / 256, 256, 0, stream>>>(W1, W1t, 128, 128);
    convert_w_t<<<(128 * 128 + 255) / 256, 256, 0, stream>>>(W2, W2t, 128, 128);
    convert_w_t<<<(128 * 32 + 255) / 256, 256, 0, stream>>>(W3r, W3rt, 128, 32);
    convert_w_t<<<(128 * 32 + 255) / 256, 256, 0, stream>>>(W3l, W3lt, 128, 32);

    const int gmm = (N + 63) / 64;
    const int gag = (N + 3) / 4;
    // GAT layer 1 (reads fp32 x directly)
    gemm_att_mfma<float><<<gmm, 256, 0, stream>>>(x, W1t, as1, ad1, buf3, aS, aD, N);
    gat_aggr<<<gag, 256, 0, stream>>>(buf3, aS, aD, rowptr, colsrc, b1, buf2, N);
    // GAT layer 2
    gemm_att_mfma<__hip_bfloat16><<<gmm, 256, 0, stream>>>(buf2, W2t, as2, ad2, buf3, aS, aD, N);
    gat_aggr<<<gag, 256, 0, stream>>>(buf3, aS, aD, rowptr, colsrc, b2, buf1, N);
    // GraphConv
    sum_aggr128<<<gag, 256, 0, stream>>>(buf1, rowptr, colsrc, buf3, N);
    graphconv_mfma<<<gmm, 256, 0, stream>>>(buf3, buf1, W3rt, W3lt, b3, X3b, N);
    // SAGE
    mean_aggr32<<<gag, 256, 0, stream>>>(X3b, rowptr, colsrc, MEAN, N);
    sage_gemm<<<1024, 256, 0, stream>>>(MEAN, X3b, W4l, b4l, W4r, X4, N);
    // pool + head
    pool_kernel<<<64, 256, 0, stream>>>(X4, batch, gpool, N);
    head_kernel<<<1, 256, 0, stream>>>(gpool, Wf1, bf1, Wf2, bf2, (float*)d_out);
}

// Round 6
// 418.936 us; speedup vs baseline: 2.2530x; 1.0974x over previous
//
#include <hip/hip_runtime.h>
#include <hip/hip_bf16.h>
#include <type_traits>

// GNN: GAT(128->4x32) -> GAT(128->4x32) -> GraphConv(128->32) -> SAGE(32->32)
//      -> global mean pool (64 graphs) -> MLP(32->32->10)
// R1: CSR gather aggregation, fp32.                         944 us
// R2: bf16 features + cooperative alpha.                    782 us
// R3: parallel scan + MFMA bf16 GEMMs.                      523 us
// R4: wave-per-dst aggr — FAILED (shfl from exec-inactive lane).
// R5: fixed wave-per-dst single-pass aggr.                  460 us
// R6: softmax WITHOUT max subtraction (logits are O(8), exp safe in fp32:
//     kills both butterflies + rescale per chunk); GraphConv reordered via
//     linearity (gather 64B y-rows instead of 256B x-rows); merged W converts.

typedef __bf16 v8bf __attribute__((ext_vector_type(8)));
typedef float  v4f  __attribute__((ext_vector_type(4)));

__device__ __forceinline__ float lrelu(float x) { return x > 0.f ? x : 0.2f * x; }

__device__ __forceinline__ float bf2f(__hip_bfloat16 b) {
    unsigned short u = *(const unsigned short*)&b;
    return __uint_as_float((unsigned)u << 16);
}
__device__ __forceinline__ unsigned short f2bf(float f) {
    unsigned u = __float_as_uint(f);
    unsigned r = (u + 0x7FFF + ((u >> 16) & 1)) >> 16;   // RNE
    return (unsigned short)r;
}
__device__ __forceinline__ float bflo(int v) { return __uint_as_float((unsigned)v << 16); }
__device__ __forceinline__ float bfhi(int v) { return __uint_as_float((unsigned)v & 0xffff0000u); }
__device__ __forceinline__ int packbf2(float a, float b) {
    return (int)f2bf(a) | ((int)f2bf(b) << 16);
}

// ---------------- CSR build ----------------
__global__ void hist_kernel(const int* __restrict__ dst, int* __restrict__ deg, int E) {
    int e = blockIdx.x * 256 + threadIdx.x;
    if (e < E) atomicAdd(&deg[dst[e]], 1);
}

__global__ __launch_bounds__(256) void scan_partial(const int* __restrict__ deg,
                                                    int* __restrict__ bsum, int n) {
    __shared__ int red[256];
    int t = threadIdx.x;
    int base = blockIdx.x * 1024 + t * 4;
    int s = 0;
    if (base + 3 < n) { int4 v = *(const int4*)&deg[base]; s = v.x + v.y + v.z + v.w; }
    else { for (int j = 0; j < 4; ++j) if (base + j < n) s += deg[base + j]; }
    red[t] = s;
    __syncthreads();
    for (int off = 128; off; off >>= 1) { if (t < off) red[t] += red[t + off]; __syncthreads(); }
    if (t == 0) bsum[blockIdx.x] = red[0];
}

__global__ __launch_bounds__(64) void scan_block(const int* __restrict__ bsum,
                                                 int* __restrict__ boff, int nb,
                                                 int* __restrict__ rowptr, int n) {
    int t = threadIdx.x;
    int s = (t < nb) ? bsum[t] : 0;
    int v = s;
    for (int off = 1; off < 64; off <<= 1) {
        int u = __shfl_up(v, off);
        if (t >= off) v += u;
    }
    if (t < nb) boff[t] = v - s;
    if (t == nb - 1) rowptr[n] = v;
}

__global__ __launch_bounds__(256) void scan_final(const int* __restrict__ deg,
                                                  const int* __restrict__ boff,
                                                  int* __restrict__ rowptr,
                                                  int* __restrict__ cur, int n) {
    __shared__ int red[256];
    int t = threadIdx.x;
    int base = blockIdx.x * 1024 + t * 4;
    int d0 = 0, d1 = 0, d2 = 0, d3 = 0;
    if (base + 3 < n) { int4 v = *(const int4*)&deg[base]; d0 = v.x; d1 = v.y; d2 = v.z; d3 = v.w; }
    else {
        if (base < n)     d0 = deg[base];
        if (base + 1 < n) d1 = deg[base + 1];
        if (base + 2 < n) d2 = deg[base + 2];
        if (base + 3 < n) d3 = deg[base + 3];
    }
    int s = d0 + d1 + d2 + d3;
    red[t] = s;
    __syncthreads();
    for (int off = 1; off < 256; off <<= 1) {
        int v = (t >= off) ? red[t - off] : 0;
        __syncthreads();
        red[t] += v;
        __syncthreads();
    }
    int pre = boff[blockIdx.x] + red[t] - s;
    if (base < n)     { rowptr[base]     = pre; cur[base]     = pre; } pre += d0;
    if (base + 1 < n) { rowptr[base + 1] = pre; cur[base + 1] = pre; } pre += d1;
    if (base + 2 < n) { rowptr[base + 2] = pre; cur[base + 2] = pre; }
    pre += d2;
    if (base + 3 < n) { rowptr[base + 3] = pre; cur[base + 3] = pre; }
}

__global__ void fill_kernel(const int* __restrict__ src, const int* __restrict__ dst,
                            int* __restrict__ cur, int* __restrict__ colsrc, int E) {
    int e = blockIdx.x * 256 + threadIdx.x;
    if (e < E) {
        int d = dst[e];
        int p = atomicAdd(&cur[d], 1);
        colsrc[p] = src[e];
    }
}

// ---------------- merged weight prep: W[k][c] fp32 -> Wt[c][k] bf16 ---------------
__global__ void convert_weights(const float* __restrict__ W1, const float* __restrict__ W2,
                                const float* __restrict__ W3r, const float* __restrict__ W3l,
                                __hip_bfloat16* __restrict__ W1t, __hip_bfloat16* __restrict__ W2t,
                                __hip_bfloat16* __restrict__ W3rt, __hip_bfloat16* __restrict__ W3lt) {
    int i = blockIdx.x * 256 + threadIdx.x;
    if (i < 16384) {
        int k = i >> 7, c = i & 127;
        *(unsigned short*)&W1t[c * 128 + k] = f2bf(W1[i]);
        *(unsigned short*)&W2t[c * 128 + k] = f2bf(W2[i]);
    }
    if (i < 4096) {
        int k = i >> 5, c = i & 31;
        *(unsigned short*)&W3rt[c * 128 + k] = f2bf(W3r[i]);
        *(unsigned short*)&W3lt[c * 128 + k] = f2bf(W3l[i]);
    }
}

// ---------------- GAT GEMM via MFMA: h = X@W (bf16), a_s/a_d dots -----------------
template <typename T>
__global__ __launch_bounds__(256) void gemm_att_mfma(
    const T* __restrict__ X, const __hip_bfloat16* __restrict__ Wt,
    const float* __restrict__ att_s, const float* __restrict__ att_d,
    __hip_bfloat16* __restrict__ h, float* __restrict__ a_s, float* __restrict__ a_d, int n)
{
    __shared__ __align__(16) __hip_bfloat16 sWt[128 * 136];   // [col][k], +8 pad
    int t = threadIdx.x;
    for (int i = t; i < 128 * 16; i += 256) {
        int row = i >> 4, ch = i & 15;
        *(int4*)&sWt[row * 136 + ch * 8] = *(const int4*)&Wt[row * 128 + ch * 8];
    }
    __syncthreads();
    int wave = t >> 6, lane = t & 63, quad = lane >> 4, l16 = lane & 15;
    int rowbase = (blockIdx.x * 4 + wave) * 16;
    if (rowbase >= n) return;

    v8bf z;
    #pragma unroll
    for (int i = 0; i < 8; ++i) z[i] = (__bf16)0.f;
    int arow = rowbase + l16;
    bool ok = arow < n;
    v8bf af[4];
    if constexpr (std::is_same<T, float>::value) {
        const float* xf = X + (size_t)(ok ? arow : 0) * 128;
        #pragma unroll
        for (int ks = 0; ks < 4; ++ks) {
            if (ok) {
                float4 u = *(const float4*)&xf[ks * 32 + quad * 8];
                float4 v = *(const float4*)&xf[ks * 32 + quad * 8 + 4];
                v8bf a;
                unsigned short r;
                r = f2bf(u.x); a[0] = *(__bf16*)&r;
                r = f2bf(u.y); a[1] = *(__bf16*)&r;
                r = f2bf(u.z); a[2] = *(__bf16*)&r;
                r = f2bf(u.w); a[3] = *(__bf16*)&r;
                r = f2bf(v.x); a[4] = *(__bf16*)&r;
                r = f2bf(v.y); a[5] = *(__bf16*)&r;
                r = f2bf(v.z); a[6] = *(__bf16*)&r;
                r = f2bf(v.w); a[7] = *(__bf16*)&r;
                af[ks] = a;
            } else af[ks] = z;
        }
    } else {
        const v8bf* px = (const v8bf*)(X + (size_t)(ok ? arow : 0) * 128);
        #pragma unroll
        for (int ks = 0; ks < 4; ++ks) af[ks] = ok ? px[ks * 4 + quad] : z;
    }

    v4f acc[8];
    #pragma unroll
    for (int ct = 0; ct < 8; ++ct) acc[ct] = (v4f){0.f, 0.f, 0.f, 0.f};
    #pragma unroll
    for (int ct = 0; ct < 8; ++ct) {
        #pragma unroll
        for (int ks = 0; ks < 4; ++ks) {
            v8bf b = *(const v8bf*)&sWt[(ct * 16 + l16) * 136 + ks * 32 + quad * 8];
            acc[ct] = __builtin_amdgcn_mfma_f32_16x16x32_bf16(af[ks], b, acc[ct], 0, 0, 0);
        }
    }

    float sas[4][4], sad[4][4];
    #pragma unroll
    for (int r = 0; r < 4; ++r)
        #pragma unroll
        for (int hd = 0; hd < 4; ++hd) { sas[r][hd] = 0.f; sad[r][hd] = 0.f; }
    #pragma unroll
    for (int ct = 0; ct < 8; ++ct) {
        float sa = att_s[ct * 16 + l16];
        float da = att_d[ct * 16 + l16];
        int hd = ct >> 1;
        #pragma unroll
        for (int r = 0; r < 4; ++r) {
            float v = acc[ct][r];
            sas[r][hd] += v * sa;
            sad[r][hd] += v * da;
        }
    }
    #pragma unroll
    for (int reg = 0; reg < 4; ++reg) {
        int r = rowbase + quad * 4 + reg;
        if (r < n) {
            #pragma unroll
            for (int ct = 0; ct < 8; ++ct)
                *(unsigned short*)&h[(size_t)r * 128 + ct * 16 + l16] = f2bf(acc[ct][reg]);
        }
    }
    #pragma unroll
    for (int off = 1; off < 16; off <<= 1) {
        #pragma unroll
        for (int r = 0; r < 4; ++r)
            #pragma unroll
            for (int hd = 0; hd < 4; ++hd) {
                sas[r][hd] += __shfl_xor(sas[r][hd], off);
                sad[r][hd] += __shfl_xor(sad[r][hd], off);
            }
    }
    if (l16 == 0) {
        #pragma unroll
        for (int reg = 0; reg < 4; ++reg) {
            int r = rowbase + quad * 4 + reg;
            if (r < n) {
                float4 vs = {sas[reg][0], sas[reg][1], sas[reg][2], sas[reg][3]};
                float4 vd = {sad[reg][0], sad[reg][1], sad[reg][2], sad[reg][3]};
                *(float4*)&a_s[r * 4] = vs;
                *(float4*)&a_d[r * 4] = vd;
            }
        }
    }
}

// ---------------- GAT: wave-per-dst aggregation, softmax without max --------------
// exp(e) directly (logits O(8), fp32-safe; softmax is shift-invariant so
// result identical to reference). z accumulates per-lane; one butterfly at end.
__global__ __launch_bounds__(256) void gat_aggr(
    const __hip_bfloat16* __restrict__ h, const float* __restrict__ a_s,
    const float* __restrict__ a_d,
    const int* __restrict__ rowptr, const int* __restrict__ colsrc,
    const float* __restrict__ bias, __hip_bfloat16* __restrict__ out, int n)
{
    __shared__ float s_w[4][64 * 4];
    int t = threadIdx.x;
    int wave = t >> 6, lane = t & 63;
    int d = blockIdx.x * 4 + wave;
    if (d >= n) d = n - 1;                         // duplicate work, benign
    int beg = rowptr[d], end = rowptr[d + 1];
    int cnt = end - beg;
    float4 ad4 = *(const float4*)&a_d[d * 4];
    float4 asd = *(const float4*)&a_s[d * 4];
    float es0 = lrelu(asd.x + ad4.x), es1 = lrelu(asd.y + ad4.y);
    float es2 = lrelu(asd.z + ad4.z), es3 = lrelu(asd.w + ad4.w);
    float z0 = 0.f, z1 = 0.f, z2 = 0.f, z3 = 0.f;   // per-lane partials

    int l16 = lane & 15, egrp = lane >> 4;
    int ch = l16 * 8;                               // channels ch..ch+7
    int head = l16 >> 2;
    float acc[8];
    #pragma unroll
    for (int i = 0; i < 8; ++i) acc[i] = 0.f;

    for (int j0 = 0; j0 < cnt; j0 += 64) {
        int ne = min(64, cnt - j0);
        float w0 = 0.f, w1 = 0.f, w2 = 0.f, w3 = 0.f;
        int s = 0;
        if (lane < ne) {
            s = colsrc[beg + j0 + lane];
            float4 sv = *(const float4*)&a_s[s * 4];
            w0 = __expf(lrelu(sv.x + ad4.x));
            w1 = __expf(lrelu(sv.y + ad4.y));
            w2 = __expf(lrelu(sv.z + ad4.z));
            w3 = __expf(lrelu(sv.w + ad4.w));
        }
        z0 += w0; z1 += w1; z2 += w2; z3 += w3;
        float4 wv = {w0, w1, w2, w3};
        *(float4*)&s_w[wave][lane * 4] = wv;
        __asm volatile("s_waitcnt lgkmcnt(0)" ::: "memory");  // wave-sync LDS
        int kmax = (ne + 3) >> 2;                   // UNIFORM trip count
        for (int k = 0; k < kmax; ++k) {
            int j = egrp + 4 * k;
            int ss = __shfl(s, min(j, 63));         // full-exec shuffle, active src
            if (j < ne) {
                float wj = s_w[wave][j * 4 + head];
                int4 u = *(const int4*)&h[(size_t)ss * 128 + ch];
                acc[0] += wj * bflo(u.x); acc[1] += wj * bfhi(u.x);
                acc[2] += wj * bflo(u.y); acc[3] += wj * bfhi(u.y);
                acc[4] += wj * bflo(u.z); acc[5] += wj * bfhi(u.z);
                acc[6] += wj * bflo(u.w); acc[7] += wj * bfhi(u.w);
            }
        }
    }
    // one butterfly for z (all 64 lanes -> full sums everywhere)
    #pragma unroll
    for (int off = 1; off < 64; off <<= 1) {
        z0 += __shfl_xor(z0, off);
        z1 += __shfl_xor(z1, off);
        z2 += __shfl_xor(z2, off);
        z3 += __shfl_xor(z3, off);
    }
    // reduce acc partials across the 4 edge groups (full exec)
    #pragma unroll
    for (int off = 16; off < 64; off <<= 1)
        #pragma unroll
        for (int i = 0; i < 8; ++i) acc[i] += __shfl_xor(acc[i], off);

    if (egrp == 0) {                                // lanes 0..15 write 16B each
        float zh = (head < 2) ? (head == 0 ? z0 : z1) : (head == 2 ? z2 : z3);
        float eh = (head < 2) ? (head == 0 ? es0 : es1) : (head == 2 ? es2 : es3);
        float ws = __expf(eh);                      // self-loop weight
        float inv = 1.f / (zh + ws + 1e-16f);
        int4 hu = *(const int4*)&h[(size_t)d * 128 + ch];
        float hs[8] = {bflo(hu.x), bfhi(hu.x), bflo(hu.y), bfhi(hu.y),
                       bflo(hu.z), bfhi(hu.z), bflo(hu.w), bfhi(hu.w)};
        float4 b0 = *(const float4*)&bias[ch];
        float4 b1 = *(const float4*)&bias[ch + 4];
        float o[8];
        o[0] = fmaxf((acc[0] + ws * hs[0]) * inv + b0.x, 0.f);
        o[1] = fmaxf((acc[1] + ws * hs[1]) * inv + b0.y, 0.f);
        o[2] = fmaxf((acc[2] + ws * hs[2]) * inv + b0.z, 0.f);
        o[3] = fmaxf((acc[3] + ws * hs[3]) * inv + b0.w, 0.f);
        o[4] = fmaxf((acc[4] + ws * hs[4]) * inv + b1.x, 0.f);
        o[5] = fmaxf((acc[5] + ws * hs[5]) * inv + b1.y, 0.f);
        o[6] = fmaxf((acc[6] + ws * hs[6]) * inv + b1.z, 0.f);
        o[7] = fmaxf((acc[7] + ws * hs[7]) * inv + b1.w, 0.f);
        int4 ou;
        ou.x = packbf2(o[0], o[1]); ou.y = packbf2(o[2], o[3]);
        ou.z = packbf2(o[4], o[5]); ou.w = packbf2(o[6], o[7]);
        *(int4*)&out[(size_t)d * 128 + ch] = ou;
    }
}

// ---------------- GraphConv linear: y = x@Wr (bf16), root = x@Wl + b (fp32) -------
__global__ __launch_bounds__(256) void graphconv_lin(
    const __hip_bfloat16* __restrict__ Xb,
    const __hip_bfloat16* __restrict__ Wrt, const __hip_bfloat16* __restrict__ Wlt,
    const float* __restrict__ bias, __hip_bfloat16* __restrict__ y,
    float* __restrict__ root, int n)
{
    __shared__ __align__(16) __hip_bfloat16 sWr[32 * 136], sWl[32 * 136];
    int t = threadIdx.x;
    for (int i = t; i < 32 * 16; i += 256) {
        int row = i >> 4, ch = i & 15;
        *(int4*)&sWr[row * 136 + ch * 8] = *(const int4*)&Wrt[row * 128 + ch * 8];
        *(int4*)&sWl[row * 136 + ch * 8] = *(const int4*)&Wlt[row * 128 + ch * 8];
    }
    __syncthreads();
    int wave = t >> 6, lane = t & 63, quad = lane >> 4, l16 = lane & 15;
    int rowbase = (blockIdx.x * 4 + wave) * 16;
    if (rowbase >= n) return;

    v8bf z;
    #pragma unroll
    for (int i = 0; i < 8; ++i) z[i] = (__bf16)0.f;
    int arow = rowbase + l16;
    bool ok = arow < n;
    const v8bf* px = (const v8bf*)(Xb + (size_t)(ok ? arow : 0) * 128);
    v8bf fx[4];
    #pragma unroll
    for (int ks = 0; ks < 4; ++ks) fx[ks] = ok ? px[ks * 4 + quad] : z;

    v4f accR[2], accL[2];
    #pragma unroll
    for (int ct = 0; ct < 2; ++ct) {
        accR[ct] = (v4f){0.f, 0.f, 0.f, 0.f};
        accL[ct] = (v4f){0.f, 0.f, 0.f, 0.f};
        #pragma unroll
        for (int ks = 0; ks < 4; ++ks) {
            v8bf br = *(const v8bf*)&sWr[(ct * 16 + l16) * 136 + ks * 32 + quad * 8];
            accR[ct] = __builtin_amdgcn_mfma_f32_16x16x32_bf16(fx[ks], br, accR[ct], 0, 0, 0);
            v8bf bl = *(const v8bf*)&sWl[(ct * 16 + l16) * 136 + ks * 32 + quad * 8];
            accL[ct] = __builtin_amdgcn_mfma_f32_16x16x32_bf16(fx[ks], bl, accL[ct], 0, 0, 0);
        }
    }
    #pragma unroll
    for (int ct = 0; ct < 2; ++ct) {
        float bcol = bias[ct * 16 + l16];
        #pragma unroll
        for (int reg = 0; reg < 4; ++reg) {
            int r = rowbase + quad * 4 + reg;
            if (r < n) {
                *(unsigned short*)&y[(size_t)r * 32 + ct * 16 + l16] = f2bf(accR[ct][reg]);
                root[(size_t)r * 32 + ct * 16 + l16] = accL[ct][reg] + bcol;
            }
        }
    }
}

// ---------------- GraphConv aggr: x3 = relu(sum_{src} y[src] + root), 32 ch -------
__global__ __launch_bounds__(256) void graphconv_aggr(
    const __hip_bfloat16* __restrict__ y, const float* __restrict__ root,
    const int* __restrict__ rowptr, const int* __restrict__ colsrc,
    __hip_bfloat16* __restrict__ x3, int n)
{
    int t = threadIdx.x;
    int wave = t >> 6, lane = t & 63;
    int d = blockIdx.x * 4 + wave;
    if (d >= n) d = n - 1;
    int beg = rowptr[d], end = rowptr[d + 1];
    int cnt = end - beg;
    int l4 = lane & 3, egrp = lane >> 2;      // 16 edges concurrent, 4 lanes/row
    int ch = l4 * 8;
    float acc[8];
    #pragma unroll
    for (int i = 0; i < 8; ++i) acc[i] = 0.f;
    for (int j0 = 0; j0 < cnt; j0 += 64) {
        int ne = min(64, cnt - j0);
        int s = (lane < ne) ? colsrc[beg + j0 + lane] : 0;
        int kmax = (ne + 15) >> 4;                  // UNIFORM trip count
        for (int k = 0; k < kmax; ++k) {
            int j = egrp + 16 * k;
            int ss = __shfl(s, min(j, 63));         // full-exec shuffle
            if (j < ne) {
                int4 u = *(const int4*)&y[(size_t)ss * 32 + ch];
                acc[0] += bflo(u.x); acc[1] += bfhi(u.x);
                acc[2] += bflo(u.y); acc[3] += bfhi(u.y);
                acc[4] += bflo(u.z); acc[5] += bfhi(u.z);
                acc[6] += bflo(u.w); acc[7] += bfhi(u.w);
            }
        }
    }
    #pragma unroll
    for (int off = 4; off < 64; off <<= 1)
        #pragma unroll
        for (int i = 0; i < 8; ++i) acc[i] += __shfl_xor(acc[i], off);
    if (egrp == 0) {                           // lanes 0..3 write 16B each
        float4 r0 = *(const float4*)&root[(size_t)d * 32 + ch];
        float4 r1 = *(const float4*)&root[(size_t)d * 32 + ch + 4];
        float o[8];
        o[0] = fmaxf(acc[0] + r0.x, 0.f); o[1] = fmaxf(acc[1] + r0.y, 0.f);
        o[2] = fmaxf(acc[2] + r0.z, 0.f); o[3] = fmaxf(acc[3] + r0.w, 0.f);
        o[4] = fmaxf(acc[4] + r1.x, 0.f); o[5] = fmaxf(acc[5] + r1.y, 0.f);
        o[6] = fmaxf(acc[6] + r1.z, 0.f); o[7] = fmaxf(acc[7] + r1.w, 0.f);
        int4 ou;
        ou.x = packbf2(o[0], o[1]); ou.y = packbf2(o[2], o[3]);
        ou.z = packbf2(o[4], o[5]); ou.w = packbf2(o[6], o[7]);
        *(int4*)&x3[(size_t)d * 32 + ch] = ou;
    }
}

// ---------------- SAGE mean aggregation: wave per dst, 32 ch ----------------------
__global__ __launch_bounds__(256) void mean_aggr32(
    const __hip_bfloat16* __restrict__ x, const int* __restrict__ rowptr,
    const int* __restrict__ colsrc, float* __restrict__ mean, int n)
{
    int t = threadIdx.x;
    int wave = t >> 6, lane = t & 63;
    int d = blockIdx.x * 4 + wave;
    if (d >= n) d = n - 1;
    int beg = rowptr[d], end = rowptr[d + 1];
    int cnt = end - beg;
    int l4 = lane & 3, egrp = lane >> 2;      // 16 edges concurrent, 4 lanes/row
    int ch = l4 * 8;
    float acc[8];
    #pragma unroll
    for (int i = 0; i < 8; ++i) acc[i] = 0.f;
    for (int j0 = 0; j0 < cnt; j0 += 64) {
        int ne = min(64, cnt - j0);
        int s = (lane < ne) ? colsrc[beg + j0 + lane] : 0;
        int kmax = (ne + 15) >> 4;                  // UNIFORM trip count
        for (int k = 0; k < kmax; ++k) {
            int j = egrp + 16 * k;
            int ss = __shfl(s, min(j, 63));         // full-exec shuffle
            if (j < ne) {
                int4 u = *(const int4*)&x[(size_t)ss * 32 + ch];
                acc[0] += bflo(u.x); acc[1] += bfhi(u.x);
                acc[2] += bflo(u.y); acc[3] += bfhi(u.y);
                acc[4] += bflo(u.z); acc[5] += bfhi(u.z);
                acc[6] += bflo(u.w); acc[7] += bfhi(u.w);
            }
        }
    }
    #pragma unroll
    for (int off = 4; off < 64; off <<= 1)
        #pragma unroll
        for (int i = 0; i < 8; ++i) acc[i] += __shfl_xor(acc[i], off);
    if (egrp == 0) {                           // lanes 0..3
        float invd = 1.f / fmaxf((float)cnt, 1.f);
        float4 lo = {acc[0] * invd, acc[1] * invd, acc[2] * invd, acc[3] * invd};
        float4 hi = {acc[4] * invd, acc[5] * invd, acc[6] * invd, acc[7] * invd};
        *(float4*)&mean[(size_t)d * 32 + ch]     = lo;
        *(float4*)&mean[(size_t)d * 32 + ch + 4] = hi;
    }
}

// ---------------- SAGE GEMM: out = relu(mean@Wl + bl + x@Wr), 32->32 --------------
__global__ __launch_bounds__(256) void sage_gemm(
    const float* __restrict__ mean, const __hip_bfloat16* __restrict__ xin,
    const float* __restrict__ Wl, const float* __restrict__ bl,
    const float* __restrict__ Wr, float* __restrict__ out, int n)
{
    __shared__ __align__(16) float sWl[32 * 32], sWr[32 * 32];
    __shared__ __align__(16) float sm[8 * 32], sx[8 * 32];
    int t = threadIdx.x;
    for (int i = t; i < 1024; i += 256) { sWl[i] = Wl[i]; sWr[i] = Wr[i]; }
    int c = t & 31, rr = t >> 5;
    float bc = bl[c];
    for (int row0 = blockIdx.x * 8; row0 < n; row0 += gridDim.x * 8) {
        __syncthreads();
        {
            int i = t;
            int r = i >> 5, cc = i & 31;
            int row = row0 + r;
            sm[i] = (row < n) ? mean[row * 32 + cc] : 0.f;
            sx[i] = (row < n) ? bf2f(xin[row * 32 + cc]) : 0.f;
        }
        __syncthreads();
        float acc = bc;
        const float4* pm = (const float4*)&sm[rr * 32];
        const float4* px = (const float4*)&sx[rr * 32];
        #pragma unroll
        for (int k4 = 0; k4 < 8; ++k4) {
            float4 vm = pm[k4], vx = px[k4];
            const float* wl = &sWl[(k4 * 4) * 32 + c];
            const float* wr = &sWr[(k4 * 4) * 32 + c];
            acc += vm.x * wl[0] + vm.y * wl[32] + vm.z * wl[64] + vm.w * wl[96];
            acc += vx.x * wr[0] + vx.y * wr[32] + vx.z * wr[64] + vx.w * wr[96];
        }
        int row = row0 + rr;
        if (row < n) out[row * 32 + c] = fmaxf(acc, 0.f);
    }
}

// ---------------- global mean pool (batch sorted) ----------------
__device__ __forceinline__ int lower_bound_i(const int* a, int n, int key) {
    int lo = 0, hi = n;
    while (lo < hi) { int mid = (lo + hi) >> 1; if (a[mid] < key) lo = mid + 1; else hi = mid; }
    return lo;
}

__global__ __launch_bounds__(256) void pool_kernel(
    const float* __restrict__ x, const int* __restrict__ batch,
    float* __restrict__ gpool, int n)
{
    int g = blockIdx.x;
    int lo = lower_bound_i(batch, n, g);
    int hi = lower_bound_i(batch, n, g + 1);
    int t = threadIdx.x;
    int c = t & 31, rr = t >> 5;
    float acc = 0.f;
    for (int i = lo + rr; i < hi; i += 8) acc += x[i * 32 + c];
    __shared__ float sred[256];
    sred[t] = acc;
    __syncthreads();
    if (t < 128) sred[t] += sred[t + 128];
    __syncthreads();
    if (t < 64) sred[t] += sred[t + 64];
    __syncthreads();
    if (t < 32) {
        float v = sred[t] + sred[t + 32];
        gpool[g * 32 + t] = v / fmaxf((float)(hi - lo), 1.f);
    }
}

// ---------------- MLP head ----------------
__global__ __launch_bounds__(256) void head_kernel(
    const float* __restrict__ gpool, const float* __restrict__ Wf1, const float* __restrict__ bf1,
    const float* __restrict__ Wf2, const float* __restrict__ bf2, float* __restrict__ out)
{
    __shared__ float sg[64 * 32], st[64 * 32];
    __shared__ float sW1[32 * 32], sW2[32 * 10];
    int t = threadIdx.x;
    for (int i = t; i < 2048; i += 256) sg[i] = gpool[i];
    for (int i = t; i < 1024; i += 256) sW1[i] = Wf1[i];
    for (int i = t; i < 320; i += 256) sW2[i] = Wf2[i];
    __syncthreads();
    for (int i = t; i < 2048; i += 256) {
        int g = i >> 5, c = i & 31;
        float acc = bf1[c];
        #pragma unroll
        for (int k = 0; k < 32; ++k) acc += sg[g * 32 + k] * sW1[k * 32 + c];
        st[i] = fmaxf(acc, 0.f);
    }
    __syncthreads();
    for (int i = t; i < 640; i += 256) {
        int g = i / 10, o = i - g * 10;
        float acc = bf2[o];
        #pragma unroll
        for (int k = 0; k < 32; ++k) acc += st[g * 32 + k] * sW2[k * 10 + o];
        out[i] = acc;
    }
}

extern "C" void kernel_launch(void* const* d_in, const int* in_sizes, int n_in,
                              void* d_out, int out_size, void* d_ws, size_t ws_size,
                              hipStream_t stream) {
    const float* x    = (const float*)d_in[0];
    const int*   ei   = (const int*)d_in[1];
    const int*   batch= (const int*)d_in[2];
    const float* W1   = (const float*)d_in[3];
    const float* as1  = (const float*)d_in[4];
    const float* ad1  = (const float*)d_in[5];
    const float* b1   = (const float*)d_in[6];
    const float* W2   = (const float*)d_in[7];
    const float* as2  = (const float*)d_in[8];
    const float* ad2  = (const float*)d_in[9];
    const float* b2   = (const float*)d_in[10];
    const float* W3r  = (const float*)d_in[11];
    const float* W3l  = (const float*)d_in[12];
    const float* b3   = (const float*)d_in[13];
    const float* W4l  = (const float*)d_in[14];
    const float* b4l  = (const float*)d_in[15];
    const float* W4r  = (const float*)d_in[16];
    const float* Wf1  = (const float*)d_in[17];
    const float* bf1  = (const float*)d_in[18];
    const float* Wf2  = (const float*)d_in[19];
    const float* bf2  = (const float*)d_in[20];

    const int N = in_sizes[0] / 128;
    const int E = in_sizes[1] / 2;
    const int* src = ei;
    const int* dst = ei + E;

    char* p = (char*)d_ws;
    auto alloc = [&](size_t bytes) -> void* {
        void* r = (void*)p;
        p += (bytes + 255) & ~(size_t)255;
        return r;
    };
    __hip_bfloat16* buf1 = (__hip_bfloat16*)alloc((size_t)N * 128 * 2);  // x2 / X4
    __hip_bfloat16* buf2 = (__hip_bfloat16*)alloc((size_t)N * 128 * 2);  // x1 / x3+mean
    __hip_bfloat16* buf3 = (__hip_bfloat16*)alloc((size_t)N * 128 * 2);  // h1,h2 / y+root
    float* aS     = (float*)alloc((size_t)N * 4 * 4);
    float* aD     = (float*)alloc((size_t)N * 4 * 4);
    int*   deg    = (int*)alloc((size_t)N * 4);
    int*   rowptr = (int*)alloc((size_t)(N + 1) * 4);
    int*   cur    = (int*)alloc((size_t)N * 4);
    int*   colsrc = (int*)alloc((size_t)E * 4);
    int*   bsum   = (int*)alloc(64 * 4);
    int*   boff   = (int*)alloc(64 * 4);
    __hip_bfloat16* W1t  = (__hip_bfloat16*)alloc(128 * 128 * 2);
    __hip_bfloat16* W2t  = (__hip_bfloat16*)alloc(128 * 128 * 2);
    __hip_bfloat16* W3rt = (__hip_bfloat16*)alloc(32 * 128 * 2);
    __hip_bfloat16* W3lt = (__hip_bfloat16*)alloc(32 * 128 * 2);
    float* gpool  = (float*)alloc(64 * 32 * 4);

    // aliased views
    __hip_bfloat16* X3b  = buf2;                                        // N*32 bf16
    float*          MEAN = (float*)((char*)buf2 + (((size_t)N * 32 * 2 + 255) & ~(size_t)255));
    float*          X4   = (float*)buf1;                                // N*32 fp32
    __hip_bfloat16* Y32  = buf3;                                        // N*32 bf16
    float*          ROOT = (float*)((char*)buf3 + (((size_t)N * 32 * 2 + 255) & ~(size_t)255));

    const int nb = (N + 1023) / 1024;

    // CSR build
    hipMemsetAsync(deg, 0, (size_t)N * 4, stream);
    hist_kernel<<<(E + 255) / 256, 256, 0, stream>>>(dst, deg, E);
    scan_partial<<<nb, 256, 0, stream>>>(deg, bsum, N);
    scan_block<<<1, 64, 0, stream>>>(bsum, boff, nb, rowptr, N);
    scan_final<<<nb, 256, 0, stream>>>(deg, boff, rowptr, cur, N);
    fill_kernel<<<(E + 255) / 256, 256, 0, stream>>>(src, dst, cur, colsrc, E);

    // weight prep (single launch)
    convert_weights<<<64, 256, 0, stream>>>(W1, W2, W3r, W3l, W1t, W2t, W3rt, W3lt);

    const int gmm = (N + 63) / 64;
    const int gag = (N + 3) / 4;
    // GAT layer 1 (reads fp32 x directly)
    gemm_att_mfma<float><<<gmm, 256, 0, stream>>>(x, W1t, as1, ad1, buf3, aS, aD, N);
    gat_aggr<<<gag, 256, 0, stream>>>(buf3, aS, aD, rowptr, colsrc, b1, buf2, N);
    // GAT layer 2
    gemm_att_mfma<__hip_bfloat16><<<gmm, 256, 0, stream>>>(buf2, W2t, as2, ad2, buf3, aS, aD, N);
    gat_aggr<<<gag, 256, 0, stream>>>(buf3, aS, aD, rowptr, colsrc, b2, buf1, N);
    // GraphConv (reordered: project first, then 64B-row gather)
    graphconv_lin<<<gmm, 256, 0, stream>>>(buf1, W3rt, W3lt, b3, Y32, ROOT, N);
    graphconv_aggr<<<gag, 256, 0, stream>>>(Y32, ROOT, rowptr, colsrc, X3b, N);
    // SAGE
    mean_aggr32<<<gag, 256, 0, stream>>>(X3b, rowptr, colsrc, MEAN, N);
    sage_gemm<<<1024, 256, 0, stream>>>(MEAN, X3b, W4l, b4l, W4r, X4, N);
    // pool + head
    pool_kernel<<<64, 256, 0, stream>>>(X4, batch, gpool, N);
    head_kernel<<<1, 256, 0, stream>>>(gpool, Wf1, bf1, Wf2, bf2, (float*)d_out);
}

// Round 7
// 361.096 us; speedup vs baseline: 2.6139x; 1.1602x over previous
//
#include <hip/hip_runtime.h>
#include <hip/hip_bf16.h>
#include <type_traits>

// GNN: GAT(128->4x32) -> GAT(128->4x32) -> GraphConv(128->32) -> SAGE(32->32)
//      -> global mean pool (64 graphs) -> MLP(32->32->10)
// R1: CSR gather aggregation, fp32.                         944 us
// R2: bf16 features + cooperative alpha.                    782 us
// R3: parallel scan + MFMA bf16 GEMMs.                      523 us
// R4: wave-per-dst aggr — FAILED (shfl from exec-inactive lane).
// R5: fixed wave-per-dst single-pass aggr.                  460 us
// R6: no-max softmax, GraphConv linearity reorder.          419 us
// R7: bucketed CSR build (counting sort by dst>>8, LDS-privatized):
//     fill_kernel's 52 MB write amplification (64 B/edge random scatter +
//     800k device atomics) -> windowed L2-resident scatter, ~25 us total.
//     Requires N <= 65536 (8-bit dloc) and N <= 131072 (17-bit src pack).

typedef __bf16 v8bf __attribute__((ext_vector_type(8)));
typedef float  v4f  __attribute__((ext_vector_type(4)));

__device__ __forceinline__ float lrelu(float x) { return x > 0.f ? x : 0.2f * x; }

__device__ __forceinline__ float bf2f(__hip_bfloat16 b) {
    unsigned short u = *(const unsigned short*)&b;
    return __uint_as_float((unsigned)u << 16);
}
__device__ __forceinline__ unsigned short f2bf(float f) {
    unsigned u = __float_as_uint(f);
    unsigned r = (u + 0x7FFF + ((u >> 16) & 1)) >> 16;   // RNE
    return (unsigned short)r;
}
__device__ __forceinline__ float bflo(int v) { return __uint_as_float((unsigned)v << 16); }
__device__ __forceinline__ float bfhi(int v) { return __uint_as_float((unsigned)v & 0xffff0000u); }
__device__ __forceinline__ int packbf2(float a, float b) {
    return (int)f2bf(a) | ((int)f2bf(b) << 16);
}

// ================= bucketed CSR build =================
// bucket = dst >> 8 (256 dst per bucket); pairs word = (dst&255)<<17 | src.

__global__ __launch_bounds__(256) void bucket_hist(const int* __restrict__ dst,
                                                   int* __restrict__ bcount,
                                                   int E, int nbuck) {
    __shared__ int hist[256];
    int t = threadIdx.x;
    for (int i = t; i < nbuck; i += 256) hist[i] = 0;
    __syncthreads();
    int base = blockIdx.x * 4096;
    #pragma unroll
    for (int k = 0; k < 16; ++k) {
        int e = base + k * 256 + t;
        if (e < E) atomicAdd(&hist[dst[e] >> 8], 1);
    }
    __syncthreads();
    for (int i = t; i < nbuck; i += 256) {
        int c = hist[i];
        if (c) atomicAdd(&bcount[i], c);
    }
}

__global__ __launch_bounds__(256) void scan_buckets(const int* __restrict__ bcount,
                                                    int* __restrict__ bbase,
                                                    int* __restrict__ gcursor,
                                                    int nbuck, int E,
                                                    int* __restrict__ rowptr, int n) {
    __shared__ int red[256];
    int t = threadIdx.x;
    int v = (t < nbuck) ? bcount[t] : 0;
    red[t] = v;
    __syncthreads();
    for (int off = 1; off < 256; off <<= 1) {
        int u = (t >= off) ? red[t - off] : 0;
        __syncthreads();
        red[t] += u;
        __syncthreads();
    }
    int ex = red[t] - v;                           // exclusive prefix
    if (t < nbuck) { bbase[t] = ex; gcursor[t] = ex; }
    if (t == 0) { bbase[nbuck] = E; rowptr[n] = E; }
}

__global__ __launch_bounds__(256) void bucket_scatter(const int* __restrict__ dst,
                                                      const int* __restrict__ src,
                                                      int* __restrict__ gcursor,
                                                      int* __restrict__ pairs,
                                                      int E, int nbuck) {
    __shared__ int hist[256], lcur[256];
    int t = threadIdx.x;
    for (int i = t; i < nbuck; i += 256) hist[i] = 0;
    __syncthreads();
    int base = blockIdx.x * 2048;
    int dreg[8];
    #pragma unroll
    for (int k = 0; k < 8; ++k) {
        int e = base + k * 256 + t;
        int d = (e < E) ? dst[e] : -1;
        dreg[k] = d;
        if (d >= 0) atomicAdd(&hist[d >> 8], 1);
    }
    __syncthreads();
    for (int i = t; i < nbuck; i += 256) {
        int c = hist[i];
        lcur[i] = c ? atomicAdd(&gcursor[i], c) : 0;   // reserve contiguous run
    }
    __syncthreads();
    #pragma unroll
    for (int k = 0; k < 8; ++k) {
        int e = base + k * 256 + t;
        if (e < E) {
            int d = dreg[k];
            int p = atomicAdd(&lcur[d >> 8], 1);
            pairs[p] = ((d & 255) << 17) | src[e];
        }
    }
}

__global__ __launch_bounds__(256) void bucket_fill(const int* __restrict__ pairs,
                                                   const int* __restrict__ bbase,
                                                   int* __restrict__ rowptr,
                                                   int* __restrict__ colsrc, int n) {
    __shared__ int deg[256], excl[256], cur[256];
    int b = blockIdx.x, t = threadIdx.x;
    int e0 = bbase[b], e1 = bbase[b + 1];
    int d0 = b << 8;
    deg[t] = 0;
    __syncthreads();
    for (int j = e0 + t; j < e1; j += 256)
        atomicAdd(&deg[pairs[j] >> 17], 1);
    __syncthreads();
    int v = deg[t];
    excl[t] = v;
    __syncthreads();
    for (int off = 1; off < 256; off <<= 1) {
        int u = (t >= off) ? excl[t - off] : 0;
        __syncthreads();
        excl[t] += u;
        __syncthreads();
    }
    int base = e0 + excl[t] - v;                   // exclusive
    if (d0 + t < n) rowptr[d0 + t] = base;
    cur[t] = base;
    __syncthreads();
    for (int j = e0 + t; j < e1; j += 256) {
        int w = pairs[j];
        int p = atomicAdd(&cur[w >> 17], 1);
        colsrc[p] = w & 0x1FFFF;
    }
}

// ---------------- merged weight prep: W[k][c] fp32 -> Wt[c][k] bf16 ---------------
__global__ void convert_weights(const float* __restrict__ W1, const float* __restrict__ W2,
                                const float* __restrict__ W3r, const float* __restrict__ W3l,
                                __hip_bfloat16* __restrict__ W1t, __hip_bfloat16* __restrict__ W2t,
                                __hip_bfloat16* __restrict__ W3rt, __hip_bfloat16* __restrict__ W3lt) {
    int i = blockIdx.x * 256 + threadIdx.x;
    if (i < 16384) {
        int k = i >> 7, c = i & 127;
        *(unsigned short*)&W1t[c * 128 + k] = f2bf(W1[i]);
        *(unsigned short*)&W2t[c * 128 + k] = f2bf(W2[i]);
    }
    if (i < 4096) {
        int k = i >> 5, c = i & 31;
        *(unsigned short*)&W3rt[c * 128 + k] = f2bf(W3r[i]);
        *(unsigned short*)&W3lt[c * 128 + k] = f2bf(W3l[i]);
    }
}

// ---------------- GAT GEMM via MFMA: h = X@W (bf16), a_s/a_d dots -----------------
template <typename T>
__global__ __launch_bounds__(256) void gemm_att_mfma(
    const T* __restrict__ X, const __hip_bfloat16* __restrict__ Wt,
    const float* __restrict__ att_s, const float* __restrict__ att_d,
    __hip_bfloat16* __restrict__ h, float* __restrict__ a_s, float* __restrict__ a_d, int n)
{
    __shared__ __align__(16) __hip_bfloat16 sWt[128 * 136];   // [col][k], +8 pad
    int t = threadIdx.x;
    for (int i = t; i < 128 * 16; i += 256) {
        int row = i >> 4, ch = i & 15;
        *(int4*)&sWt[row * 136 + ch * 8] = *(const int4*)&Wt[row * 128 + ch * 8];
    }
    __syncthreads();
    int wave = t >> 6, lane = t & 63, quad = lane >> 4, l16 = lane & 15;
    int rowbase = (blockIdx.x * 4 + wave) * 16;
    if (rowbase >= n) return;

    v8bf z;
    #pragma unroll
    for (int i = 0; i < 8; ++i) z[i] = (__bf16)0.f;
    int arow = rowbase + l16;
    bool ok = arow < n;
    v8bf af[4];
    if constexpr (std::is_same<T, float>::value) {
        const float* xf = X + (size_t)(ok ? arow : 0) * 128;
        #pragma unroll
        for (int ks = 0; ks < 4; ++ks) {
            if (ok) {
                float4 u = *(const float4*)&xf[ks * 32 + quad * 8];
                float4 v = *(const float4*)&xf[ks * 32 + quad * 8 + 4];
                v8bf a;
                unsigned short r;
                r = f2bf(u.x); a[0] = *(__bf16*)&r;
                r = f2bf(u.y); a[1] = *(__bf16*)&r;
                r = f2bf(u.z); a[2] = *(__bf16*)&r;
                r = f2bf(u.w); a[3] = *(__bf16*)&r;
                r = f2bf(v.x); a[4] = *(__bf16*)&r;
                r = f2bf(v.y); a[5] = *(__bf16*)&r;
                r = f2bf(v.z); a[6] = *(__bf16*)&r;
                r = f2bf(v.w); a[7] = *(__bf16*)&r;
                af[ks] = a;
            } else af[ks] = z;
        }
    } else {
        const v8bf* px = (const v8bf*)(X + (size_t)(ok ? arow : 0) * 128);
        #pragma unroll
        for (int ks = 0; ks < 4; ++ks) af[ks] = ok ? px[ks * 4 + quad] : z;
    }

    v4f acc[8];
    #pragma unroll
    for (int ct = 0; ct < 8; ++ct) acc[ct] = (v4f){0.f, 0.f, 0.f, 0.f};
    #pragma unroll
    for (int ct = 0; ct < 8; ++ct) {
        #pragma unroll
        for (int ks = 0; ks < 4; ++ks) {
            v8bf b = *(const v8bf*)&sWt[(ct * 16 + l16) * 136 + ks * 32 + quad * 8];
            acc[ct] = __builtin_amdgcn_mfma_f32_16x16x32_bf16(af[ks], b, acc[ct], 0, 0, 0);
        }
    }

    float sas[4][4], sad[4][4];
    #pragma unroll
    for (int r = 0; r < 4; ++r)
        #pragma unroll
        for (int hd = 0; hd < 4; ++hd) { sas[r][hd] = 0.f; sad[r][hd] = 0.f; }
    #pragma unroll
    for (int ct = 0; ct < 8; ++ct) {
        float sa = att_s[ct * 16 + l16];
        float da = att_d[ct * 16 + l16];
        int hd = ct >> 1;
        #pragma unroll
        for (int r = 0; r < 4; ++r) {
            float v = acc[ct][r];
            sas[r][hd] += v * sa;
            sad[r][hd] += v * da;
        }
    }
    #pragma unroll
    for (int reg = 0; reg < 4; ++reg) {
        int r = rowbase + quad * 4 + reg;
        if (r < n) {
            #pragma unroll
            for (int ct = 0; ct < 8; ++ct)
                *(unsigned short*)&h[(size_t)r * 128 + ct * 16 + l16] = f2bf(acc[ct][reg]);
        }
    }
    #pragma unroll
    for (int off = 1; off < 16; off <<= 1) {
        #pragma unroll
        for (int r = 0; r < 4; ++r)
            #pragma unroll
            for (int hd = 0; hd < 4; ++hd) {
                sas[r][hd] += __shfl_xor(sas[r][hd], off);
                sad[r][hd] += __shfl_xor(sad[r][hd], off);
            }
    }
    if (l16 == 0) {
        #pragma unroll
        for (int reg = 0; reg < 4; ++reg) {
            int r = rowbase + quad * 4 + reg;
            if (r < n) {
                float4 vs = {sas[reg][0], sas[reg][1], sas[reg][2], sas[reg][3]};
                float4 vd = {sad[reg][0], sad[reg][1], sad[reg][2], sad[reg][3]};
                *(float4*)&a_s[r * 4] = vs;
                *(float4*)&a_d[r * 4] = vd;
            }
        }
    }
}

// ---------------- GAT: wave-per-dst aggregation, softmax without max --------------
__global__ __launch_bounds__(256) void gat_aggr(
    const __hip_bfloat16* __restrict__ h, const float* __restrict__ a_s,
    const float* __restrict__ a_d,
    const int* __restrict__ rowptr, const int* __restrict__ colsrc,
    const float* __restrict__ bias, __hip_bfloat16* __restrict__ out, int n)
{
    __shared__ float s_w[4][64 * 4];
    int t = threadIdx.x;
    int wave = t >> 6, lane = t & 63;
    int d = blockIdx.x * 4 + wave;
    if (d >= n) d = n - 1;                         // duplicate work, benign
    int beg = rowptr[d], end = rowptr[d + 1];
    int cnt = end - beg;
    float4 ad4 = *(const float4*)&a_d[d * 4];
    float4 asd = *(const float4*)&a_s[d * 4];
    float es0 = lrelu(asd.x + ad4.x), es1 = lrelu(asd.y + ad4.y);
    float es2 = lrelu(asd.z + ad4.z), es3 = lrelu(asd.w + ad4.w);
    float z0 = 0.f, z1 = 0.f, z2 = 0.f, z3 = 0.f;   // per-lane partials

    int l16 = lane & 15, egrp = lane >> 4;
    int ch = l16 * 8;                               // channels ch..ch+7
    int head = l16 >> 2;
    float acc[8];
    #pragma unroll
    for (int i = 0; i < 8; ++i) acc[i] = 0.f;

    for (int j0 = 0; j0 < cnt; j0 += 64) {
        int ne = min(64, cnt - j0);
        float w0 = 0.f, w1 = 0.f, w2 = 0.f, w3 = 0.f;
        int s = 0;
        if (lane < ne) {
            s = colsrc[beg + j0 + lane];
            float4 sv = *(const float4*)&a_s[s * 4];
            w0 = __expf(lrelu(sv.x + ad4.x));
            w1 = __expf(lrelu(sv.y + ad4.y));
            w2 = __expf(lrelu(sv.z + ad4.z));
            w3 = __expf(lrelu(sv.w + ad4.w));
        }
        z0 += w0; z1 += w1; z2 += w2; z3 += w3;
        float4 wv = {w0, w1, w2, w3};
        *(float4*)&s_w[wave][lane * 4] = wv;
        __asm volatile("s_waitcnt lgkmcnt(0)" ::: "memory");  // wave-sync LDS
        int kmax = (ne + 3) >> 2;                   // UNIFORM trip count
        for (int k = 0; k < kmax; ++k) {
            int j = egrp + 4 * k;
            int ss = __shfl(s, min(j, 63));         // full-exec shuffle, active src
            if (j < ne) {
                float wj = s_w[wave][j * 4 + head];
                int4 u = *(const int4*)&h[(size_t)ss * 128 + ch];
                acc[0] += wj * bflo(u.x); acc[1] += wj * bfhi(u.x);
                acc[2] += wj * bflo(u.y); acc[3] += wj * bfhi(u.y);
                acc[4] += wj * bflo(u.z); acc[5] += wj * bfhi(u.z);
                acc[6] += wj * bflo(u.w); acc[7] += wj * bfhi(u.w);
            }
        }
    }
    #pragma unroll
    for (int off = 1; off < 64; off <<= 1) {
        z0 += __shfl_xor(z0, off);
        z1 += __shfl_xor(z1, off);
        z2 += __shfl_xor(z2, off);
        z3 += __shfl_xor(z3, off);
    }
    #pragma unroll
    for (int off = 16; off < 64; off <<= 1)
        #pragma unroll
        for (int i = 0; i < 8; ++i) acc[i] += __shfl_xor(acc[i], off);

    if (egrp == 0) {                                // lanes 0..15 write 16B each
        float zh = (head < 2) ? (head == 0 ? z0 : z1) : (head == 2 ? z2 : z3);
        float eh = (head < 2) ? (head == 0 ? es0 : es1) : (head == 2 ? es2 : es3);
        float ws = __expf(eh);                      // self-loop weight
        float inv = 1.f / (zh + ws + 1e-16f);
        int4 hu = *(const int4*)&h[(size_t)d * 128 + ch];
        float hs[8] = {bflo(hu.x), bfhi(hu.x), bflo(hu.y), bfhi(hu.y),
                       bflo(hu.z), bfhi(hu.z), bflo(hu.w), bfhi(hu.w)};
        float4 b0 = *(const float4*)&bias[ch];
        float4 b1 = *(const float4*)&bias[ch + 4];
        float o[8];
        o[0] = fmaxf((acc[0] + ws * hs[0]) * inv + b0.x, 0.f);
        o[1] = fmaxf((acc[1] + ws * hs[1]) * inv + b0.y, 0.f);
        o[2] = fmaxf((acc[2] + ws * hs[2]) * inv + b0.z, 0.f);
        o[3] = fmaxf((acc[3] + ws * hs[3]) * inv + b0.w, 0.f);
        o[4] = fmaxf((acc[4] + ws * hs[4]) * inv + b1.x, 0.f);
        o[5] = fmaxf((acc[5] + ws * hs[5]) * inv + b1.y, 0.f);
        o[6] = fmaxf((acc[6] + ws * hs[6]) * inv + b1.z, 0.f);
        o[7] = fmaxf((acc[7] + ws * hs[7]) * inv + b1.w, 0.f);
        int4 ou;
        ou.x = packbf2(o[0], o[1]); ou.y = packbf2(o[2], o[3]);
        ou.z = packbf2(o[4], o[5]); ou.w = packbf2(o[6], o[7]);
        *(int4*)&out[(size_t)d * 128 + ch] = ou;
    }
}

// ---------------- GraphConv linear: y = x@Wr (bf16), root = x@Wl + b (fp32) -------
__global__ __launch_bounds__(256) void graphconv_lin(
    const __hip_bfloat16* __restrict__ Xb,
    const __hip_bfloat16* __restrict__ Wrt, const __hip_bfloat16* __restrict__ Wlt,
    const float* __restrict__ bias, __hip_bfloat16* __restrict__ y,
    float* __restrict__ root, int n)
{
    __shared__ __align__(16) __hip_bfloat16 sWr[32 * 136], sWl[32 * 136];
    int t = threadIdx.x;
    for (int i = t; i < 32 * 16; i += 256) {
        int row = i >> 4, ch = i & 15;
        *(int4*)&sWr[row * 136 + ch * 8] = *(const int4*)&Wrt[row * 128 + ch * 8];
        *(int4*)&sWl[row * 136 + ch * 8] = *(const int4*)&Wlt[row * 128 + ch * 8];
    }
    __syncthreads();
    int wave = t >> 6, lane = t & 63, quad = lane >> 4, l16 = lane & 15;
    int rowbase = (blockIdx.x * 4 + wave) * 16;
    if (rowbase >= n) return;

    v8bf z;
    #pragma unroll
    for (int i = 0; i < 8; ++i) z[i] = (__bf16)0.f;
    int arow = rowbase + l16;
    bool ok = arow < n;
    const v8bf* px = (const v8bf*)(Xb + (size_t)(ok ? arow : 0) * 128);
    v8bf fx[4];
    #pragma unroll
    for (int ks = 0; ks < 4; ++ks) fx[ks] = ok ? px[ks * 4 + quad] : z;

    v4f accR[2], accL[2];
    #pragma unroll
    for (int ct = 0; ct < 2; ++ct) {
        accR[ct] = (v4f){0.f, 0.f, 0.f, 0.f};
        accL[ct] = (v4f){0.f, 0.f, 0.f, 0.f};
        #pragma unroll
        for (int ks = 0; ks < 4; ++ks) {
            v8bf br = *(const v8bf*)&sWr[(ct * 16 + l16) * 136 + ks * 32 + quad * 8];
            accR[ct] = __builtin_amdgcn_mfma_f32_16x16x32_bf16(fx[ks], br, accR[ct], 0, 0, 0);
            v8bf bl = *(const v8bf*)&sWl[(ct * 16 + l16) * 136 + ks * 32 + quad * 8];
            accL[ct] = __builtin_amdgcn_mfma_f32_16x16x32_bf16(fx[ks], bl, accL[ct], 0, 0, 0);
        }
    }
    #pragma unroll
    for (int ct = 0; ct < 2; ++ct) {
        float bcol = bias[ct * 16 + l16];
        #pragma unroll
        for (int reg = 0; reg < 4; ++reg) {
            int r = rowbase + quad * 4 + reg;
            if (r < n) {
                *(unsigned short*)&y[(size_t)r * 32 + ct * 16 + l16] = f2bf(accR[ct][reg]);
                root[(size_t)r * 32 + ct * 16 + l16] = accL[ct][reg] + bcol;
            }
        }
    }
}

// ---------------- GraphConv aggr: x3 = relu(sum_{src} y[src] + root), 32 ch -------
__global__ __launch_bounds__(256) void graphconv_aggr(
    const __hip_bfloat16* __restrict__ y, const float* __restrict__ root,
    const int* __restrict__ rowptr, const int* __restrict__ colsrc,
    __hip_bfloat16* __restrict__ x3, int n)
{
    int t = threadIdx.x;
    int wave = t >> 6, lane = t & 63;
    int d = blockIdx.x * 4 + wave;
    if (d >= n) d = n - 1;
    int beg = rowptr[d], end = rowptr[d + 1];
    int cnt = end - beg;
    int l4 = lane & 3, egrp = lane >> 2;      // 16 edges concurrent, 4 lanes/row
    int ch = l4 * 8;
    float acc[8];
    #pragma unroll
    for (int i = 0; i < 8; ++i) acc[i] = 0.f;
    for (int j0 = 0; j0 < cnt; j0 += 64) {
        int ne = min(64, cnt - j0);
        int s = (lane < ne) ? colsrc[beg + j0 + lane] : 0;
        int kmax = (ne + 15) >> 4;                  // UNIFORM trip count
        for (int k = 0; k < kmax; ++k) {
            int j = egrp + 16 * k;
            int ss = __shfl(s, min(j, 63));         // full-exec shuffle
            if (j < ne) {
                int4 u = *(const int4*)&y[(size_t)ss * 32 + ch];
                acc[0] += bflo(u.x); acc[1] += bfhi(u.x);
                acc[2] += bflo(u.y); acc[3] += bfhi(u.y);
                acc[4] += bflo(u.z); acc[5] += bfhi(u.z);
                acc[6] += bflo(u.w); acc[7] += bfhi(u.w);
            }
        }
    }
    #pragma unroll
    for (int off = 4; off < 64; off <<= 1)
        #pragma unroll
        for (int i = 0; i < 8; ++i) acc[i] += __shfl_xor(acc[i], off);
    if (egrp == 0) {                           // lanes 0..3 write 16B each
        float4 r0 = *(const float4*)&root[(size_t)d * 32 + ch];
        float4 r1 = *(const float4*)&root[(size_t)d * 32 + ch + 4];
        float o[8];
        o[0] = fmaxf(acc[0] + r0.x, 0.f); o[1] = fmaxf(acc[1] + r0.y, 0.f);
        o[2] = fmaxf(acc[2] + r0.z, 0.f); o[3] = fmaxf(acc[3] + r0.w, 0.f);
        o[4] = fmaxf(acc[4] + r1.x, 0.f); o[5] = fmaxf(acc[5] + r1.y, 0.f);
        o[6] = fmaxf(acc[6] + r1.z, 0.f); o[7] = fmaxf(acc[7] + r1.w, 0.f);
        int4 ou;
        ou.x = packbf2(o[0], o[1]); ou.y = packbf2(o[2], o[3]);
        ou.z = packbf2(o[4], o[5]); ou.w = packbf2(o[6], o[7]);
        *(int4*)&x3[(size_t)d * 32 + ch] = ou;
    }
}

// ---------------- SAGE mean aggregation: wave per dst, 32 ch ----------------------
__global__ __launch_bounds__(256) void mean_aggr32(
    const __hip_bfloat16* __restrict__ x, const int* __restrict__ rowptr,
    const int* __restrict__ colsrc, float* __restrict__ mean, int n)
{
    int t = threadIdx.x;
    int wave = t >> 6, lane = t & 63;
    int d = blockIdx.x * 4 + wave;
    if (d >= n) d = n - 1;
    int beg = rowptr[d], end = rowptr[d + 1];
    int cnt = end - beg;
    int l4 = lane & 3, egrp = lane >> 2;      // 16 edges concurrent, 4 lanes/row
    int ch = l4 * 8;
    float acc[8];
    #pragma unroll
    for (int i = 0; i < 8; ++i) acc[i] = 0.f;
    for (int j0 = 0; j0 < cnt; j0 += 64) {
        int ne = min(64, cnt - j0);
        int s = (lane < ne) ? colsrc[beg + j0 + lane] : 0;
        int kmax = (ne + 15) >> 4;                  // UNIFORM trip count
        for (int k = 0; k < kmax; ++k) {
            int j = egrp + 16 * k;
            int ss = __shfl(s, min(j, 63));         // full-exec shuffle
            if (j < ne) {
                int4 u = *(const int4*)&x[(size_t)ss * 32 + ch];
                acc[0] += bflo(u.x); acc[1] += bfhi(u.x);
                acc[2] += bflo(u.y); acc[3] += bfhi(u.y);
                acc[4] += bflo(u.z); acc[5] += bfhi(u.z);
                acc[6] += bflo(u.w); acc[7] += bfhi(u.w);
            }
        }
    }
    #pragma unroll
    for (int off = 4; off < 64; off <<= 1)
        #pragma unroll
        for (int i = 0; i < 8; ++i) acc[i] += __shfl_xor(acc[i], off);
    if (egrp == 0) {                           // lanes 0..3
        float invd = 1.f / fmaxf((float)cnt, 1.f);
        float4 lo = {acc[0] * invd, acc[1] * invd, acc[2] * invd, acc[3] * invd};
        float4 hi = {acc[4] * invd, acc[5] * invd, acc[6] * invd, acc[7] * invd};
        *(float4*)&mean[(size_t)d * 32 + ch]     = lo;
        *(float4*)&mean[(size_t)d * 32 + ch + 4] = hi;
    }
}

// ---------------- SAGE GEMM: out = relu(mean@Wl + bl + x@Wr), 32->32 --------------
__global__ __launch_bounds__(256) void sage_gemm(
    const float* __restrict__ mean, const __hip_bfloat16* __restrict__ xin,
    const float* __restrict__ Wl, const float* __restrict__ bl,
    const float* __restrict__ Wr, float* __restrict__ out, int n)
{
    __shared__ __align__(16) float sWl[32 * 32], sWr[32 * 32];
    __shared__ __align__(16) float sm[8 * 32], sx[8 * 32];
    int t = threadIdx.x;
    for (int i = t; i < 1024; i += 256) { sWl[i] = Wl[i]; sWr[i] = Wr[i]; }
    int c = t & 31, rr = t >> 5;
    float bc = bl[c];
    for (int row0 = blockIdx.x * 8; row0 < n; row0 += gridDim.x * 8) {
        __syncthreads();
        {
            int i = t;
            int r = i >> 5, cc = i & 31;
            int row = row0 + r;
            sm[i] = (row < n) ? mean[row * 32 + cc] : 0.f;
            sx[i] = (row < n) ? bf2f(xin[row * 32 + cc]) : 0.f;
        }
        __syncthreads();
        float acc = bc;
        const float4* pm = (const float4*)&sm[rr * 32];
        const float4* px = (const float4*)&sx[rr * 32];
        #pragma unroll
        for (int k4 = 0; k4 < 8; ++k4) {
            float4 vm = pm[k4], vx = px[k4];
            const float* wl = &sWl[(k4 * 4) * 32 + c];
            const float* wr = &sWr[(k4 * 4) * 32 + c];
            acc += vm.x * wl[0] + vm.y * wl[32] + vm.z * wl[64] + vm.w * wl[96];
            acc += vx.x * wr[0] + vx.y * wr[32] + vx.z * wr[64] + vx.w * wr[96];
        }
        int row = row0 + rr;
        if (row < n) out[row * 32 + c] = fmaxf(acc, 0.f);
    }
}

// ---------------- global mean pool (batch sorted) ----------------
__device__ __forceinline__ int lower_bound_i(const int* a, int n, int key) {
    int lo = 0, hi = n;
    while (lo < hi) { int mid = (lo + hi) >> 1; if (a[mid] < key) lo = mid + 1; else hi = mid; }
    return lo;
}

__global__ __launch_bounds__(256) void pool_kernel(
    const float* __restrict__ x, const int* __restrict__ batch,
    float* __restrict__ gpool, int n)
{
    int g = blockIdx.x;
    int lo = lower_bound_i(batch, n, g);
    int hi = lower_bound_i(batch, n, g + 1);
    int t = threadIdx.x;
    int c = t & 31, rr = t >> 5;
    float acc = 0.f;
    for (int i = lo + rr; i < hi; i += 8) acc += x[i * 32 + c];
    __shared__ float sred[256];
    sred[t] = acc;
    __syncthreads();
    if (t < 128) sred[t] += sred[t + 128];
    __syncthreads();
    if (t < 64) sred[t] += sred[t + 64];
    __syncthreads();
    if (t < 32) {
        float v = sred[t] + sred[t + 32];
        gpool[g * 32 + t] = v / fmaxf((float)(hi - lo), 1.f);
    }
}

// ---------------- MLP head ----------------
__global__ __launch_bounds__(256) void head_kernel(
    const float* __restrict__ gpool, const float* __restrict__ Wf1, const float* __restrict__ bf1,
    const float* __restrict__ Wf2, const float* __restrict__ bf2, float* __restrict__ out)
{
    __shared__ float sg[64 * 32], st[64 * 32];
    __shared__ float sW1[32 * 32], sW2[32 * 10];
    int t = threadIdx.x;
    for (int i = t; i < 2048; i += 256) sg[i] = gpool[i];
    for (int i = t; i < 1024; i += 256) sW1[i] = Wf1[i];
    for (int i = t; i < 320; i += 256) sW2[i] = Wf2[i];
    __syncthreads();
    for (int i = t; i < 2048; i += 256) {
        int g = i >> 5, c = i & 31;
        float acc = bf1[c];
        #pragma unroll
        for (int k = 0; k < 32; ++k) acc += sg[g * 32 + k] * sW1[k * 32 + c];
        st[i] = fmaxf(acc, 0.f);
    }
    __syncthreads();
    for (int i = t; i < 640; i += 256) {
        int g = i / 10, o = i - g * 10;
        float acc = bf2[o];
        #pragma unroll
        for (int k = 0; k < 32; ++k) acc += st[g * 32 + k] * sW2[k * 10 + o];
        out[i] = acc;
    }
}

extern "C" void kernel_launch(void* const* d_in, const int* in_sizes, int n_in,
                              void* d_out, int out_size, void* d_ws, size_t ws_size,
                              hipStream_t stream) {
    const float* x    = (const float*)d_in[0];
    const int*   ei   = (const int*)d_in[1];
    const int*   batch= (const int*)d_in[2];
    const float* W1   = (const float*)d_in[3];
    const float* as1  = (const float*)d_in[4];
    const float* ad1  = (const float*)d_in[5];
    const float* b1   = (const float*)d_in[6];
    const float* W2   = (const float*)d_in[7];
    const float* as2  = (const float*)d_in[8];
    const float* ad2  = (const float*)d_in[9];
    const float* b2   = (const float*)d_in[10];
    const float* W3r  = (const float*)d_in[11];
    const float* W3l  = (const float*)d_in[12];
    const float* b3   = (const float*)d_in[13];
    const float* W4l  = (const float*)d_in[14];
    const float* b4l  = (const float*)d_in[15];
    const float* W4r  = (const float*)d_in[16];
    const float* Wf1  = (const float*)d_in[17];
    const float* bf1  = (const float*)d_in[18];
    const float* Wf2  = (const float*)d_in[19];
    const float* bf2  = (const float*)d_in[20];

    const int N = in_sizes[0] / 128;
    const int E = in_sizes[1] / 2;
    const int* src = ei;
    const int* dst = ei + E;

    char* p = (char*)d_ws;
    auto alloc = [&](size_t bytes) -> void* {
        void* r = (void*)p;
        p += (bytes + 255) & ~(size_t)255;
        return r;
    };
    __hip_bfloat16* buf1 = (__hip_bfloat16*)alloc((size_t)N * 128 * 2);  // x2 / X4
    __hip_bfloat16* buf2 = (__hip_bfloat16*)alloc((size_t)N * 128 * 2);  // x1 / x3+mean
    __hip_bfloat16* buf3 = (__hip_bfloat16*)alloc((size_t)N * 128 * 2);  // pairs / h1,h2 / y+root
    float* aS     = (float*)alloc((size_t)N * 4 * 4);
    float* aD     = (float*)alloc((size_t)N * 4 * 4);
    int*   rowptr = (int*)alloc((size_t)(N + 1) * 4);
    int*   colsrc = (int*)alloc((size_t)E * 4);
    int*   bcount = (int*)alloc(256 * 4);
    int*   bbase  = (int*)alloc(257 * 4);
    int*   gcursor= (int*)alloc(256 * 4);
    __hip_bfloat16* W1t  = (__hip_bfloat16*)alloc(128 * 128 * 2);
    __hip_bfloat16* W2t  = (__hip_bfloat16*)alloc(128 * 128 * 2);
    __hip_bfloat16* W3rt = (__hip_bfloat16*)alloc(32 * 128 * 2);
    __hip_bfloat16* W3lt = (__hip_bfloat16*)alloc(32 * 128 * 2);
    float* gpool  = (float*)alloc(64 * 32 * 4);

    // aliased views
    __hip_bfloat16* X3b  = buf2;                                        // N*32 bf16
    float*          MEAN = (float*)((char*)buf2 + (((size_t)N * 32 * 2 + 255) & ~(size_t)255));
    float*          X4   = (float*)buf1;                                // N*32 fp32
    __hip_bfloat16* Y32  = buf3;                                        // N*32 bf16
    float*          ROOT = (float*)((char*)buf3 + (((size_t)N * 32 * 2 + 255) & ~(size_t)255));
    int*            pairs = (int*)buf3;   // E*4 B, consumed before h is written

    const int nbuck = (N + 255) >> 8;     // 196 for N=50000 (requires N<=65536)

    // ---- bucketed CSR build ----
    hipMemsetAsync(bcount, 0, 256 * 4, stream);
    bucket_hist<<<(E + 4095) / 4096, 256, 0, stream>>>(dst, bcount, E, nbuck);
    scan_buckets<<<1, 256, 0, stream>>>(bcount, bbase, gcursor, nbuck, E, rowptr, N);
    bucket_scatter<<<(E + 2047) / 2048, 256, 0, stream>>>(dst, src, gcursor, pairs, E, nbuck);
    bucket_fill<<<nbuck, 256, 0, stream>>>(pairs, bbase, rowptr, colsrc, N);

    // weight prep (single launch)
    convert_weights<<<64, 256, 0, stream>>>(W1, W2, W3r, W3l, W1t, W2t, W3rt, W3lt);

    const int gmm = (N + 63) / 64;
    const int gag = (N + 3) / 4;
    // GAT layer 1 (reads fp32 x directly)
    gemm_att_mfma<float><<<gmm, 256, 0, stream>>>(x, W1t, as1, ad1, buf3, aS, aD, N);
    gat_aggr<<<gag, 256, 0, stream>>>(buf3, aS, aD, rowptr, colsrc, b1, buf2, N);
    // GAT layer 2
    gemm_att_mfma<__hip_bfloat16><<<gmm, 256, 0, stream>>>(buf2, W2t, as2, ad2, buf3, aS, aD, N);
    gat_aggr<<<gag, 256, 0, stream>>>(buf3, aS, aD, rowptr, colsrc, b2, buf1, N);
    // GraphConv (project first, then 64B-row gather)
    graphconv_lin<<<gmm, 256, 0, stream>>>(buf1, W3rt, W3lt, b3, Y32, ROOT, N);
    graphconv_aggr<<<gag, 256, 0, stream>>>(Y32, ROOT, rowptr, colsrc, X3b, N);
    // SAGE
    mean_aggr32<<<gag, 256, 0, stream>>>(X3b, rowptr, colsrc, MEAN, N);
    sage_gemm<<<1024, 256, 0, stream>>>(MEAN, X3b, W4l, b4l, W4r, X4, N);
    // pool + head
    pool_kernel<<<64, 256, 0, stream>>>(X4, batch, gpool, N);
    head_kernel<<<1, 256, 0, stream>>>(gpool, Wf1, bf1, Wf2, bf2, (float*)d_out);
}

// Round 8
// 357.429 us; speedup vs baseline: 2.6407x; 1.0103x over previous
//
#include <hip/hip_runtime.h>
#include <hip/hip_bf16.h>
#include <type_traits>

// GNN: GAT(128->4x32) -> GAT(128->4x32) -> GraphConv(128->32) -> SAGE(32->32)
//      -> global mean pool (64 graphs) -> MLP(32->32->10)
// R1: CSR gather aggregation, fp32.                         944 us
// R2: bf16 features + cooperative alpha.                    782 us
// R3: parallel scan + MFMA bf16 GEMMs.                      523 us
// R4: wave-per-dst aggr — FAILED (shfl from exec-inactive lane).
// R5: fixed wave-per-dst single-pass aggr.                  460 us
// R6: no-max softmax, GraphConv linearity reorder.          419 us
// R7: bucketed CSR build (counting sort by dst>>8).         361 us
// R8: branchless gat_aggr inner loop (predicate was redundant: s_w==0 for
//     pad lanes) + unroll 2; attention dots fused into GEMM as 16 extra
//     weight columns (Vs/Vd hi+lo bf16 split); scan+convert merged.

typedef __bf16 v8bf __attribute__((ext_vector_type(8)));
typedef float  v4f  __attribute__((ext_vector_type(4)));

__device__ __forceinline__ float lrelu(float x) { return x > 0.f ? x : 0.2f * x; }

__device__ __forceinline__ unsigned short f2bf(float f) {
    unsigned u = __float_as_uint(f);
    unsigned r = (u + 0x7FFF + ((u >> 16) & 1)) >> 16;   // RNE
    return (unsigned short)r;
}
__device__ __forceinline__ float bfbits2f(unsigned short u) {
    return __uint_as_float((unsigned)u << 16);
}
__device__ __forceinline__ float bflo(int v) { return __uint_as_float((unsigned)v << 16); }
__device__ __forceinline__ float bfhi(int v) { return __uint_as_float((unsigned)v & 0xffff0000u); }
__device__ __forceinline__ int packbf2(float a, float b) {
    return (int)f2bf(a) | ((int)f2bf(b) << 16);
}

// ================= bucketed CSR build =================
// bucket = dst >> 8 (256 dst per bucket); pairs word = (dst&255)<<17 | src.

__global__ __launch_bounds__(256) void bucket_hist(const int* __restrict__ dst,
                                                   int* __restrict__ bcount,
                                                   int E, int nbuck) {
    __shared__ int hist[256];
    int t = threadIdx.x;
    for (int i = t; i < nbuck; i += 256) hist[i] = 0;
    __syncthreads();
    int base = blockIdx.x * 4096;
    #pragma unroll
    for (int k = 0; k < 16; ++k) {
        int e = base + k * 256 + t;
        if (e < E) atomicAdd(&hist[dst[e] >> 8], 1);
    }
    __syncthreads();
    for (int i = t; i < nbuck; i += 256) {
        int c = hist[i];
        if (c) atomicAdd(&bcount[i], c);
    }
}

// block 0: scan bucket counts. blocks 1..64: weight prep (transpose+bf16 and
// attention-dot columns Vs/Vd in hi+lo bf16 split appended as rows 128..143).
__global__ __launch_bounds__(256) void scan_convert(
    const int* __restrict__ bcount, int* __restrict__ bbase, int* __restrict__ gcursor,
    int nbuck, int E, int* __restrict__ rowptr, int n,
    const float* __restrict__ W1, const float* __restrict__ W2,
    const float* __restrict__ W3r, const float* __restrict__ W3l,
    const float* __restrict__ as1, const float* __restrict__ ad1,
    const float* __restrict__ as2, const float* __restrict__ ad2,
    __hip_bfloat16* __restrict__ W1t, __hip_bfloat16* __restrict__ W2t,
    __hip_bfloat16* __restrict__ W3rt, __hip_bfloat16* __restrict__ W3lt)
{
    int t = threadIdx.x;
    if (blockIdx.x == 0) {
        __shared__ int red[256];
        int v = (t < nbuck) ? bcount[t] : 0;
        red[t] = v;
        __syncthreads();
        for (int off = 1; off < 256; off <<= 1) {
            int u = (t >= off) ? red[t - off] : 0;
            __syncthreads();
            red[t] += u;
            __syncthreads();
        }
        int ex = red[t] - v;
        if (t < nbuck) { bbase[t] = ex; gcursor[t] = ex; }
        if (t == 0) { bbase[nbuck] = E; rowptr[n] = E; }
        return;
    }
    int b = blockIdx.x - 1;                 // 0..63
    int i = b * 256 + t;                    // 0..16383
    {   // transpose W1/W2 into rows 0..127 of the 144-row layout
        int k = i >> 7, c = i & 127;
        *(unsigned short*)&W1t[c * 128 + k] = f2bf(W1[i]);
        *(unsigned short*)&W2t[c * 128 + k] = f2bf(W2[i]);
    }
    if (i < 4096) {
        int k = i >> 5, c = i & 31;
        *(unsigned short*)&W3rt[c * 128 + k] = f2bf(W3r[i]);
        *(unsigned short*)&W3lt[c * 128 + k] = f2bf(W3l[i]);
    }
    if (b == 0) {                           // attention-dot columns: 512 units
        for (int u = t; u < 512; u += 256) {
            int k = u & 127, hd = u >> 7;
            float vs1 = 0.f, vd1 = 0.f, vs2 = 0.f, vd2 = 0.f;
            #pragma unroll
            for (int j = 0; j < 32; ++j) {
                int c = hd * 32 + j;
                float w1 = W1[k * 128 + c], w2 = W2[k * 128 + c];
                vs1 += w1 * as1[c]; vd1 += w1 * ad1[c];
                vs2 += w2 * as2[c]; vd2 += w2 * ad2[c];
            }
            unsigned short h1s = f2bf(vs1), h1d = f2bf(vd1);
            unsigned short h2s = f2bf(vs2), h2d = f2bf(vd2);
            *(unsigned short*)&W1t[(128 + hd) * 128 + k] = h1s;
            *(unsigned short*)&W1t[(132 + hd) * 128 + k] = f2bf(vs1 - bfbits2f(h1s));
            *(unsigned short*)&W1t[(136 + hd) * 128 + k] = h1d;
            *(unsigned short*)&W1t[(140 + hd) * 128 + k] = f2bf(vd1 - bfbits2f(h1d));
            *(unsigned short*)&W2t[(128 + hd) * 128 + k] = h2s;
            *(unsigned short*)&W2t[(132 + hd) * 128 + k] = f2bf(vs2 - bfbits2f(h2s));
            *(unsigned short*)&W2t[(136 + hd) * 128 + k] = h2d;
            *(unsigned short*)&W2t[(140 + hd) * 128 + k] = f2bf(vd2 - bfbits2f(h2d));
        }
    }
}

__global__ __launch_bounds__(256) void bucket_scatter(const int* __restrict__ dst,
                                                      const int* __restrict__ src,
                                                      int* __restrict__ gcursor,
                                                      int* __restrict__ pairs,
                                                      int E, int nbuck) {
    __shared__ int hist[256], lcur[256];
    int t = threadIdx.x;
    for (int i = t; i < nbuck; i += 256) hist[i] = 0;
    __syncthreads();
    int base = blockIdx.x * 2048;
    int dreg[8];
    #pragma unroll
    for (int k = 0; k < 8; ++k) {
        int e = base + k * 256 + t;
        int d = (e < E) ? dst[e] : -1;
        dreg[k] = d;
        if (d >= 0) atomicAdd(&hist[d >> 8], 1);
    }
    __syncthreads();
    for (int i = t; i < nbuck; i += 256) {
        int c = hist[i];
        lcur[i] = c ? atomicAdd(&gcursor[i], c) : 0;   // reserve contiguous run
    }
    __syncthreads();
    #pragma unroll
    for (int k = 0; k < 8; ++k) {
        int e = base + k * 256 + t;
        if (e < E) {
            int d = dreg[k];
            int p = atomicAdd(&lcur[d >> 8], 1);
            pairs[p] = ((d & 255) << 17) | src[e];
        }
    }
}

__global__ __launch_bounds__(256) void bucket_fill(const int* __restrict__ pairs,
                                                   const int* __restrict__ bbase,
                                                   int* __restrict__ rowptr,
                                                   int* __restrict__ colsrc, int n) {
    __shared__ int deg[256], excl[256], cur[256];
    int b = blockIdx.x, t = threadIdx.x;
    int e0 = bbase[b], e1 = bbase[b + 1];
    int d0 = b << 8;
    deg[t] = 0;
    __syncthreads();
    for (int j = e0 + t; j < e1; j += 256)
        atomicAdd(&deg[pairs[j] >> 17], 1);
    __syncthreads();
    int v = deg[t];
    excl[t] = v;
    __syncthreads();
    for (int off = 1; off < 256; off <<= 1) {
        int u = (t >= off) ? excl[t - off] : 0;
        __syncthreads();
        excl[t] += u;
        __syncthreads();
    }
    int base = e0 + excl[t] - v;                   // exclusive
    if (d0 + t < n) rowptr[d0 + t] = base;
    cur[t] = base;
    __syncthreads();
    for (int j = e0 + t; j < e1; j += 256) {
        int w = pairs[j];
        int p = atomicAdd(&cur[w >> 17], 1);
        colsrc[p] = w & 0x1FFFF;
    }
}

// ---------------- GAT GEMM via MFMA: [h | a_s | a_d] = X @ Wt(144 cols) ----------
template <typename T>
__global__ __launch_bounds__(256) void gemm_att_mfma(
    const T* __restrict__ X, const __hip_bfloat16* __restrict__ Wt,
    __hip_bfloat16* __restrict__ h, float* __restrict__ a_s, float* __restrict__ a_d, int n)
{
    __shared__ __align__(16) __hip_bfloat16 sWt[144 * 136];   // [col][k], +8 pad
    int t = threadIdx.x;
    for (int i = t; i < 144 * 16; i += 256) {
        int row = i >> 4, ch = i & 15;
        *(int4*)&sWt[row * 136 + ch * 8] = *(const int4*)&Wt[row * 128 + ch * 8];
    }
    __syncthreads();
    int wave = t >> 6, lane = t & 63, quad = lane >> 4, l16 = lane & 15;
    int rowbase = (blockIdx.x * 4 + wave) * 16;
    if (rowbase >= n) return;

    v8bf z;
    #pragma unroll
    for (int i = 0; i < 8; ++i) z[i] = (__bf16)0.f;
    int arow = rowbase + l16;
    bool ok = arow < n;
    v8bf af[4];
    if constexpr (std::is_same<T, float>::value) {
        const float* xf = X + (size_t)(ok ? arow : 0) * 128;
        #pragma unroll
        for (int ks = 0; ks < 4; ++ks) {
            if (ok) {
                float4 u = *(const float4*)&xf[ks * 32 + quad * 8];
                float4 v = *(const float4*)&xf[ks * 32 + quad * 8 + 4];
                v8bf a;
                unsigned short r;
                r = f2bf(u.x); a[0] = *(__bf16*)&r;
                r = f2bf(u.y); a[1] = *(__bf16*)&r;
                r = f2bf(u.z); a[2] = *(__bf16*)&r;
                r = f2bf(u.w); a[3] = *(__bf16*)&r;
                r = f2bf(v.x); a[4] = *(__bf16*)&r;
                r = f2bf(v.y); a[5] = *(__bf16*)&r;
                r = f2bf(v.z); a[6] = *(__bf16*)&r;
                r = f2bf(v.w); a[7] = *(__bf16*)&r;
                af[ks] = a;
            } else af[ks] = z;
        }
    } else {
        const v8bf* px = (const v8bf*)(X + (size_t)(ok ? arow : 0) * 128);
        #pragma unroll
        for (int ks = 0; ks < 4; ++ks) af[ks] = ok ? px[ks * 4 + quad] : z;
    }

    v4f acc[9];
    #pragma unroll
    for (int ct = 0; ct < 9; ++ct) acc[ct] = (v4f){0.f, 0.f, 0.f, 0.f};
    #pragma unroll
    for (int ct = 0; ct < 9; ++ct) {
        #pragma unroll
        for (int ks = 0; ks < 4; ++ks) {
            v8bf b = *(const v8bf*)&sWt[(ct * 16 + l16) * 136 + ks * 32 + quad * 8];
            acc[ct] = __builtin_amdgcn_mfma_f32_16x16x32_bf16(af[ks], b, acc[ct], 0, 0, 0);
        }
    }

    // h store (tiles 0..7): C layout col=l16, row=quad*4+reg
    #pragma unroll
    for (int reg = 0; reg < 4; ++reg) {
        int r = rowbase + quad * 4 + reg;
        if (r < n) {
            #pragma unroll
            for (int ct = 0; ct < 8; ++ct)
                *(unsigned short*)&h[(size_t)r * 128 + ct * 16 + l16] = f2bf(acc[ct][reg]);
        }
    }
    // tile 8 = attention dots: cols l16: 0-3 s_hi, 4-7 s_lo, 8-11 d_hi, 12-15 d_lo
    #pragma unroll
    for (int reg = 0; reg < 4; ++reg) {
        float v = acc[8][reg] + __shfl_xor(acc[8][reg], 4);   // hi + lo
        int r = rowbase + quad * 4 + reg;
        if (r < n) {
            if (l16 < 4)                    a_s[r * 4 + l16] = v;
            else if (l16 >= 8 && l16 < 12)  a_d[r * 4 + (l16 - 8)] = v;
        }
    }
}

// ---------------- GAT: wave-per-dst aggregation, branchless inner loop ------------
__global__ __launch_bounds__(256) void gat_aggr(
    const __hip_bfloat16* __restrict__ h, const float* __restrict__ a_s,
    const float* __restrict__ a_d,
    const int* __restrict__ rowptr, const int* __restrict__ colsrc,
    const float* __restrict__ bias, __hip_bfloat16* __restrict__ out, int n)
{
    __shared__ float s_w[4][64 * 4];
    int t = threadIdx.x;
    int wave = t >> 6, lane = t & 63;
    int d = blockIdx.x * 4 + wave;
    if (d >= n) d = n - 1;                         // duplicate work, benign
    int beg = rowptr[d], end = rowptr[d + 1];
    int cnt = end - beg;
    float4 ad4 = *(const float4*)&a_d[d * 4];
    float4 asd = *(const float4*)&a_s[d * 4];
    float es0 = lrelu(asd.x + ad4.x), es1 = lrelu(asd.y + ad4.y);
    float es2 = lrelu(asd.z + ad4.z), es3 = lrelu(asd.w + ad4.w);
    float z0 = 0.f, z1 = 0.f, z2 = 0.f, z3 = 0.f;   // per-lane partials

    int l16 = lane & 15, egrp = lane >> 4;
    int ch = l16 * 8;                               // channels ch..ch+7
    int head = l16 >> 2;
    float acc[8];
    #pragma unroll
    for (int i = 0; i < 8; ++i) acc[i] = 0.f;

    for (int j0 = 0; j0 < cnt; j0 += 64) {
        int ne = min(64, cnt - j0);
        float w0 = 0.f, w1 = 0.f, w2 = 0.f, w3 = 0.f;
        int s = 0;                                  // row 0 is a valid address
        if (lane < ne) {
            s = colsrc[beg + j0 + lane];
            float4 sv = *(const float4*)&a_s[s * 4];
            w0 = __expf(lrelu(sv.x + ad4.x));
            w1 = __expf(lrelu(sv.y + ad4.y));
            w2 = __expf(lrelu(sv.z + ad4.z));
            w3 = __expf(lrelu(sv.w + ad4.w));
        }
        z0 += w0; z1 += w1; z2 += w2; z3 += w3;
        float4 wv = {w0, w1, w2, w3};               // zeros for pad lanes
        *(float4*)&s_w[wave][lane * 4] = wv;
        __asm volatile("s_waitcnt lgkmcnt(0)" ::: "memory");  // wave-sync LDS
        // BRANCHLESS: j <= 63 always; s_w[j]==0 and s==0 for pad lanes, so
        // the pad iterations contribute exactly 0 with a valid (cached) load.
        int kmax = (ne + 3) >> 2;                   // uniform trip count
        #pragma unroll 2
        for (int k = 0; k < kmax; ++k) {
            int j = egrp + 4 * k;
            int ss = __shfl(s, j);
            float wj = s_w[wave][j * 4 + head];
            int4 u = *(const int4*)&h[(size_t)ss * 128 + ch];
            acc[0] += wj * bflo(u.x); acc[1] += wj * bfhi(u.x);
            acc[2] += wj * bflo(u.y); acc[3] += wj * bfhi(u.y);
            acc[4] += wj * bflo(u.z); acc[5] += wj * bfhi(u.z);
            acc[6] += wj * bflo(u.w); acc[7] += wj * bfhi(u.w);
        }
    }
    #pragma unroll
    for (int off = 1; off < 64; off <<= 1) {
        z0 += __shfl_xor(z0, off);
        z1 += __shfl_xor(z1, off);
        z2 += __shfl_xor(z2, off);
        z3 += __shfl_xor(z3, off);
    }
    #pragma unroll
    for (int off = 16; off < 64; off <<= 1)
        #pragma unroll
        for (int i = 0; i < 8; ++i) acc[i] += __shfl_xor(acc[i], off);

    if (egrp == 0) {                                // lanes 0..15 write 16B each
        float zh = (head < 2) ? (head == 0 ? z0 : z1) : (head == 2 ? z2 : z3);
        float eh = (head < 2) ? (head == 0 ? es0 : es1) : (head == 2 ? es2 : es3);
        float ws = __expf(eh);                      // self-loop weight
        float inv = 1.f / (zh + ws + 1e-16f);
        int4 hu = *(const int4*)&h[(size_t)d * 128 + ch];
        float hs[8] = {bflo(hu.x), bfhi(hu.x), bflo(hu.y), bfhi(hu.y),
                       bflo(hu.z), bfhi(hu.z), bflo(hu.w), bfhi(hu.w)};
        float4 b0 = *(const float4*)&bias[ch];
        float4 b1 = *(const float4*)&bias[ch + 4];
        float o[8];
        o[0] = fmaxf((acc[0] + ws * hs[0]) * inv + b0.x, 0.f);
        o[1] = fmaxf((acc[1] + ws * hs[1]) * inv + b0.y, 0.f);
        o[2] = fmaxf((acc[2] + ws * hs[2]) * inv + b0.z, 0.f);
        o[3] = fmaxf((acc[3] + ws * hs[3]) * inv + b0.w, 0.f);
        o[4] = fmaxf((acc[4] + ws * hs[4]) * inv + b1.x, 0.f);
        o[5] = fmaxf((acc[5] + ws * hs[5]) * inv + b1.y, 0.f);
        o[6] = fmaxf((acc[6] + ws * hs[6]) * inv + b1.z, 0.f);
        o[7] = fmaxf((acc[7] + ws * hs[7]) * inv + b1.w, 0.f);
        int4 ou;
        ou.x = packbf2(o[0], o[1]); ou.y = packbf2(o[2], o[3]);
        ou.z = packbf2(o[4], o[5]); ou.w = packbf2(o[6], o[7]);
        *(int4*)&out[(size_t)d * 128 + ch] = ou;
    }
}

// ---------------- GraphConv linear: y = x@Wr (bf16), root = x@Wl + b (fp32) -------
__global__ __launch_bounds__(256) void graphconv_lin(
    const __hip_bfloat16* __restrict__ Xb,
    const __hip_bfloat16* __restrict__ Wrt, const __hip_bfloat16* __restrict__ Wlt,
    const float* __restrict__ bias, __hip_bfloat16* __restrict__ y,
    float* __restrict__ root, int n)
{
    __shared__ __align__(16) __hip_bfloat16 sWr[32 * 136], sWl[32 * 136];
    int t = threadIdx.x;
    for (int i = t; i < 32 * 16; i += 256) {
        int row = i >> 4, ch = i & 15;
        *(int4*)&sWr[row * 136 + ch * 8] = *(const int4*)&Wrt[row * 128 + ch * 8];
        *(int4*)&sWl[row * 136 + ch * 8] = *(const int4*)&Wlt[row * 128 + ch * 8];
    }
    __syncthreads();
    int wave = t >> 6, lane = t & 63, quad = lane >> 4, l16 = lane & 15;
    int rowbase = (blockIdx.x * 4 + wave) * 16;
    if (rowbase >= n) return;

    v8bf z;
    #pragma unroll
    for (int i = 0; i < 8; ++i) z[i] = (__bf16)0.f;
    int arow = rowbase + l16;
    bool ok = arow < n;
    const v8bf* px = (const v8bf*)(Xb + (size_t)(ok ? arow : 0) * 128);
    v8bf fx[4];
    #pragma unroll
    for (int ks = 0; ks < 4; ++ks) fx[ks] = ok ? px[ks * 4 + quad] : z;

    v4f accR[2], accL[2];
    #pragma unroll
    for (int ct = 0; ct < 2; ++ct) {
        accR[ct] = (v4f){0.f, 0.f, 0.f, 0.f};
        accL[ct] = (v4f){0.f, 0.f, 0.f, 0.f};
        #pragma unroll
        for (int ks = 0; ks < 4; ++ks) {
            v8bf br = *(const v8bf*)&sWr[(ct * 16 + l16) * 136 + ks * 32 + quad * 8];
            accR[ct] = __builtin_amdgcn_mfma_f32_16x16x32_bf16(fx[ks], br, accR[ct], 0, 0, 0);
            v8bf bl = *(const v8bf*)&sWl[(ct * 16 + l16) * 136 + ks * 32 + quad * 8];
            accL[ct] = __builtin_amdgcn_mfma_f32_16x16x32_bf16(fx[ks], bl, accL[ct], 0, 0, 0);
        }
    }
    #pragma unroll
    for (int ct = 0; ct < 2; ++ct) {
        float bcol = bias[ct * 16 + l16];
        #pragma unroll
        for (int reg = 0; reg < 4; ++reg) {
            int r = rowbase + quad * 4 + reg;
            if (r < n) {
                *(unsigned short*)&y[(size_t)r * 32 + ct * 16 + l16] = f2bf(accR[ct][reg]);
                root[(size_t)r * 32 + ct * 16 + l16] = accL[ct][reg] + bcol;
            }
        }
    }
}

// ---------------- GraphConv aggr: x3 = relu(sum_{src} y[src] + root), 32 ch -------
__global__ __launch_bounds__(256) void graphconv_aggr(
    const __hip_bfloat16* __restrict__ y, const float* __restrict__ root,
    const int* __restrict__ rowptr, const int* __restrict__ colsrc,
    __hip_bfloat16* __restrict__ x3, int n)
{
    int t = threadIdx.x;
    int wave = t >> 6, lane = t & 63;
    int d = blockIdx.x * 4 + wave;
    if (d >= n) d = n - 1;
    int beg = rowptr[d], end = rowptr[d + 1];
    int cnt = end - beg;
    int l4 = lane & 3, egrp = lane >> 2;      // 16 edges concurrent, 4 lanes/row
    int ch = l4 * 8;
    float acc[8];
    #pragma unroll
    for (int i = 0; i < 8; ++i) acc[i] = 0.f;
    for (int j0 = 0; j0 < cnt; j0 += 64) {
        int ne = min(64, cnt - j0);
        int s = (lane < ne) ? colsrc[beg + j0 + lane] : 0;
        int kmax = (ne + 15) >> 4;                  // uniform trip count
        #pragma unroll 2
        for (int k = 0; k < kmax; ++k) {
            int j = egrp + 16 * k;                  // <= 63 always
            int ss = __shfl(s, j);
            float m = (j < ne) ? 1.f : 0.f;         // branchless mask
            int4 u = *(const int4*)&y[(size_t)ss * 32 + ch];
            acc[0] += m * bflo(u.x); acc[1] += m * bfhi(u.x);
            acc[2] += m * bflo(u.y); acc[3] += m * bfhi(u.y);
            acc[4] += m * bflo(u.z); acc[5] += m * bfhi(u.z);
            acc[6] += m * bflo(u.w); acc[7] += m * bfhi(u.w);
        }
    }
    #pragma unroll
    for (int off = 4; off < 64; off <<= 1)
        #pragma unroll
        for (int i = 0; i < 8; ++i) acc[i] += __shfl_xor(acc[i], off);
    if (egrp == 0) {                           // lanes 0..3 write 16B each
        float4 r0 = *(const float4*)&root[(size_t)d * 32 + ch];
        float4 r1 = *(const float4*)&root[(size_t)d * 32 + ch + 4];
        float o[8];
        o[0] = fmaxf(acc[0] + r0.x, 0.f); o[1] = fmaxf(acc[1] + r0.y, 0.f);
        o[2] = fmaxf(acc[2] + r0.z, 0.f); o[3] = fmaxf(acc[3] + r0.w, 0.f);
        o[4] = fmaxf(acc[4] + r1.x, 0.f); o[5] = fmaxf(acc[5] + r1.y, 0.f);
        o[6] = fmaxf(acc[6] + r1.z, 0.f); o[7] = fmaxf(acc[7] + r1.w, 0.f);
        int4 ou;
        ou.x = packbf2(o[0], o[1]); ou.y = packbf2(o[2], o[3]);
        ou.z = packbf2(o[4], o[5]); ou.w = packbf2(o[6], o[7]);
        *(int4*)&x3[(size_t)d * 32 + ch] = ou;
    }
}

// ---------------- SAGE mean aggregation: wave per dst, 32 ch ----------------------
__global__ __launch_bounds__(256) void mean_aggr32(
    const __hip_bfloat16* __restrict__ x, const int* __restrict__ rowptr,
    const int* __restrict__ colsrc, float* __restrict__ mean, int n)
{
    int t = threadIdx.x;
    int wave = t >> 6, lane = t & 63;
    int d = blockIdx.x * 4 + wave;
    if (d >= n) d = n - 1;
    int beg = rowptr[d], end = rowptr[d + 1];
    int cnt = end - beg;
    int l4 = lane & 3, egrp = lane >> 2;
    int ch = l4 * 8;
    float acc[8];
    #pragma unroll
    for (int i = 0; i < 8; ++i) acc[i] = 0.f;
    for (int j0 = 0; j0 < cnt; j0 += 64) {
        int ne = min(64, cnt - j0);
        int s = (lane < ne) ? colsrc[beg + j0 + lane] : 0;
        int kmax = (ne + 15) >> 4;
        #pragma unroll 2
        for (int k = 0; k < kmax; ++k) {
            int j = egrp + 16 * k;
            int ss = __shfl(s, j);
            float m = (j < ne) ? 1.f : 0.f;
            int4 u = *(const int4*)&x[(size_t)ss * 32 + ch];
            acc[0] += m * bflo(u.x); acc[1] += m * bfhi(u.x);
            acc[2] += m * bflo(u.y); acc[3] += m * bfhi(u.y);
            acc[4] += m * bflo(u.z); acc[5] += m * bfhi(u.z);
            acc[6] += m * bflo(u.w); acc[7] += m * bfhi(u.w);
        }
    }
    #pragma unroll
    for (int off = 4; off < 64; off <<= 1)
        #pragma unroll
        for (int i = 0; i < 8; ++i) acc[i] += __shfl_xor(acc[i], off);
    if (egrp == 0) {
        float invd = 1.f / fmaxf((float)cnt, 1.f);
        float4 lo = {acc[0] * invd, acc[1] * invd, acc[2] * invd, acc[3] * invd};
        float4 hi = {acc[4] * invd, acc[5] * invd, acc[6] * invd, acc[7] * invd};
        *(float4*)&mean[(size_t)d * 32 + ch]     = lo;
        *(float4*)&mean[(size_t)d * 32 + ch + 4] = hi;
    }
}

// ---------------- SAGE GEMM: out = relu(mean@Wl + bl + x@Wr), 32->32 --------------
__global__ __launch_bounds__(256) void sage_gemm(
    const float* __restrict__ mean, const __hip_bfloat16* __restrict__ xin,
    const float* __restrict__ Wl, const float* __restrict__ bl,
    const float* __restrict__ Wr, float* __restrict__ out, int n)
{
    __shared__ __align__(16) float sWl[32 * 32], sWr[32 * 32];
    __shared__ __align__(16) float sm[8 * 32], sx[8 * 32];
    int t = threadIdx.x;
    for (int i = t; i < 1024; i += 256) { sWl[i] = Wl[i]; sWr[i] = Wr[i]; }
    int c = t & 31, rr = t >> 5;
    float bc = bl[c];
    for (int row0 = blockIdx.x * 8; row0 < n; row0 += gridDim.x * 8) {
        __syncthreads();
        {
            int i = t;
            int r = i >> 5, cc = i & 31;
            int row = row0 + r;
            sm[i] = (row < n) ? mean[row * 32 + cc] : 0.f;
            sx[i] = (row < n) ? bfbits2f(*(const unsigned short*)&xin[row * 32 + cc]) : 0.f;
        }
        __syncthreads();
        float acc = bc;
        const float4* pm = (const float4*)&sm[rr * 32];
        const float4* px = (const float4*)&sx[rr * 32];
        #pragma unroll
        for (int k4 = 0; k4 < 8; ++k4) {
            float4 vm = pm[k4], vx = px[k4];
            const float* wl = &sWl[(k4 * 4) * 32 + c];
            const float* wr = &sWr[(k4 * 4) * 32 + c];
            acc += vm.x * wl[0] + vm.y * wl[32] + vm.z * wl[64] + vm.w * wl[96];
            acc += vx.x * wr[0] + vx.y * wr[32] + vx.z * wr[64] + vx.w * wr[96];
        }
        int row = row0 + rr;
        if (row < n) out[row * 32 + c] = fmaxf(acc, 0.f);
    }
}

// ---------------- global mean pool (batch sorted) ----------------
__device__ __forceinline__ int lower_bound_i(const int* a, int n, int key) {
    int lo = 0, hi = n;
    while (lo < hi) { int mid = (lo + hi) >> 1; if (a[mid] < key) lo = mid + 1; else hi = mid; }
    return lo;
}

__global__ __launch_bounds__(256) void pool_kernel(
    const float* __restrict__ x, const int* __restrict__ batch,
    float* __restrict__ gpool, int n)
{
    int g = blockIdx.x;
    int lo = lower_bound_i(batch, n, g);
    int hi = lower_bound_i(batch, n, g + 1);
    int t = threadIdx.x;
    int c = t & 31, rr = t >> 5;
    float acc = 0.f;
    for (int i = lo + rr; i < hi; i += 8) acc += x[i * 32 + c];
    __shared__ float sred[256];
    sred[t] = acc;
    __syncthreads();
    if (t < 128) sred[t] += sred[t + 128];
    __syncthreads();
    if (t < 64) sred[t] += sred[t + 64];
    __syncthreads();
    if (t < 32) {
        float v = sred[t] + sred[t + 32];
        gpool[g * 32 + t] = v / fmaxf((float)(hi - lo), 1.f);
    }
}

// ---------------- MLP head ----------------
__global__ __launch_bounds__(256) void head_kernel(
    const float* __restrict__ gpool, const float* __restrict__ Wf1, const float* __restrict__ bf1,
    const float* __restrict__ Wf2, const float* __restrict__ bf2, float* __restrict__ out)
{
    __shared__ float sg[64 * 32], st[64 * 32];
    __shared__ float sW1[32 * 32], sW2[32 * 10];
    int t = threadIdx.x;
    for (int i = t; i < 2048; i += 256) sg[i] = gpool[i];
    for (int i = t; i < 1024; i += 256) sW1[i] = Wf1[i];
    for (int i = t; i < 320; i += 256) sW2[i] = Wf2[i];
    __syncthreads();
    for (int i = t; i < 2048; i += 256) {
        int g = i >> 5, c = i & 31;
        float acc = bf1[c];
        #pragma unroll
        for (int k = 0; k < 32; ++k) acc += sg[g * 32 + k] * sW1[k * 32 + c];
        st[i] = fmaxf(acc, 0.f);
    }
    __syncthreads();
    for (int i = t; i < 640; i += 256) {
        int g = i / 10, o = i - g * 10;
        float acc = bf2[o];
        #pragma unroll
        for (int k = 0; k < 32; ++k) acc += st[g * 32 + k] * sW2[k * 10 + o];
        out[i] = acc;
    }
}

extern "C" void kernel_launch(void* const* d_in, const int* in_sizes, int n_in,
                              void* d_out, int out_size, void* d_ws, size_t ws_size,
                              hipStream_t stream) {
    const float* x    = (const float*)d_in[0];
    const int*   ei   = (const int*)d_in[1];
    const int*   batch= (const int*)d_in[2];
    const float* W1   = (const float*)d_in[3];
    const float* as1  = (const float*)d_in[4];
    const float* ad1  = (const float*)d_in[5];
    const float* b1   = (const float*)d_in[6];
    const float* W2   = (const float*)d_in[7];
    const float* as2  = (const float*)d_in[8];
    const float* ad2  = (const float*)d_in[9];
    const float* b2   = (const float*)d_in[10];
    const float* W3r  = (const float*)d_in[11];
    const float* W3l  = (const float*)d_in[12];
    const float* b3   = (const float*)d_in[13];
    const float* W4l  = (const float*)d_in[14];
    const float* b4l  = (const float*)d_in[15];
    const float* W4r  = (const float*)d_in[16];
    const float* Wf1  = (const float*)d_in[17];
    const float* bf1  = (const float*)d_in[18];
    const float* Wf2  = (const float*)d_in[19];
    const float* bf2  = (const float*)d_in[20];

    const int N = in_sizes[0] / 128;
    const int E = in_sizes[1] / 2;
    const int* src = ei;
    const int* dst = ei + E;

    char* p = (char*)d_ws;
    auto alloc = [&](size_t bytes) -> void* {
        void* r = (void*)p;
        p += (bytes + 255) & ~(size_t)255;
        return r;
    };
    __hip_bfloat16* buf1 = (__hip_bfloat16*)alloc((size_t)N * 128 * 2);  // x2 / X4
    __hip_bfloat16* buf2 = (__hip_bfloat16*)alloc((size_t)N * 128 * 2);  // x1 / x3+mean
    __hip_bfloat16* buf3 = (__hip_bfloat16*)alloc((size_t)N * 128 * 2);  // pairs / h1,h2 / y+root
    float* aS     = (float*)alloc((size_t)N * 4 * 4);
    float* aD     = (float*)alloc((size_t)N * 4 * 4);
    int*   rowptr = (int*)alloc((size_t)(N + 1) * 4);
    int*   colsrc = (int*)alloc((size_t)E * 4);
    int*   bcount = (int*)alloc(256 * 4);
    int*   bbase  = (int*)alloc(257 * 4);
    int*   gcursor= (int*)alloc(256 * 4);
    __hip_bfloat16* W1t  = (__hip_bfloat16*)alloc(144 * 128 * 2);
    __hip_bfloat16* W2t  = (__hip_bfloat16*)alloc(144 * 128 * 2);
    __hip_bfloat16* W3rt = (__hip_bfloat16*)alloc(32 * 128 * 2);
    __hip_bfloat16* W3lt = (__hip_bfloat16*)alloc(32 * 128 * 2);
    float* gpool  = (float*)alloc(64 * 32 * 4);

    // aliased views
    __hip_bfloat16* X3b  = buf2;                                        // N*32 bf16
    float*          MEAN = (float*)((char*)buf2 + (((size_t)N * 32 * 2 + 255) & ~(size_t)255));
    float*          X4   = (float*)buf1;                                // N*32 fp32
    __hip_bfloat16* Y32  = buf3;                                        // N*32 bf16
    float*          ROOT = (float*)((char*)buf3 + (((size_t)N * 32 * 2 + 255) & ~(size_t)255));
    int*            pairs = (int*)buf3;   // E*4 B, consumed before h is written

    const int nbuck = (N + 255) >> 8;     // 196 for N=50000 (requires N<=65536)

    // ---- bucketed CSR build + weight prep ----
    hipMemsetAsync(bcount, 0, 256 * 4, stream);
    bucket_hist<<<(E + 4095) / 4096, 256, 0, stream>>>(dst, bcount, E, nbuck);
    scan_convert<<<65, 256, 0, stream>>>(bcount, bbase, gcursor, nbuck, E, rowptr, N,
                                         W1, W2, W3r, W3l, as1, ad1, as2, ad2,
                                         W1t, W2t, W3rt, W3lt);
    bucket_scatter<<<(E + 2047) / 2048, 256, 0, stream>>>(dst, src, gcursor, pairs, E, nbuck);
    bucket_fill<<<nbuck, 256, 0, stream>>>(pairs, bbase, rowptr, colsrc, N);

    const int gmm = (N + 63) / 64;
    const int gag = (N + 3) / 4;
    // GAT layer 1 (reads fp32 x directly)
    gemm_att_mfma<float><<<gmm, 256, 0, stream>>>(x, W1t, buf3, aS, aD, N);
    gat_aggr<<<gag, 256, 0, stream>>>(buf3, aS, aD, rowptr, colsrc, b1, buf2, N);
    // GAT layer 2
    gemm_att_mfma<__hip_bfloat16><<<gmm, 256, 0, stream>>>(buf2, W2t, buf3, aS, aD, N);
    gat_aggr<<<gag, 256, 0, stream>>>(buf3, aS, aD, rowptr, colsrc, b2, buf1, N);
    // GraphConv (project first, then 64B-row gather)
    graphconv_lin<<<gmm, 256, 0, stream>>>(buf1, W3rt, W3lt, b3, Y32, ROOT, N);
    graphconv_aggr<<<gag, 256, 0, stream>>>(Y32, ROOT, rowptr, colsrc, X3b, N);
    // SAGE
    mean_aggr32<<<gag, 256, 0, stream>>>(X3b, rowptr, colsrc, MEAN, N);
    sage_gemm<<<1024, 256, 0, stream>>>(MEAN, X3b, W4l, b4l, W4r, X4, N);
    // pool + head
    pool_kernel<<<64, 256, 0, stream>>>(X4, batch, gpool, N);
    head_kernel<<<1, 256, 0, stream>>>(gpool, Wf1, bf1, Wf2, bf2, (float*)d_out);
}